// Round 1
// baseline (6626.382 us; speedup 1.0000x reference)
//
#include <hip/hip_runtime.h>
#include <math.h>

#define D_  128
#define B_  8
#define H_  8
#define LC_ 512
#define LQ_ 64

// ---------------------------------------------------------------- kernels

__global__ void k_pos_add(const float* __restrict__ x, float* __restrict__ y,
                          int L, int total) {
  int idx = blockIdx.x * 256 + threadIdx.x;
  if (idx >= total) return;
  int l = idx % L;
  int d = (idx / L) & (D_ - 1);
  const float inc = 0.14619588f;  // log(1e4)/63
  int j = d & 63;
  float arg = (float)l * expf(-(float)j * inc);
  float sig = (d < 64) ? sinf(arg) : cosf(arg);
  y[idx] = x[idx] + sig;
}

__global__ void k_ln(const float* __restrict__ x, float* __restrict__ y,
                     const float* __restrict__ g, const float* __restrict__ be,
                     int L, int total) {
  int idx = blockIdx.x * 256 + threadIdx.x;
  if (idx >= total) return;  // total = B*L, one thread per column
  int l = idx % L;
  int b = idx / L;
  const float* xb = x + (size_t)b * D_ * L + l;
  float s = 0.f, s2 = 0.f;
#pragma unroll 8
  for (int d = 0; d < D_; d++) {
    float v = xb[(size_t)d * L];
    s += v; s2 += v * v;
  }
  float mu = s * (1.f / D_);
  float var = fmaxf(s2 * (1.f / D_) - mu * mu, 0.f);
  float rstd = rsqrtf(var + 1e-5f);
  float* yb = y + (size_t)b * D_ * L + l;
#pragma unroll 8
  for (int d = 0; d < D_; d++) {
    float v = xb[(size_t)d * L];
    yb[(size_t)d * L] = (v - mu) * rstd * g[d] + be[d];
  }
}

__global__ void k_dwconv(const float* __restrict__ x, float* __restrict__ y,
                         const float* __restrict__ w, int K, int L, int total) {
  int idx = blockIdx.x * 256 + threadIdx.x;
  if (idx >= total) return;
  int l = idx % L;
  int d = (idx / L) & (D_ - 1);
  const float* wr = w + d * K;
  const float* xr = x + (idx - l);
  int r = K >> 1;
  float acc = 0.f;
  for (int t = 0; t < K; t++) {
    int ll = l + t - r;
    float v = (ll >= 0 && ll < L) ? xr[ll] : 0.f;
    acc += wr[t] * v;
  }
  y[idx] = acc;
}

// y[b,o,l] = op( sum_i w[o,i] x[b,i,l] + bias ) [+ res]; grid (L/64, O/64, B)
template <int RELU, int RES, int BIAS>
__global__ __launch_bounds__(256) void k_conv1x1(
    const float* __restrict__ x, const float* __restrict__ w,
    const float* __restrict__ bias, const float* __restrict__ res,
    float* __restrict__ y, int I, int L) {
  __shared__ float xs[64][64];
  __shared__ float wsT[64][64];
  int l0 = blockIdx.x * 64;
  int o0 = blockIdx.y * 64;
  int b = blockIdx.z;
  int O = gridDim.y * 64;
  int tid = threadIdx.x;
  int tx = tid & 15, ty = tid >> 4;
  float acc[4][4] = {};
  for (int kt = 0; kt < I; kt += 64) {
    for (int idx = tid; idx < 64 * 64; idx += 256) {
      int i = idx >> 6, c = idx & 63;
      xs[i][c] = x[((size_t)b * I + kt + i) * L + l0 + c];
    }
    for (int idx = tid; idx < 64 * 64; idx += 256) {
      int oo = idx & 63, i = idx >> 6;
      wsT[i][oo] = w[(size_t)(o0 + oo) * I + kt + i];
    }
    __syncthreads();
#pragma unroll 4
    for (int i = 0; i < 64; i++) {
      float4 xv = *(const float4*)&xs[i][tx * 4];
      float4 wv = *(const float4*)&wsT[i][ty * 4];
      acc[0][0] += wv.x * xv.x; acc[0][1] += wv.x * xv.y; acc[0][2] += wv.x * xv.z; acc[0][3] += wv.x * xv.w;
      acc[1][0] += wv.y * xv.x; acc[1][1] += wv.y * xv.y; acc[1][2] += wv.y * xv.z; acc[1][3] += wv.y * xv.w;
      acc[2][0] += wv.z * xv.x; acc[2][1] += wv.z * xv.y; acc[2][2] += wv.z * xv.z; acc[2][3] += wv.z * xv.w;
      acc[3][0] += wv.w * xv.x; acc[3][1] += wv.w * xv.y; acc[3][2] += wv.w * xv.z; acc[3][3] += wv.w * xv.w;
    }
    __syncthreads();
  }
  for (int j = 0; j < 4; j++) {
    int o = o0 + ty * 4 + j;
    float bv = BIAS ? bias[o] : 0.f;
    size_t base = ((size_t)b * O + o) * L + l0 + tx * 4;
    float4 v;
    v.x = acc[j][0] + bv; v.y = acc[j][1] + bv; v.z = acc[j][2] + bv; v.w = acc[j][3] + bv;
    if (RELU) {
      v.x = fmaxf(v.x, 0.f); v.y = fmaxf(v.y, 0.f);
      v.z = fmaxf(v.z, 0.f); v.w = fmaxf(v.w, 0.f);
    }
    if (RES) {
      float4 r = *(const float4*)&res[base];
      v.x += r.x; v.y += r.y; v.z += r.z; v.w += r.w;
    }
    *(float4*)&y[base] = v;
  }
}

// flash-style attention, residual fused: cur += softmax(QK^T)V ; grid (L/64, H, B)
__global__ __launch_bounds__(256) void k_attn(
    const float* __restrict__ memKV, const float* __restrict__ qp,
    const float* __restrict__ mask, float* __restrict__ cur, int L) {
  __shared__ float Qs[64][17];
  __shared__ float Ks[128][17];
  __shared__ float Vs[128][17];
  __shared__ float Ss[64][129];
  __shared__ float Ms[128];
  int q0 = blockIdx.x * 64;
  int h = blockIdx.y, b = blockIdx.z;
  int tid = threadIdx.x;
  const float* qb = qp + ((size_t)b * D_ + h * 16) * L;
  const float* kb = memKV + ((size_t)b * 256 + h * 16) * L;
  const float* vb = memKV + ((size_t)b * 256 + 128 + h * 16) * L;
  for (int idx = tid; idx < 64 * 16; idx += 256) {
    int e = idx >> 6, q = idx & 63;
    Qs[q][e] = qb[(size_t)e * L + q0 + q] * 0.25f;  // dh^-0.5 = 16^-0.5
  }
  int ql = tid & 63, g = tid >> 6;
  float m = -INFINITY, ssum = 0.f;
  float a0 = 0.f, a1 = 0.f, a2 = 0.f, a3 = 0.f;
  for (int k0 = 0; k0 < L; k0 += 128) {
    __syncthreads();
    for (int idx = tid; idx < 128 * 16; idx += 256) {
      int e = idx >> 7, k = idx & 127;
      bool ok = (k0 + k) < L;
      Ks[k][e] = ok ? kb[(size_t)e * L + k0 + k] : 0.f;
      Vs[k][e] = ok ? vb[(size_t)e * L + k0 + k] : 0.f;
    }
    if (tid < 128) Ms[tid] = ((k0 + tid) < L) ? mask[(size_t)b * L + k0 + tid] : 0.f;
    __syncthreads();
    for (int idx = tid; idx < 64 * 128; idx += 256) {
      int q = idx >> 7, k = idx & 127;
      float dot = 0.f;
#pragma unroll
      for (int e = 0; e < 16; e++) dot += Qs[q][e] * Ks[k][e];
      float mv = Ms[k];
      Ss[q][k] = dot * mv + (1.f - mv) * (-1e30f);
    }
    __syncthreads();
    float tmax = -INFINITY;
#pragma unroll 8
    for (int k = 0; k < 128; k++) tmax = fmaxf(tmax, Ss[ql][k]);
    float nm = fmaxf(m, tmax);
    float c = expf(m - nm);
    ssum *= c; a0 *= c; a1 *= c; a2 *= c; a3 *= c;
#pragma unroll 4
    for (int k = 0; k < 128; k++) {
      float p = expf(Ss[ql][k] - nm);
      ssum += p;
      a0 += p * Vs[k][g * 4 + 0];
      a1 += p * Vs[k][g * 4 + 1];
      a2 += p * Vs[k][g * 4 + 2];
      a3 += p * Vs[k][g * 4 + 3];
    }
    m = nm;
  }
  float inv = 1.f / ssum;
  size_t ob = ((size_t)b * D_ + h * 16 + g * 4) * L + q0 + ql;
  cur[ob] += a0 * inv;
  cur[ob + (size_t)L] += a1 * inv;
  cur[ob + 2 * (size_t)L] += a2 * inv;
  cur[ob + 3 * (size_t)L] += a3 * inv;
}

__global__ void k_concat2(const float* __restrict__ x1, const float* __restrict__ x2,
                          float* __restrict__ out, int L, int total) {
  int idx = blockIdx.x * 256 + threadIdx.x;
  if (idx >= total) return;
  int l = idx % L;
  int c = (idx / L) & 255;
  int b = idx / (L * 256);
  float v = (c < 128) ? x1[((size_t)b * 128 + c) * L + l]
                      : x2[((size_t)b * 128 + (c - 128)) * L + l];
  out[idx] = v;
}

__global__ void k_chandot(const float* __restrict__ X, const float* __restrict__ w,
                          float* __restrict__ out, int C, int L, int total) {
  int idx = blockIdx.x * 256 + threadIdx.x;
  if (idx >= total) return;
  int l = idx % L;
  int b = idx / L;
  const float* xb = X + (size_t)b * C * L + l;
  float s = 0.f;
  for (int j = 0; j < C; j++) s += xb[(size_t)j * L] * w[j];
  out[idx] = s;
}

__global__ void k_cqS(const float* __restrict__ Ce, const float* __restrict__ Qe,
                      const float* __restrict__ s0, const float* __restrict__ s1,
                      const float* __restrict__ w4mlu, const float* __restrict__ cqb,
                      float* __restrict__ S) {
  int idx = blockIdx.x * 256 + threadIdx.x;  // B*LC*LQ
  if (idx >= B_ * LC_ * LQ_) return;
  int q = idx & 63;
  int l = (idx >> 6) % LC_;
  int b = (idx >> 6) / LC_;
  const float* ce = Ce + (size_t)b * 256 * LC_ + l;
  const float* qe = Qe + (size_t)b * 256 * LQ_ + q;
  float acc = 0.f;
  for (int j = 0; j < 256; j++) acc += ce[(size_t)j * LC_] * w4mlu[j] * qe[(size_t)j * LQ_];
  S[idx] = acc + s0[b * LC_ + l] + s1[b * LQ_ + q] + cqb[0];
}

__global__ void k_softmax_row(const float* __restrict__ S, const float* __restrict__ qmask,
                              float* __restrict__ S1) {
  int wave = (blockIdx.x * 256 + threadIdx.x) >> 6;  // one wave per (b,l)
  int lane = threadIdx.x & 63;
  int l = wave % LC_, b = wave / LC_;
  float mv = qmask[b * LQ_ + lane];
  float v = S[((size_t)b * LC_ + l) * LQ_ + lane];
  v = v * mv + (1.f - mv) * (-1e30f);
  float mx = v;
  for (int off = 32; off; off >>= 1) mx = fmaxf(mx, __shfl_xor(mx, off));
  float p = expf(v - mx);
  float s = p;
  for (int off = 32; off; off >>= 1) s += __shfl_xor(s, off);
  S1[((size_t)b * LC_ + l) * LQ_ + lane] = p / s;
}

__global__ void k_softmax_col(const float* __restrict__ S, const float* __restrict__ cmask,
                              float* __restrict__ S2) {
  int idx = blockIdx.x * 256 + threadIdx.x;  // B*LQ threads
  if (idx >= B_ * LQ_) return;
  int q = idx % LQ_, b = idx / LQ_;
  const float* col = S + (size_t)b * LC_ * LQ_ + q;
  const float* mk = cmask + b * LC_;
  float mx = -INFINITY;
  for (int l = 0; l < LC_; l++) {
    float mv = mk[l];
    float v = col[(size_t)l * LQ_] * mv + (1.f - mv) * (-1e30f);
    mx = fmaxf(mx, v);
  }
  float s = 0.f;
  for (int l = 0; l < LC_; l++) {
    float mv = mk[l];
    float v = col[(size_t)l * LQ_] * mv + (1.f - mv) * (-1e30f);
    s += expf(v - mx);
  }
  float invs = 1.f / s;
  float* out = S2 + (size_t)b * LC_ * LQ_ + q;
  for (int l = 0; l < LC_; l++) {
    float mv = mk[l];
    float v = col[(size_t)l * LQ_] * mv + (1.f - mv) * (-1e30f);
    out[(size_t)l * LQ_] = expf(v - mx) * invs;
  }
}

// Y[b,j,q] = sum_l S2[b,l,q] * Ce[b,j,l]
__global__ void k_cqY(const float* __restrict__ S2, const float* __restrict__ Ce,
                      float* __restrict__ Y) {
  int idx = blockIdx.x * 256 + threadIdx.x;  // B*256*LQ
  if (idx >= B_ * 256 * LQ_) return;
  int q = idx & 63;
  int j = (idx >> 6) & 255;
  int b = idx >> 14;
  const float* s2 = S2 + (size_t)b * LC_ * LQ_ + q;
  const float* ce = Ce + ((size_t)b * 256 + j) * LC_;
  float acc = 0.f;
  for (int l = 0; l < LC_; l++) acc += s2[(size_t)l * LQ_] * ce[l];
  Y[idx] = acc;
}

// A[b,j,l] = sum_q S1[b,l,q] Qe[b,j,q];  Bt[b,j,l] = sum_q S1[b,l,q] Y[b,j,q]
__global__ __launch_bounds__(256) void k_cqAB(
    const float* __restrict__ S1, const float* __restrict__ Qe, const float* __restrict__ Y,
    float* __restrict__ A, float* __restrict__ Bt) {
  __shared__ float s1s[64][65];
  int l0 = blockIdx.x * 64;
  int b = blockIdx.z;
  int tid = threadIdx.x;
  for (int idx = tid; idx < 64 * 64; idx += 256) {
    int l = idx >> 6, q = idx & 63;
    s1s[l][q] = S1[((size_t)b * LC_ + l0 + l) * LQ_ + q];
  }
  __syncthreads();
  int ll = tid & 63, jj = tid >> 6;
  int j = blockIdx.y * 4 + jj;
  const float* qe = Qe + ((size_t)b * 256 + j) * LQ_;
  const float* yb = Y + ((size_t)b * 256 + j) * LQ_;
  float a = 0.f, bt = 0.f;
#pragma unroll 8
  for (int q = 0; q < 64; q++) {
    float sv = s1s[ll][q];
    a += sv * qe[q];
    bt += sv * yb[q];
  }
  A[((size_t)b * 256 + j) * LC_ + l0 + ll] = a;
  Bt[((size_t)b * 256 + j) * LC_ + l0 + ll] = bt;
}

// M0 = resizer_w [128,1280] @ X where X rows: [Ce; A; Ce*A; Ce*Bt; Ce]
__global__ __launch_bounds__(256) void k_resizer(
    const float* __restrict__ Ce, const float* __restrict__ A, const float* __restrict__ Bt,
    const float* __restrict__ w, float* __restrict__ y) {
  __shared__ float xs[64][64];
  __shared__ float wsT[64][64];
  int l0 = blockIdx.x * 64;
  int o0 = blockIdx.y * 64;
  int b = blockIdx.z;
  int tid = threadIdx.x;
  int tx = tid & 15, ty = tid >> 4;
  float acc[4][4] = {};
  for (int kt = 0; kt < 1280; kt += 64) {
    for (int idx = tid; idx < 64 * 64; idx += 256) {
      int i = idx >> 6, cc = idx & 63;
      int c = kt + i;
      int seg = c >> 8;
      int jch = c & 255;
      size_t p = ((size_t)b * 256 + jch) * LC_ + l0 + cc;
      float v;
      if (seg == 0 || seg == 4) v = Ce[p];
      else if (seg == 1) v = A[p];
      else if (seg == 2) v = Ce[p] * A[p];
      else v = Ce[p] * Bt[p];
      xs[i][cc] = v;
    }
    for (int idx = tid; idx < 64 * 64; idx += 256) {
      int oo = idx & 63, i = idx >> 6;
      wsT[i][oo] = w[(size_t)(o0 + oo) * 1280 + kt + i];
    }
    __syncthreads();
#pragma unroll 4
    for (int i = 0; i < 64; i++) {
      float4 xv = *(const float4*)&xs[i][tx * 4];
      float4 wv = *(const float4*)&wsT[i][ty * 4];
      acc[0][0] += wv.x * xv.x; acc[0][1] += wv.x * xv.y; acc[0][2] += wv.x * xv.z; acc[0][3] += wv.x * xv.w;
      acc[1][0] += wv.y * xv.x; acc[1][1] += wv.y * xv.y; acc[1][2] += wv.y * xv.z; acc[1][3] += wv.y * xv.w;
      acc[2][0] += wv.z * xv.x; acc[2][1] += wv.z * xv.y; acc[2][2] += wv.z * xv.z; acc[2][3] += wv.z * xv.w;
      acc[3][0] += wv.w * xv.x; acc[3][1] += wv.w * xv.y; acc[3][2] += wv.w * xv.z; acc[3][3] += wv.w * xv.w;
    }
    __syncthreads();
  }
  for (int j = 0; j < 4; j++) {
    int o = o0 + ty * 4 + j;
    *(float4*)&y[((size_t)b * D_ + o) * LC_ + l0 + tx * 4] =
        make_float4(acc[j][0], acc[j][1], acc[j][2], acc[j][3]);
  }
}

// ---------------------------------------------------------------- host side

struct BlkP {
  int n_conv, k;
  const float* lnc_g[4]; const float* lnc_b[4];
  const float* dw[4]; const float* pw[4]; const float* pw_b[4];
  const float* mem_w; const float* q_w;
  const float* ln1_g; const float* ln1_b;
  const float* ffn1_w; const float* ffn1_b;
  const float* ffn2_w; const float* ffn2_b;
  const float* ln2_g; const float* ln2_b;
};

static void encoder_block(hipStream_t st, const float* xin, float* cur,
                          float* t1, float* t2, float* mkv, float* qpb,
                          const float* mask, int L, const BlkP& P) {
  int totBDL = B_ * D_ * L;
  k_pos_add<<<(totBDL + 255) / 256, 256, 0, st>>>(xin, cur, L, totBDL);
  for (int i = 0; i < P.n_conv; i++) {
    k_ln<<<(B_ * L + 255) / 256, 256, 0, st>>>(cur, t1, P.lnc_g[i], P.lnc_b[i], L, B_ * L);
    k_dwconv<<<(totBDL + 255) / 256, 256, 0, st>>>(t1, t2, P.dw[i], P.k, L, totBDL);
    k_conv1x1<1, 1, 1><<<dim3(L / 64, 2, B_), 256, 0, st>>>(t2, P.pw[i], P.pw_b[i], cur, cur, 128, L);
  }
  k_ln<<<(B_ * L + 255) / 256, 256, 0, st>>>(cur, t1, P.ln1_g, P.ln1_b, L, B_ * L);
  k_conv1x1<0, 0, 0><<<dim3(L / 64, 4, B_), 256, 0, st>>>(t1, P.mem_w, nullptr, nullptr, mkv, 128, L);
  k_conv1x1<0, 0, 0><<<dim3(L / 64, 2, B_), 256, 0, st>>>(t1, P.q_w, nullptr, nullptr, qpb, 128, L);
  k_attn<<<dim3(L / 64, H_, B_), 256, 0, st>>>(mkv, qpb, mask, cur, L);
  k_ln<<<(B_ * L + 255) / 256, 256, 0, st>>>(cur, t1, P.ln2_g, P.ln2_b, L, B_ * L);
  k_conv1x1<1, 0, 1><<<dim3(L / 64, 2, B_), 256, 0, st>>>(t1, P.ffn1_w, P.ffn1_b, nullptr, t2, 128, L);
  k_conv1x1<0, 1, 1><<<dim3(L / 64, 2, B_), 256, 0, st>>>(t2, P.ffn2_w, P.ffn2_b, cur, cur, 128, L);
}

extern "C" void kernel_launch(void* const* d_in, const int* in_sizes, int n_in,
                              void* d_out, int out_size, void* d_ws, size_t ws_size,
                              hipStream_t stream) {
  (void)in_sizes; (void)n_in; (void)out_size; (void)ws_size;
  const float* C        = (const float*)d_in[0];
  const float* Q        = (const float*)d_in[1];
  const float* maskC    = (const float*)d_in[2];
  const float* maskQ    = (const float*)d_in[3];
  const float* e_dw     = (const float*)d_in[4];
  const float* e_pw     = (const float*)d_in[5];
  const float* e_pw_b   = (const float*)d_in[6];
  const float* e_lnc_g  = (const float*)d_in[7];
  const float* e_lnc_b  = (const float*)d_in[8];
  const float* e_mem_w  = (const float*)d_in[9];
  const float* e_q_w    = (const float*)d_in[10];
  const float* e_ffn1_w = (const float*)d_in[11];
  const float* e_ffn1_b = (const float*)d_in[12];
  const float* e_ffn2_w = (const float*)d_in[13];
  const float* e_ffn2_b = (const float*)d_in[14];
  const float* e_ln1_g  = (const float*)d_in[15];
  const float* e_ln1_b  = (const float*)d_in[16];
  const float* e_ln2_g  = (const float*)d_in[17];
  const float* e_ln2_b  = (const float*)d_in[18];
  const float* w4C      = (const float*)d_in[19];
  const float* w4Q      = (const float*)d_in[20];
  const float* w4mlu    = (const float*)d_in[21];
  const float* cq_b     = (const float*)d_in[22];
  const float* resizer_w= (const float*)d_in[23];
  const float* m_dw     = (const float*)d_in[24];
  const float* m_pw     = (const float*)d_in[25];
  const float* m_pw_b   = (const float*)d_in[26];
  const float* m_lnc_g  = (const float*)d_in[27];
  const float* m_lnc_b  = (const float*)d_in[28];
  const float* m_mem_w  = (const float*)d_in[29];
  const float* m_q_w    = (const float*)d_in[30];
  const float* m_ffn1_w = (const float*)d_in[31];
  const float* m_ffn1_b = (const float*)d_in[32];
  const float* m_ffn2_w = (const float*)d_in[33];
  const float* m_ffn2_b = (const float*)d_in[34];
  const float* m_ln1_g  = (const float*)d_in[35];
  const float* m_ln1_b  = (const float*)d_in[36];
  const float* m_ln2_g  = (const float*)d_in[37];
  const float* m_ln2_b  = (const float*)d_in[38];

  float* ws = (float*)d_ws;
  const size_t SB = (size_t)B_ * D_ * LC_;  // 524288
  float* cur  = ws;
  float* t1   = cur + SB;
  float* t2   = t1 + SB;
  float* mkv  = t2 + SB;                 // 2*SB
  float* qpb  = mkv + 2 * SB;            // SB
  float* Ce   = qpb + SB;                // 2*SB
  float* Qe   = Ce + 2 * SB;             // B*256*LQ
  float* Sbuf = Qe + (size_t)B_ * 256 * LQ_;
  float* S1   = Sbuf + (size_t)B_ * LC_ * LQ_;
  float* S2   = S1 + (size_t)B_ * LC_ * LQ_;
  float* s0v  = S2 + (size_t)B_ * LC_ * LQ_;
  float* s1v  = s0v + (size_t)B_ * LC_;
  float* Yb   = s1v + (size_t)B_ * LQ_;
  float* Ab   = Yb + (size_t)B_ * 256 * LQ_;  // 2*SB
  float* Bb   = Ab + 2 * SB;                  // 2*SB
  float* Mb   = Bb + 2 * SB;                  // SB

  // input-encoder params (shared C/Q): 4 convs, k=7
  BlkP ep{};
  ep.n_conv = 4; ep.k = 7;
  for (int i = 0; i < 4; i++) {
    ep.lnc_g[i] = e_lnc_g + i * 128;
    ep.lnc_b[i] = e_lnc_b + i * 128;
    ep.dw[i]    = e_dw + i * 128 * 7;
    ep.pw[i]    = e_pw + (size_t)i * 128 * 128;
    ep.pw_b[i]  = e_pw_b + i * 128;
  }
  ep.mem_w = e_mem_w; ep.q_w = e_q_w;
  ep.ln1_g = e_ln1_g; ep.ln1_b = e_ln1_b;
  ep.ffn1_w = e_ffn1_w; ep.ffn1_b = e_ffn1_b;
  ep.ffn2_w = e_ffn2_w; ep.ffn2_b = e_ffn2_b;
  ep.ln2_g = e_ln2_g; ep.ln2_b = e_ln2_b;

  // ---- C encoder -> Ce ----
  encoder_block(stream, C, cur, t1, t2, mkv, qpb, maskC, LC_, ep);
  {
    int tot = B_ * 256 * LC_;
    k_concat2<<<(tot + 255) / 256, 256, 0, stream>>>(cur, C, Ce, LC_, tot);
  }
  // ---- Q encoder -> Qe ----
  encoder_block(stream, Q, cur, t1, t2, mkv, qpb, maskQ, LQ_, ep);
  {
    int tot = B_ * 256 * LQ_;
    k_concat2<<<(tot + 255) / 256, 256, 0, stream>>>(cur, Q, Qe, LQ_, tot);
  }

  // ---- CQ attention + resizer -> Mb (= M0) ----
  k_chandot<<<(B_ * LC_ + 255) / 256, 256, 0, stream>>>(Ce, w4C, s0v, 256, LC_, B_ * LC_);
  k_chandot<<<(B_ * LQ_ + 255) / 256, 256, 0, stream>>>(Qe, w4Q, s1v, 256, LQ_, B_ * LQ_);
  k_cqS<<<(B_ * LC_ * LQ_) / 256, 256, 0, stream>>>(Ce, Qe, s0v, s1v, w4mlu, cq_b, Sbuf);
  k_softmax_row<<<(B_ * LC_) / 4, 256, 0, stream>>>(Sbuf, maskQ, S1);
  k_softmax_col<<<(B_ * LQ_ + 255) / 256, 256, 0, stream>>>(Sbuf, maskC, S2);
  k_cqY<<<(B_ * 256 * LQ_) / 256, 256, 0, stream>>>(S2, Ce, Yb);
  k_cqAB<<<dim3(LC_ / 64, 64, B_), 256, 0, stream>>>(S1, Qe, Yb, Ab, Bb);
  k_resizer<<<dim3(LC_ / 64, 2, B_), 256, 0, stream>>>(Ce, Ab, Bb, resizer_w, Mb);

  // ---- model encoder: 3 runs of 7 blocks ----
  float* out = (float*)d_out;
  const float* src = Mb;
  for (int r = 0; r < 3; r++) {
    for (int bi = 0; bi < 7; bi++) {
      BlkP mp{};
      mp.n_conv = 2; mp.k = 5;
      for (int ci = 0; ci < 2; ci++) {
        int pc = bi * 2 + ci;
        mp.lnc_g[ci] = m_lnc_g + pc * 128;
        mp.lnc_b[ci] = m_lnc_b + pc * 128;
        mp.dw[ci]    = m_dw + pc * 128 * 5;
        mp.pw[ci]    = m_pw + (size_t)pc * 128 * 128;
        mp.pw_b[ci]  = m_pw_b + pc * 128;
      }
      mp.mem_w  = m_mem_w + (size_t)bi * 256 * 128;
      mp.q_w    = m_q_w + (size_t)bi * 128 * 128;
      mp.ffn1_w = m_ffn1_w + (size_t)bi * 128 * 128;
      mp.ffn1_b = m_ffn1_b + bi * 128;
      mp.ffn2_w = m_ffn2_w + (size_t)bi * 128 * 128;
      mp.ffn2_b = m_ffn2_b + bi * 128;
      mp.ln1_g = m_ln1_g + bi * 128; mp.ln1_b = m_ln1_b + bi * 128;
      mp.ln2_g = m_ln2_g + bi * 128; mp.ln2_b = m_ln2_b + bi * 128;
      encoder_block(stream, (bi == 0) ? src : cur, cur, t1, t2, mkv, qpb, maskC, LC_, mp);
    }
    hipMemcpyAsync(out + (size_t)r * SB, cur, SB * sizeof(float),
                   hipMemcpyDeviceToDevice, stream);
    src = cur;
  }
}

// Round 2
// 5871.923 us; speedup vs baseline: 1.1285x; 1.1285x over previous
//
#include <hip/hip_runtime.h>
#include <math.h>

#define D_  128
#define B_  8
#define H_  8
#define LC_ 512
#define LQ_ 64

// ---------------------------------------------------------------- kernels

// Fused LayerNorm + depthwise conv (+ optional pos-signal add).
// Block = (b, 64-column tile). Stages raw (x[+pos]) [128][70] in LDS,
// computes per-column LN stats, emits dwconv(LN(x)) to dwout.
// If ADDPOS: also writes x+pos to pbuf (residual baseline).
template <int KK, int ADDPOS>
__global__ __launch_bounds__(256) void k_lndw(
    const float* __restrict__ x, float* __restrict__ dwout, float* __restrict__ pbuf,
    const float* __restrict__ dwv, const float* __restrict__ g, const float* __restrict__ be,
    int L) {
  __shared__ float raw[128 * 72];
  __shared__ float mu_s[70], rs_s[70];
  __shared__ float ps[140], ps2[140];
  int l0 = blockIdx.x * 64;
  int b = blockIdx.z;
  int tid = threadIdx.x;
  const float inc = 0.14619588f;  // log(1e4)/63
  for (int idx = tid; idx < 128 * 70; idx += 256) {
    int d = idx / 70, c = idx - d * 70;
    int l = l0 + c - 3;
    float v = 0.f;
    if (l >= 0 && l < L) {
      v = x[((size_t)b * 128 + d) * L + l];
      if (ADDPOS) {
        int j = d & 63;
        float arg = (float)l * expf(-(float)j * inc);
        v += (d < 64) ? sinf(arg) : cosf(arg);
        if (c >= 3 && c < 67) pbuf[((size_t)b * 128 + d) * L + l] = v;
      }
    }
    raw[d * 72 + c] = v;
  }
  __syncthreads();
  if (tid < 140) {
    int c = tid % 70, hh = tid / 70;
    float s = 0.f, s2 = 0.f;
    for (int d = hh * 64; d < hh * 64 + 64; d++) {
      float v = raw[d * 72 + c];
      s += v; s2 += v * v;
    }
    ps[tid] = s; ps2[tid] = s2;
  }
  __syncthreads();
  if (tid < 70) {
    float s = ps[tid] + ps[tid + 70], s2 = ps2[tid] + ps2[tid + 70];
    float mu = s * (1.f / 128.f);
    float var = fmaxf(s2 * (1.f / 128.f) - mu * mu, 0.f);
    mu_s[tid] = mu; rs_s[tid] = rsqrtf(var + 1e-5f);
  }
  __syncthreads();
  const int r = KK / 2;
  for (int idx = tid; idx < 128 * 64; idx += 256) {
    int d = idx >> 6, c = idx & 63;
    float gg = g[d], bb = be[d];
    const float* wr = dwv + d * KK;
    float acc = 0.f;
#pragma unroll
    for (int t = 0; t < KK; t++) {
      int cc = c + 3 + t - r;
      int l = l0 + cc - 3;
      float lv = 0.f;
      if (l >= 0 && l < L)
        lv = (raw[d * 72 + cc] - mu_s[cc]) * rs_s[cc] * gg + bb;
      acc += wr[t] * lv;
    }
    dwout[((size_t)b * 128 + d) * L + l0 + c] = acc;
  }
}

// GEMM y[b,o,l] = op( sum_i w[o,i]*X[b,i,l] + bias ) [+ res]
// where X = LN(x) (stats computed in-block) if LN else x.  K fixed = 128.
// grid (L/64, O/64, B), 256 threads, 64x64 output tile per block.
template <int LN, int RELU, int RES, int BIAS>
__global__ __launch_bounds__(256) void k_lngemm(
    const float* __restrict__ x, const float* __restrict__ w,
    const float* __restrict__ bias, const float* __restrict__ res,
    float* __restrict__ y, const float* __restrict__ g, const float* __restrict__ be,
    int L) {
  __shared__ float xs[128 * 68];
  __shared__ float wsT[128 * 68];
  __shared__ float mu_s[64], rs_s[64];
  __shared__ float ps[256], ps2[256];
  int l0 = blockIdx.x * 64;
  int o0 = blockIdx.y * 64;
  int b = blockIdx.z;
  int O = gridDim.y * 64;
  int tid = threadIdx.x;
  for (int idx = tid; idx < 128 * 64; idx += 256) {
    int d = idx >> 6, c = idx & 63;
    xs[d * 68 + c] = x[((size_t)b * 128 + d) * L + l0 + c];
  }
  for (int idx = tid; idx < 64 * 128; idx += 256) {
    int oo = idx & 63, i = idx >> 6;
    wsT[i * 68 + oo] = w[(size_t)(o0 + oo) * 128 + i];
  }
  __syncthreads();
  if (LN) {
    {
      int c = tid & 63, qq = tid >> 6;
      float s = 0.f, s2 = 0.f;
      for (int d = qq * 32; d < qq * 32 + 32; d++) {
        float v = xs[d * 68 + c];
        s += v; s2 += v * v;
      }
      ps[tid] = s; ps2[tid] = s2;
    }
    __syncthreads();
    if (tid < 64) {
      float s = ps[tid] + ps[tid + 64] + ps[tid + 128] + ps[tid + 192];
      float s2 = ps2[tid] + ps2[tid + 64] + ps2[tid + 128] + ps2[tid + 192];
      float mu = s * (1.f / 128.f);
      float var = fmaxf(s2 * (1.f / 128.f) - mu * mu, 0.f);
      mu_s[tid] = mu; rs_s[tid] = rsqrtf(var + 1e-5f);
    }
    __syncthreads();
    for (int idx = tid; idx < 128 * 64; idx += 256) {
      int d = idx >> 6, c = idx & 63;
      xs[d * 68 + c] = (xs[d * 68 + c] - mu_s[c]) * rs_s[c] * g[d] + be[d];
    }
    __syncthreads();
  }
  int tx = tid & 15, ty = tid >> 4;
  float acc[4][4] = {};
#pragma unroll 4
  for (int i = 0; i < 128; i++) {
    float4 xv = *(const float4*)&xs[i * 68 + tx * 4];
    float4 wv = *(const float4*)&wsT[i * 68 + ty * 4];
    acc[0][0] += wv.x * xv.x; acc[0][1] += wv.x * xv.y; acc[0][2] += wv.x * xv.z; acc[0][3] += wv.x * xv.w;
    acc[1][0] += wv.y * xv.x; acc[1][1] += wv.y * xv.y; acc[1][2] += wv.y * xv.z; acc[1][3] += wv.y * xv.w;
    acc[2][0] += wv.z * xv.x; acc[2][1] += wv.z * xv.y; acc[2][2] += wv.z * xv.z; acc[2][3] += wv.z * xv.w;
    acc[3][0] += wv.w * xv.x; acc[3][1] += wv.w * xv.y; acc[3][2] += wv.w * xv.z; acc[3][3] += wv.w * xv.w;
  }
  for (int j = 0; j < 4; j++) {
    int o = o0 + ty * 4 + j;
    float bv = BIAS ? bias[o] : 0.f;
    size_t base = ((size_t)b * O + o) * L + l0 + tx * 4;
    float4 v;
    v.x = acc[j][0] + bv; v.y = acc[j][1] + bv; v.z = acc[j][2] + bv; v.w = acc[j][3] + bv;
    if (RELU) {
      v.x = fmaxf(v.x, 0.f); v.y = fmaxf(v.y, 0.f);
      v.z = fmaxf(v.z, 0.f); v.w = fmaxf(v.w, 0.f);
    }
    if (RES) {
      float4 rr = *(const float4*)&res[base];
      v.x += rr.x; v.y += rr.y; v.z += rr.z; v.w += rr.w;
    }
    *(float4*)&y[base] = v;
  }
}

// Fused LN + both attention projections (mem_w -> mkv [B,256,L], q_w -> qp [B,128,L]).
// grid (L/64, 6, B): y<4 handles mem outputs, y>=4 handles q outputs.
__global__ __launch_bounds__(256) void k_lnproj(
    const float* __restrict__ x, const float* __restrict__ memw, const float* __restrict__ qw,
    float* __restrict__ mkv, float* __restrict__ qp,
    const float* __restrict__ g, const float* __restrict__ be, int L) {
  __shared__ float xs[128 * 68];
  __shared__ float wsT[128 * 68];
  __shared__ float mu_s[64], rs_s[64];
  __shared__ float ps[256], ps2[256];
  int l0 = blockIdx.x * 64;
  int b = blockIdx.z;
  int yb = blockIdx.y;
  const float* w; float* out; int o0, O;
  if (yb < 4) { w = memw; out = mkv; o0 = yb * 64; O = 256; }
  else        { w = qw;   out = qp;  o0 = (yb - 4) * 64; O = 128; }
  int tid = threadIdx.x;
  for (int idx = tid; idx < 128 * 64; idx += 256) {
    int d = idx >> 6, c = idx & 63;
    xs[d * 68 + c] = x[((size_t)b * 128 + d) * L + l0 + c];
  }
  for (int idx = tid; idx < 64 * 128; idx += 256) {
    int oo = idx & 63, i = idx >> 6;
    wsT[i * 68 + oo] = w[(size_t)(o0 + oo) * 128 + i];
  }
  __syncthreads();
  {
    int c = tid & 63, qq = tid >> 6;
    float s = 0.f, s2 = 0.f;
    for (int d = qq * 32; d < qq * 32 + 32; d++) {
      float v = xs[d * 68 + c];
      s += v; s2 += v * v;
    }
    ps[tid] = s; ps2[tid] = s2;
  }
  __syncthreads();
  if (tid < 64) {
    float s = ps[tid] + ps[tid + 64] + ps[tid + 128] + ps[tid + 192];
    float s2 = ps2[tid] + ps2[tid + 64] + ps2[tid + 128] + ps2[tid + 192];
    float mu = s * (1.f / 128.f);
    float var = fmaxf(s2 * (1.f / 128.f) - mu * mu, 0.f);
    mu_s[tid] = mu; rs_s[tid] = rsqrtf(var + 1e-5f);
  }
  __syncthreads();
  for (int idx = tid; idx < 128 * 64; idx += 256) {
    int d = idx >> 6, c = idx & 63;
    xs[d * 68 + c] = (xs[d * 68 + c] - mu_s[c]) * rs_s[c] * g[d] + be[d];
  }
  __syncthreads();
  int tx = tid & 15, ty = tid >> 4;
  float acc[4][4] = {};
#pragma unroll 4
  for (int i = 0; i < 128; i++) {
    float4 xv = *(const float4*)&xs[i * 68 + tx * 4];
    float4 wv = *(const float4*)&wsT[i * 68 + ty * 4];
    acc[0][0] += wv.x * xv.x; acc[0][1] += wv.x * xv.y; acc[0][2] += wv.x * xv.z; acc[0][3] += wv.x * xv.w;
    acc[1][0] += wv.y * xv.x; acc[1][1] += wv.y * xv.y; acc[1][2] += wv.y * xv.z; acc[1][3] += wv.y * xv.w;
    acc[2][0] += wv.z * xv.x; acc[2][1] += wv.z * xv.y; acc[2][2] += wv.z * xv.z; acc[2][3] += wv.z * xv.w;
    acc[3][0] += wv.w * xv.x; acc[3][1] += wv.w * xv.y; acc[3][2] += wv.w * xv.z; acc[3][3] += wv.w * xv.w;
  }
  for (int j = 0; j < 4; j++) {
    int o = o0 + ty * 4 + j;
    *(float4*)&out[((size_t)b * O + o) * L + l0 + tx * 4] =
        make_float4(acc[j][0], acc[j][1], acc[j][2], acc[j][3]);
  }
}

// flash-style attention, residual fused: cur += softmax(QK^T)V ; grid (L/64, H, B)
__global__ __launch_bounds__(256) void k_attn(
    const float* __restrict__ memKV, const float* __restrict__ qp,
    const float* __restrict__ mask, float* __restrict__ cur, int L) {
  __shared__ float Qs[64][17];
  __shared__ float Ks[128][17];
  __shared__ float Vs[128][17];
  __shared__ float Ss[64][129];
  __shared__ float Ms[128];
  int q0 = blockIdx.x * 64;
  int h = blockIdx.y, b = blockIdx.z;
  int tid = threadIdx.x;
  const float* qb = qp + ((size_t)b * D_ + h * 16) * L;
  const float* kb = memKV + ((size_t)b * 256 + h * 16) * L;
  const float* vb = memKV + ((size_t)b * 256 + 128 + h * 16) * L;
  for (int idx = tid; idx < 64 * 16; idx += 256) {
    int e = idx >> 6, q = idx & 63;
    Qs[q][e] = qb[(size_t)e * L + q0 + q] * 0.25f;
  }
  int ql = tid & 63, g = tid >> 6;
  float m = -INFINITY, ssum = 0.f;
  float a0 = 0.f, a1 = 0.f, a2 = 0.f, a3 = 0.f;
  for (int k0 = 0; k0 < L; k0 += 128) {
    __syncthreads();
    for (int idx = tid; idx < 128 * 16; idx += 256) {
      int e = idx >> 7, k = idx & 127;
      bool ok = (k0 + k) < L;
      Ks[k][e] = ok ? kb[(size_t)e * L + k0 + k] : 0.f;
      Vs[k][e] = ok ? vb[(size_t)e * L + k0 + k] : 0.f;
    }
    if (tid < 128) Ms[tid] = ((k0 + tid) < L) ? mask[(size_t)b * L + k0 + tid] : 0.f;
    __syncthreads();
    for (int idx = tid; idx < 64 * 128; idx += 256) {
      int q = idx >> 7, k = idx & 127;
      float dot = 0.f;
#pragma unroll
      for (int e = 0; e < 16; e++) dot += Qs[q][e] * Ks[k][e];
      float mv = Ms[k];
      Ss[q][k] = dot * mv + (1.f - mv) * (-1e30f);
    }
    __syncthreads();
    float tmax = -INFINITY;
#pragma unroll 8
    for (int k = 0; k < 128; k++) tmax = fmaxf(tmax, Ss[ql][k]);
    float nm = fmaxf(m, tmax);
    float c = expf(m - nm);
    ssum *= c; a0 *= c; a1 *= c; a2 *= c; a3 *= c;
#pragma unroll 4
    for (int k = 0; k < 128; k++) {
      float p = expf(Ss[ql][k] - nm);
      ssum += p;
      a0 += p * Vs[k][g * 4 + 0];
      a1 += p * Vs[k][g * 4 + 1];
      a2 += p * Vs[k][g * 4 + 2];
      a3 += p * Vs[k][g * 4 + 3];
    }
    m = nm;
  }
  float inv = 1.f / ssum;
  size_t ob = ((size_t)b * D_ + h * 16 + g * 4) * L + q0 + ql;
  cur[ob] += a0 * inv;
  cur[ob + (size_t)L] += a1 * inv;
  cur[ob + 2 * (size_t)L] += a2 * inv;
  cur[ob + 3 * (size_t)L] += a3 * inv;
}

__global__ void k_concat2(const float* __restrict__ x1, const float* __restrict__ x2,
                          float* __restrict__ out, int L, int total) {
  int idx = blockIdx.x * 256 + threadIdx.x;
  if (idx >= total) return;
  int l = idx % L;
  int c = (idx / L) & 255;
  int b = idx / (L * 256);
  float v = (c < 128) ? x1[((size_t)b * 128 + c) * L + l]
                      : x2[((size_t)b * 128 + (c - 128)) * L + l];
  out[idx] = v;
}

__global__ void k_chandot(const float* __restrict__ X, const float* __restrict__ w,
                          float* __restrict__ out, int C, int L, int total) {
  int idx = blockIdx.x * 256 + threadIdx.x;
  if (idx >= total) return;
  int l = idx % L;
  int b = idx / L;
  const float* xb = X + (size_t)b * C * L + l;
  float s = 0.f;
  for (int j = 0; j < C; j++) s += xb[(size_t)j * L] * w[j];
  out[idx] = s;
}

// S build + fused row softmax (q = lane index -> wave shuffle softmax).
__global__ void k_cqSrow(const float* __restrict__ Ce, const float* __restrict__ Qe,
                         const float* __restrict__ s0, const float* __restrict__ s1,
                         const float* __restrict__ w4mlu, const float* __restrict__ cqb,
                         const float* __restrict__ qmask,
                         float* __restrict__ S, float* __restrict__ S1) {
  int idx = blockIdx.x * 256 + threadIdx.x;  // B*LC*LQ
  int q = idx & 63;
  int l = (idx >> 6) % LC_;
  int b = (idx >> 6) / LC_;
  const float* ce = Ce + (size_t)b * 256 * LC_ + l;
  const float* qe = Qe + (size_t)b * 256 * LQ_ + q;
  float acc = 0.f;
#pragma unroll 8
  for (int j = 0; j < 256; j++) acc += ce[(size_t)j * LC_] * w4mlu[j] * qe[(size_t)j * LQ_];
  float sv = acc + s0[b * LC_ + l] + s1[b * LQ_ + q] + cqb[0];
  S[idx] = sv;
  float mv = qmask[b * LQ_ + q];
  float v = sv * mv + (1.f - mv) * (-1e30f);
  float mx = v;
  for (int off = 32; off; off >>= 1) mx = fmaxf(mx, __shfl_xor(mx, off));
  float p = expf(v - mx);
  float s = p;
  for (int off = 32; off; off >>= 1) s += __shfl_xor(s, off);
  S1[idx] = p / s;
}

__global__ void k_softmax_col(const float* __restrict__ S, const float* __restrict__ cmask,
                              float* __restrict__ S2) {
  int idx = blockIdx.x * 256 + threadIdx.x;  // B*LQ threads
  if (idx >= B_ * LQ_) return;
  int q = idx % LQ_, b = idx / LQ_;
  const float* col = S + (size_t)b * LC_ * LQ_ + q;
  const float* mk = cmask + b * LC_;
  float mx = -INFINITY;
  for (int l = 0; l < LC_; l++) {
    float mv = mk[l];
    float v = col[(size_t)l * LQ_] * mv + (1.f - mv) * (-1e30f);
    mx = fmaxf(mx, v);
  }
  float s = 0.f;
  for (int l = 0; l < LC_; l++) {
    float mv = mk[l];
    float v = col[(size_t)l * LQ_] * mv + (1.f - mv) * (-1e30f);
    s += expf(v - mx);
  }
  float invs = 1.f / s;
  float* out = S2 + (size_t)b * LC_ * LQ_ + q;
  for (int l = 0; l < LC_; l++) {
    float mv = mk[l];
    float v = col[(size_t)l * LQ_] * mv + (1.f - mv) * (-1e30f);
    out[(size_t)l * LQ_] = expf(v - mx) * invs;
  }
}

// Y[b,j,q] = sum_l S2[b,l,q] * Ce[b,j,l]
__global__ void k_cqY(const float* __restrict__ S2, const float* __restrict__ Ce,
                      float* __restrict__ Y) {
  int idx = blockIdx.x * 256 + threadIdx.x;  // B*256*LQ
  if (idx >= B_ * 256 * LQ_) return;
  int q = idx & 63;
  int j = (idx >> 6) & 255;
  int b = idx >> 14;
  const float* s2 = S2 + (size_t)b * LC_ * LQ_ + q;
  const float* ce = Ce + ((size_t)b * 256 + j) * LC_;
  float acc = 0.f;
  for (int l = 0; l < LC_; l++) acc += s2[(size_t)l * LQ_] * ce[l];
  Y[idx] = acc;
}

// A[b,j,l] = sum_q S1[b,l,q] Qe[b,j,q];  Bt[b,j,l] = sum_q S1[b,l,q] Y[b,j,q]
__global__ __launch_bounds__(256) void k_cqAB(
    const float* __restrict__ S1, const float* __restrict__ Qe, const float* __restrict__ Y,
    float* __restrict__ A, float* __restrict__ Bt) {
  __shared__ float s1s[64][65];
  int l0 = blockIdx.x * 64;
  int b = blockIdx.z;
  int tid = threadIdx.x;
  for (int idx = tid; idx < 64 * 64; idx += 256) {
    int l = idx >> 6, q = idx & 63;
    s1s[l][q] = S1[((size_t)b * LC_ + l0 + l) * LQ_ + q];
  }
  __syncthreads();
  int ll = tid & 63, jj = tid >> 6;
  int j = blockIdx.y * 4 + jj;
  const float* qe = Qe + ((size_t)b * 256 + j) * LQ_;
  const float* yb = Y + ((size_t)b * 256 + j) * LQ_;
  float a = 0.f, bt = 0.f;
#pragma unroll 8
  for (int q = 0; q < 64; q++) {
    float sv = s1s[ll][q];
    a += sv * qe[q];
    bt += sv * yb[q];
  }
  A[((size_t)b * 256 + j) * LC_ + l0 + ll] = a;
  Bt[((size_t)b * 256 + j) * LC_ + l0 + ll] = bt;
}

// M0 = resizer_w [128,1280] @ X where X rows: [Ce; A; Ce*A; Ce*Bt; Ce]
__global__ __launch_bounds__(256) void k_resizer(
    const float* __restrict__ Ce, const float* __restrict__ A, const float* __restrict__ Bt,
    const float* __restrict__ w, float* __restrict__ y) {
  __shared__ float xs[64][64];
  __shared__ float wsT[64][64];
  int l0 = blockIdx.x * 64;
  int o0 = blockIdx.y * 64;
  int b = blockIdx.z;
  int tid = threadIdx.x;
  int tx = tid & 15, ty = tid >> 4;
  float acc[4][4] = {};
  for (int kt = 0; kt < 1280; kt += 64) {
    for (int idx = tid; idx < 64 * 64; idx += 256) {
      int i = idx >> 6, cc = idx & 63;
      int c = kt + i;
      int seg = c >> 8;
      int jch = c & 255;
      size_t p = ((size_t)b * 256 + jch) * LC_ + l0 + cc;
      float v;
      if (seg == 0 || seg == 4) v = Ce[p];
      else if (seg == 1) v = A[p];
      else if (seg == 2) v = Ce[p] * A[p];
      else v = Ce[p] * Bt[p];
      xs[i][cc] = v;
    }
    for (int idx = tid; idx < 64 * 64; idx += 256) {
      int oo = idx & 63, i = idx >> 6;
      wsT[i][oo] = w[(size_t)(o0 + oo) * 1280 + kt + i];
    }
    __syncthreads();
#pragma unroll 4
    for (int i = 0; i < 64; i++) {
      float4 xv = *(const float4*)&xs[i][tx * 4];
      float4 wv = *(const float4*)&wsT[i][ty * 4];
      acc[0][0] += wv.x * xv.x; acc[0][1] += wv.x * xv.y; acc[0][2] += wv.x * xv.z; acc[0][3] += wv.x * xv.w;
      acc[1][0] += wv.y * xv.x; acc[1][1] += wv.y * xv.y; acc[1][2] += wv.y * xv.z; acc[1][3] += wv.y * xv.w;
      acc[2][0] += wv.z * xv.x; acc[2][1] += wv.z * xv.y; acc[2][2] += wv.z * xv.z; acc[2][3] += wv.z * xv.w;
      acc[3][0] += wv.w * xv.x; acc[3][1] += wv.w * xv.y; acc[3][2] += wv.w * xv.z; acc[3][3] += wv.w * xv.w;
    }
    __syncthreads();
  }
  for (int j = 0; j < 4; j++) {
    int o = o0 + ty * 4 + j;
    *(float4*)&y[((size_t)b * D_ + o) * LC_ + l0 + tx * 4] =
        make_float4(acc[j][0], acc[j][1], acc[j][2], acc[j][3]);
  }
}

// ---------------------------------------------------------------- host side

struct BlkP {
  int n_conv, k;
  const float* lnc_g[4]; const float* lnc_b[4];
  const float* dw[4]; const float* pw[4]; const float* pw_b[4];
  const float* mem_w; const float* q_w;
  const float* ln1_g; const float* ln1_b;
  const float* ffn1_w; const float* ffn1_b;
  const float* ffn2_w; const float* ffn2_b;
  const float* ln2_g; const float* ln2_b;
};

static void conv_layer(hipStream_t st, const float* xin, float* cur, float* pbuf, float* t2,
                       const float* dwv, const float* pw, const float* pwb,
                       const float* g, const float* be, int K, int L, bool addpos) {
  dim3 gdw(L / 64, 1, B_), gg(L / 64, 2, B_);
  if (K == 7) {
    if (addpos) k_lndw<7, 1><<<gdw, 256, 0, st>>>(xin, t2, pbuf, dwv, g, be, L);
    else        k_lndw<7, 0><<<gdw, 256, 0, st>>>(xin, t2, nullptr, dwv, g, be, L);
  } else {
    if (addpos) k_lndw<5, 1><<<gdw, 256, 0, st>>>(xin, t2, pbuf, dwv, g, be, L);
    else        k_lndw<5, 0><<<gdw, 256, 0, st>>>(xin, t2, nullptr, dwv, g, be, L);
  }
  const float* res = addpos ? pbuf : cur;
  k_lngemm<0, 1, 1, 1><<<gg, 256, 0, st>>>(t2, pw, pwb, res, cur, nullptr, nullptr, L);
}

static void encoder_block(hipStream_t st, const float* xin, float* cur, float* pbuf, float* t2,
                          float* mkv, float* qpb, const float* mask, int L, const BlkP& P) {
  conv_layer(st, xin, cur, pbuf, t2, P.dw[0], P.pw[0], P.pw_b[0],
             P.lnc_g[0], P.lnc_b[0], P.k, L, true);
  for (int i = 1; i < P.n_conv; i++)
    conv_layer(st, cur, cur, pbuf, t2, P.dw[i], P.pw[i], P.pw_b[i],
               P.lnc_g[i], P.lnc_b[i], P.k, L, false);
  k_lnproj<<<dim3(L / 64, 6, B_), 256, 0, st>>>(cur, P.mem_w, P.q_w, mkv, qpb, P.ln1_g, P.ln1_b, L);
  k_attn<<<dim3(L / 64, H_, B_), 256, 0, st>>>(mkv, qpb, mask, cur, L);
  k_lngemm<1, 1, 0, 1><<<dim3(L / 64, 2, B_), 256, 0, st>>>(cur, P.ffn1_w, P.ffn1_b, nullptr, t2, P.ln2_g, P.ln2_b, L);
  k_lngemm<0, 0, 1, 1><<<dim3(L / 64, 2, B_), 256, 0, st>>>(t2, P.ffn2_w, P.ffn2_b, cur, cur, nullptr, nullptr, L);
}

extern "C" void kernel_launch(void* const* d_in, const int* in_sizes, int n_in,
                              void* d_out, int out_size, void* d_ws, size_t ws_size,
                              hipStream_t stream) {
  (void)in_sizes; (void)n_in; (void)out_size; (void)ws_size;
  const float* C        = (const float*)d_in[0];
  const float* Q        = (const float*)d_in[1];
  const float* maskC    = (const float*)d_in[2];
  const float* maskQ    = (const float*)d_in[3];
  const float* e_dw     = (const float*)d_in[4];
  const float* e_pw     = (const float*)d_in[5];
  const float* e_pw_b   = (const float*)d_in[6];
  const float* e_lnc_g  = (const float*)d_in[7];
  const float* e_lnc_b  = (const float*)d_in[8];
  const float* e_mem_w  = (const float*)d_in[9];
  const float* e_q_w    = (const float*)d_in[10];
  const float* e_ffn1_w = (const float*)d_in[11];
  const float* e_ffn1_b = (const float*)d_in[12];
  const float* e_ffn2_w = (const float*)d_in[13];
  const float* e_ffn2_b = (const float*)d_in[14];
  const float* e_ln1_g  = (const float*)d_in[15];
  const float* e_ln1_b  = (const float*)d_in[16];
  const float* e_ln2_g  = (const float*)d_in[17];
  const float* e_ln2_b  = (const float*)d_in[18];
  const float* w4C      = (const float*)d_in[19];
  const float* w4Q      = (const float*)d_in[20];
  const float* w4mlu    = (const float*)d_in[21];
  const float* cq_b     = (const float*)d_in[22];
  const float* resizer_w= (const float*)d_in[23];
  const float* m_dw     = (const float*)d_in[24];
  const float* m_pw     = (const float*)d_in[25];
  const float* m_pw_b   = (const float*)d_in[26];
  const float* m_lnc_g  = (const float*)d_in[27];
  const float* m_lnc_b  = (const float*)d_in[28];
  const float* m_mem_w  = (const float*)d_in[29];
  const float* m_q_w    = (const float*)d_in[30];
  const float* m_ffn1_w = (const float*)d_in[31];
  const float* m_ffn1_b = (const float*)d_in[32];
  const float* m_ffn2_w = (const float*)d_in[33];
  const float* m_ffn2_b = (const float*)d_in[34];
  const float* m_ln1_g  = (const float*)d_in[35];
  const float* m_ln1_b  = (const float*)d_in[36];
  const float* m_ln2_g  = (const float*)d_in[37];
  const float* m_ln2_b  = (const float*)d_in[38];

  float* ws = (float*)d_ws;
  const size_t SB = (size_t)B_ * D_ * LC_;  // 524288
  float* cur  = ws;
  float* pbuf = cur + SB;
  float* t2   = pbuf + SB;
  float* mkv  = t2 + SB;                 // 2*SB
  float* qpb  = mkv + 2 * SB;            // SB
  float* Ce   = qpb + SB;                // 2*SB
  float* Qe   = Ce + 2 * SB;             // B*256*LQ
  float* Sbuf = Qe + (size_t)B_ * 256 * LQ_;
  float* S1   = Sbuf + (size_t)B_ * LC_ * LQ_;
  float* S2   = S1 + (size_t)B_ * LC_ * LQ_;
  float* s0v  = S2 + (size_t)B_ * LC_ * LQ_;
  float* s1v  = s0v + (size_t)B_ * LC_;
  float* Yb   = s1v + (size_t)B_ * LQ_;
  float* Ab   = Yb + (size_t)B_ * 256 * LQ_;  // 2*SB
  float* Bb   = Ab + 2 * SB;                  // 2*SB
  float* Mb   = Bb + 2 * SB;                  // SB

  BlkP ep{};
  ep.n_conv = 4; ep.k = 7;
  for (int i = 0; i < 4; i++) {
    ep.lnc_g[i] = e_lnc_g + i * 128;
    ep.lnc_b[i] = e_lnc_b + i * 128;
    ep.dw[i]    = e_dw + i * 128 * 7;
    ep.pw[i]    = e_pw + (size_t)i * 128 * 128;
    ep.pw_b[i]  = e_pw_b + i * 128;
  }
  ep.mem_w = e_mem_w; ep.q_w = e_q_w;
  ep.ln1_g = e_ln1_g; ep.ln1_b = e_ln1_b;
  ep.ffn1_w = e_ffn1_w; ep.ffn1_b = e_ffn1_b;
  ep.ffn2_w = e_ffn2_w; ep.ffn2_b = e_ffn2_b;
  ep.ln2_g = e_ln2_g; ep.ln2_b = e_ln2_b;

  // ---- C encoder -> Ce ----
  encoder_block(stream, C, cur, pbuf, t2, mkv, qpb, maskC, LC_, ep);
  {
    int tot = B_ * 256 * LC_;
    k_concat2<<<(tot + 255) / 256, 256, 0, stream>>>(cur, C, Ce, LC_, tot);
  }
  // ---- Q encoder -> Qe ----
  encoder_block(stream, Q, cur, pbuf, t2, mkv, qpb, maskQ, LQ_, ep);
  {
    int tot = B_ * 256 * LQ_;
    k_concat2<<<(tot + 255) / 256, 256, 0, stream>>>(cur, Q, Qe, LQ_, tot);
  }

  // ---- CQ attention + resizer -> Mb (= M0) ----
  k_chandot<<<(B_ * LC_ + 255) / 256, 256, 0, stream>>>(Ce, w4C, s0v, 256, LC_, B_ * LC_);
  k_chandot<<<(B_ * LQ_ + 255) / 256, 256, 0, stream>>>(Qe, w4Q, s1v, 256, LQ_, B_ * LQ_);
  k_cqSrow<<<(B_ * LC_ * LQ_) / 256, 256, 0, stream>>>(Ce, Qe, s0v, s1v, w4mlu, cq_b, maskQ, Sbuf, S1);
  k_softmax_col<<<(B_ * LQ_ + 255) / 256, 256, 0, stream>>>(Sbuf, maskC, S2);
  k_cqY<<<(B_ * 256 * LQ_) / 256, 256, 0, stream>>>(S2, Ce, Yb);
  k_cqAB<<<dim3(LC_ / 64, 64, B_), 256, 0, stream>>>(S1, Qe, Yb, Ab, Bb);
  k_resizer<<<dim3(LC_ / 64, 2, B_), 256, 0, stream>>>(Ce, Ab, Bb, resizer_w, Mb);

  // ---- model encoder: 3 runs of 7 blocks ----
  float* out = (float*)d_out;
  const float* src = Mb;
  for (int r = 0; r < 3; r++) {
    for (int bi = 0; bi < 7; bi++) {
      BlkP mp{};
      mp.n_conv = 2; mp.k = 5;
      for (int ci = 0; ci < 2; ci++) {
        int pc = bi * 2 + ci;
        mp.lnc_g[ci] = m_lnc_g + pc * 128;
        mp.lnc_b[ci] = m_lnc_b + pc * 128;
        mp.dw[ci]    = m_dw + pc * 128 * 5;
        mp.pw[ci]    = m_pw + (size_t)pc * 128 * 128;
        mp.pw_b[ci]  = m_pw_b + pc * 128;
      }
      mp.mem_w  = m_mem_w + (size_t)bi * 256 * 128;
      mp.q_w    = m_q_w + (size_t)bi * 128 * 128;
      mp.ffn1_w = m_ffn1_w + (size_t)bi * 128 * 128;
      mp.ffn1_b = m_ffn1_b + bi * 128;
      mp.ffn2_w = m_ffn2_w + (size_t)bi * 128 * 128;
      mp.ffn2_b = m_ffn2_b + bi * 128;
      mp.ln1_g = m_ln1_g + bi * 128; mp.ln1_b = m_ln1_b + bi * 128;
      mp.ln2_g = m_ln2_g + bi * 128; mp.ln2_b = m_ln2_b + bi * 128;
      encoder_block(stream, (bi == 0) ? src : cur, cur, pbuf, t2, mkv, qpb, maskC, LC_, mp);
    }
    hipMemcpyAsync(out + (size_t)r * SB, cur, SB * sizeof(float),
                   hipMemcpyDeviceToDevice, stream);
    src = cur;
  }
}

// Round 3
// 4058.846 us; speedup vs baseline: 1.6326x; 1.4467x over previous
//
#include <hip/hip_runtime.h>
#include <math.h>

#define D_  128
#define B_  8
#define H_  8
#define LC_ 512
#define LQ_ 64

// ---------------------------------------------------------------- kernels

// Fully fused conv layer: [pos-add +] LN + depthwise conv + pointwise GEMM
// + bias + relu + residual.  Block = (32-col tile, 64-out half, b).
// Residual (= input [+pos]) kept in LDS. Reads x (with halo), writes yout.
// x and yout MUST be different buffers (halo race) -> host ping-pongs.
template <int KK, int ADDPOS>
__global__ __launch_bounds__(256) void k_convlayer(
    const float* __restrict__ x, float* __restrict__ yout,
    const float* __restrict__ dwv, const float* __restrict__ pw,
    const float* __restrict__ pwb, const float* __restrict__ g,
    const float* __restrict__ be, int L) {
  const int HALO = KK / 2;
  const int W = 32 + 2 * HALO;          // 38 (k=7) or 36 (k=5)
  __shared__ float raw[128 * 40];       // x(+pos) tile, later reused for dwconv out
  __shared__ float resid[128 * 36];     // residual copy (interior 32 cols)
  __shared__ float mu_s[40], rs_s[40];
  __shared__ float ps[160], ps2[160];
  int l0 = blockIdx.x * 32;
  int o0 = blockIdx.y * 64;
  int b = blockIdx.z;
  int tid = threadIdx.x;
  // stage x (+pos) incl. halo
  for (int idx = tid; idx < 128 * W; idx += 256) {
    int d = idx / W, c = idx - d * W;
    int l = l0 + c - HALO;
    float v = 0.f;
    if (l >= 0 && l < L) {
      v = x[((size_t)b * 128 + d) * L + l];
      if (ADDPOS) {
        int j = d & 63;
        float arg = (float)l * expf(-(float)j * 0.14619588f);  // log(1e4)/63
        v += (d < 64) ? sinf(arg) : cosf(arg);
      }
    }
    raw[d * 40 + c] = v;
  }
  __syncthreads();
  // per-column LN stats (over 128 channels)
  if (tid < 4 * W) {
    int c = tid % W, hh = tid / W;
    float s = 0.f, s2 = 0.f;
    for (int d = hh * 32; d < hh * 32 + 32; d++) {
      float v = raw[d * 40 + c];
      s += v; s2 += v * v;
    }
    ps[tid] = s; ps2[tid] = s2;
  }
  __syncthreads();
  if (tid < W) {
    float s = ps[tid] + ps[tid + W] + ps[tid + 2 * W] + ps[tid + 3 * W];
    float s2 = ps2[tid] + ps2[tid + W] + ps2[tid + 2 * W] + ps2[tid + 3 * W];
    float mu = s * (1.f / 128.f);
    float var = fmaxf(s2 * (1.f / 128.f) - mu * mu, 0.f);
    mu_s[tid] = mu; rs_s[tid] = rsqrtf(var + 1e-5f);
  }
  __syncthreads();
  // depthwise conv of LN(x) into registers; copy residual to LDS
  int cc0 = tid & 31;
  int dbase = tid >> 5;
  float dv[16];
#pragma unroll
  for (int k = 0; k < 16; k++) {
    int d = dbase + 8 * k;
    float gg = g[d], bb = be[d];
    const float* wr = dwv + d * KK;
    float acc = 0.f;
#pragma unroll
    for (int t = 0; t < KK; t++) {
      int c = cc0 + t;                  // raw col window [cc0, cc0+KK)
      int l = l0 + c - HALO;
      float lv = 0.f;
      if (l >= 0 && l < L)
        lv = (raw[d * 40 + c] - mu_s[c]) * rs_s[c] * gg + bb;
      acc += wr[t] * lv;
    }
    dv[k] = acc;
    resid[d * 36 + cc0] = raw[d * 40 + cc0 + HALO];
  }
  __syncthreads();
#pragma unroll
  for (int k = 0; k < 16; k++) {
    int d = dbase + 8 * k;
    raw[d * 40 + cc0] = dv[k];          // dwconv result, stride 40, cols 0..31
  }
  __syncthreads();
  // pointwise GEMM: 64 outs x 32 cols, weights streamed (contiguous rows)
  int tx = tid & 7, ty = tid >> 3;
  int o = o0 + ty * 2;
  float a0[4] = {0, 0, 0, 0}, a1[4] = {0, 0, 0, 0};
  const float* w0 = pw + (size_t)o * 128;
  const float* w1 = w0 + 128;
#pragma unroll 8
  for (int i = 0; i < 128; i++) {
    float4 xv = *(const float4*)&raw[i * 40 + tx * 4];
    float u0 = w0[i], u1 = w1[i];
    a0[0] += u0 * xv.x; a0[1] += u0 * xv.y; a0[2] += u0 * xv.z; a0[3] += u0 * xv.w;
    a1[0] += u1 * xv.x; a1[1] += u1 * xv.y; a1[2] += u1 * xv.z; a1[3] += u1 * xv.w;
  }
  float bb0 = pwb[o], bb1 = pwb[o + 1];
  float4 rr0 = *(const float4*)&resid[o * 36 + tx * 4];
  float4 rr1 = *(const float4*)&resid[(o + 1) * 36 + tx * 4];
  size_t base = ((size_t)b * 128 + o) * L + l0 + tx * 4;
  float4 v0, v1;
  v0.x = fmaxf(a0[0] + bb0, 0.f) + rr0.x; v0.y = fmaxf(a0[1] + bb0, 0.f) + rr0.y;
  v0.z = fmaxf(a0[2] + bb0, 0.f) + rr0.z; v0.w = fmaxf(a0[3] + bb0, 0.f) + rr0.w;
  v1.x = fmaxf(a1[0] + bb1, 0.f) + rr1.x; v1.y = fmaxf(a1[1] + bb1, 0.f) + rr1.y;
  v1.z = fmaxf(a1[2] + bb1, 0.f) + rr1.z; v1.w = fmaxf(a1[3] + bb1, 0.f) + rr1.w;
  *(float4*)&yout[base] = v0;
  *(float4*)&yout[base + L] = v1;
}

// Fused LN + both attention projections. grid (L/64, 6, B).
__global__ __launch_bounds__(256) void k_lnproj(
    const float* __restrict__ x, const float* __restrict__ memw, const float* __restrict__ qw,
    float* __restrict__ mkv, float* __restrict__ qp,
    const float* __restrict__ g, const float* __restrict__ be, int L) {
  __shared__ float xs[128 * 68];
  __shared__ float mu_s[64], rs_s[64];
  __shared__ float ps[256], ps2[256];
  int l0 = blockIdx.x * 64;
  int b = blockIdx.z;
  int yb = blockIdx.y;
  const float* w; float* out; int o0, O;
  if (yb < 4) { w = memw; out = mkv; o0 = yb * 64; O = 256; }
  else        { w = qw;   out = qp;  o0 = (yb - 4) * 64; O = 128; }
  int tid = threadIdx.x;
  for (int idx = tid; idx < 128 * 64; idx += 256) {
    int d = idx >> 6, c = idx & 63;
    xs[d * 68 + c] = x[((size_t)b * 128 + d) * L + l0 + c];
  }
  __syncthreads();
  {
    int c = tid & 63, qq = tid >> 6;
    float s = 0.f, s2 = 0.f;
    for (int d = qq * 32; d < qq * 32 + 32; d++) {
      float v = xs[d * 68 + c];
      s += v; s2 += v * v;
    }
    ps[tid] = s; ps2[tid] = s2;
  }
  __syncthreads();
  if (tid < 64) {
    float s = ps[tid] + ps[tid + 64] + ps[tid + 128] + ps[tid + 192];
    float s2 = ps2[tid] + ps2[tid + 64] + ps2[tid + 128] + ps2[tid + 192];
    float mu = s * (1.f / 128.f);
    float var = fmaxf(s2 * (1.f / 128.f) - mu * mu, 0.f);
    mu_s[tid] = mu; rs_s[tid] = rsqrtf(var + 1e-5f);
  }
  __syncthreads();
  for (int idx = tid; idx < 128 * 64; idx += 256) {
    int d = idx >> 6, c = idx & 63;
    xs[d * 68 + c] = (xs[d * 68 + c] - mu_s[c]) * rs_s[c] * g[d] + be[d];
  }
  __syncthreads();
  int tx = tid & 15, ty = tid >> 4;
  const float* r0 = w + (size_t)(o0 + ty * 4) * 128;
  const float* r1 = r0 + 128;
  const float* r2 = r0 + 256;
  const float* r3 = r0 + 384;
  float acc[4][4] = {};
#pragma unroll 8
  for (int i = 0; i < 128; i++) {
    float4 xv = *(const float4*)&xs[i * 68 + tx * 4];
    float u0 = r0[i], u1 = r1[i], u2 = r2[i], u3 = r3[i];
    acc[0][0] += u0 * xv.x; acc[0][1] += u0 * xv.y; acc[0][2] += u0 * xv.z; acc[0][3] += u0 * xv.w;
    acc[1][0] += u1 * xv.x; acc[1][1] += u1 * xv.y; acc[1][2] += u1 * xv.z; acc[1][3] += u1 * xv.w;
    acc[2][0] += u2 * xv.x; acc[2][1] += u2 * xv.y; acc[2][2] += u2 * xv.z; acc[2][3] += u2 * xv.w;
    acc[3][0] += u3 * xv.x; acc[3][1] += u3 * xv.y; acc[3][2] += u3 * xv.z; acc[3][3] += u3 * xv.w;
  }
  for (int j = 0; j < 4; j++) {
    int o = o0 + ty * 4 + j;
    *(float4*)&out[((size_t)b * O + o) * L + l0 + tx * 4] =
        make_float4(acc[j][0], acc[j][1], acc[j][2], acc[j][3]);
  }
}

// Fused LN + FFN1 + relu + FFN2 + bias + residual, in-place on cur.
// Block = (16-col tile, b). grid (L/16, 1, B).
__global__ __launch_bounds__(256) void k_ffn(
    float* __restrict__ cur, const float* __restrict__ w1, const float* __restrict__ b1,
    const float* __restrict__ w2, const float* __restrict__ b2,
    const float* __restrict__ g, const float* __restrict__ be, int L) {
  __shared__ float xs[128 * 20];
  __shared__ float mid[128 * 20];
  __shared__ float mu_s[16], rs_s[16];
  __shared__ float ps[256], ps2[256];
  int l0 = blockIdx.x * 16;
  int b = blockIdx.z;
  int tid = threadIdx.x;
  for (int idx = tid; idx < 128 * 16; idx += 256) {
    int d = idx >> 4, c = idx & 15;
    xs[d * 20 + c] = cur[((size_t)b * 128 + d) * L + l0 + c];
  }
  __syncthreads();
  {
    int c = tid & 15, hh = tid >> 4;
    float s = 0.f, s2 = 0.f;
    for (int d = hh * 8; d < hh * 8 + 8; d++) {
      float v = xs[d * 20 + c];
      s += v; s2 += v * v;
    }
    ps[tid] = s; ps2[tid] = s2;
  }
  __syncthreads();
  if (tid < 16) {
    float s = 0.f, s2 = 0.f;
    for (int hh = 0; hh < 16; hh++) { s += ps[hh * 16 + tid]; s2 += ps2[hh * 16 + tid]; }
    float mu = s * (1.f / 128.f);
    float var = fmaxf(s2 * (1.f / 128.f) - mu * mu, 0.f);
    mu_s[tid] = mu; rs_s[tid] = rsqrtf(var + 1e-5f);
  }
  __syncthreads();
  for (int idx = tid; idx < 128 * 16; idx += 256) {
    int d = idx >> 4, c = idx & 15;
    xs[d * 20 + c] = (xs[d * 20 + c] - mu_s[c]) * rs_s[c] * g[d] + be[d];
  }
  __syncthreads();
  int tx = tid & 3, ty = tid >> 2;
  int o = ty * 2;
  {
    float a0[4] = {0, 0, 0, 0}, a1[4] = {0, 0, 0, 0};
    const float* r0 = w1 + (size_t)o * 128;
    const float* r1 = r0 + 128;
#pragma unroll 8
    for (int i = 0; i < 128; i++) {
      float4 xv = *(const float4*)&xs[i * 20 + tx * 4];
      float u0 = r0[i], u1 = r1[i];
      a0[0] += u0 * xv.x; a0[1] += u0 * xv.y; a0[2] += u0 * xv.z; a0[3] += u0 * xv.w;
      a1[0] += u1 * xv.x; a1[1] += u1 * xv.y; a1[2] += u1 * xv.z; a1[3] += u1 * xv.w;
    }
    float bb0 = b1[o], bb1 = b1[o + 1];
    mid[o * 20 + tx * 4 + 0] = fmaxf(a0[0] + bb0, 0.f);
    mid[o * 20 + tx * 4 + 1] = fmaxf(a0[1] + bb0, 0.f);
    mid[o * 20 + tx * 4 + 2] = fmaxf(a0[2] + bb0, 0.f);
    mid[o * 20 + tx * 4 + 3] = fmaxf(a0[3] + bb0, 0.f);
    mid[(o + 1) * 20 + tx * 4 + 0] = fmaxf(a1[0] + bb1, 0.f);
    mid[(o + 1) * 20 + tx * 4 + 1] = fmaxf(a1[1] + bb1, 0.f);
    mid[(o + 1) * 20 + tx * 4 + 2] = fmaxf(a1[2] + bb1, 0.f);
    mid[(o + 1) * 20 + tx * 4 + 3] = fmaxf(a1[3] + bb1, 0.f);
  }
  __syncthreads();
  {
    float a0[4] = {0, 0, 0, 0}, a1[4] = {0, 0, 0, 0};
    const float* r0 = w2 + (size_t)o * 128;
    const float* r1 = r0 + 128;
#pragma unroll 8
    for (int i = 0; i < 128; i++) {
      float4 xv = *(const float4*)&mid[i * 20 + tx * 4];
      float u0 = r0[i], u1 = r1[i];
      a0[0] += u0 * xv.x; a0[1] += u0 * xv.y; a0[2] += u0 * xv.z; a0[3] += u0 * xv.w;
      a1[0] += u1 * xv.x; a1[1] += u1 * xv.y; a1[2] += u1 * xv.z; a1[3] += u1 * xv.w;
    }
    float bb0 = b2[o], bb1 = b2[o + 1];
    size_t base = ((size_t)b * 128 + o) * L + l0 + tx * 4;
    float4 res0 = *(const float4*)&cur[base];
    float4 res1 = *(const float4*)&cur[base + L];
    float4 v0, v1;
    v0.x = a0[0] + bb0 + res0.x; v0.y = a0[1] + bb0 + res0.y;
    v0.z = a0[2] + bb0 + res0.z; v0.w = a0[3] + bb0 + res0.w;
    v1.x = a1[0] + bb1 + res1.x; v1.y = a1[1] + bb1 + res1.y;
    v1.z = a1[2] + bb1 + res1.z; v1.w = a1[3] + bb1 + res1.w;
    *(float4*)&cur[base] = v0;
    *(float4*)&cur[base + L] = v1;
  }
}

// flash-style attention, residual fused: cur += softmax(QK^T)V ; grid (L/64, H, B)
__global__ __launch_bounds__(256) void k_attn(
    const float* __restrict__ memKV, const float* __restrict__ qp,
    const float* __restrict__ mask, float* __restrict__ cur, int L) {
  __shared__ float Qs[64][17];
  __shared__ float Ks[128][17];
  __shared__ float Vs[128][17];
  __shared__ float Ss[64][129];
  __shared__ float Ms[128];
  int q0 = blockIdx.x * 64;
  int h = blockIdx.y, b = blockIdx.z;
  int tid = threadIdx.x;
  const float* qb = qp + ((size_t)b * D_ + h * 16) * L;
  const float* kb = memKV + ((size_t)b * 256 + h * 16) * L;
  const float* vb = memKV + ((size_t)b * 256 + 128 + h * 16) * L;
  for (int idx = tid; idx < 64 * 16; idx += 256) {
    int e = idx >> 6, q = idx & 63;
    Qs[q][e] = qb[(size_t)e * L + q0 + q] * 0.25f;
  }
  int ql = tid & 63, g = tid >> 6;
  float m = -INFINITY, ssum = 0.f;
  float a0 = 0.f, a1 = 0.f, a2 = 0.f, a3 = 0.f;
  for (int k0 = 0; k0 < L; k0 += 128) {
    __syncthreads();
    for (int idx = tid; idx < 128 * 16; idx += 256) {
      int e = idx >> 7, k = idx & 127;
      bool ok = (k0 + k) < L;
      Ks[k][e] = ok ? kb[(size_t)e * L + k0 + k] : 0.f;
      Vs[k][e] = ok ? vb[(size_t)e * L + k0 + k] : 0.f;
    }
    if (tid < 128) Ms[tid] = ((k0 + tid) < L) ? mask[(size_t)b * L + k0 + tid] : 0.f;
    __syncthreads();
    for (int idx = tid; idx < 64 * 128; idx += 256) {
      int q = idx >> 7, k = idx & 127;
      float dot = 0.f;
#pragma unroll
      for (int e = 0; e < 16; e++) dot += Qs[q][e] * Ks[k][e];
      float mv = Ms[k];
      Ss[q][k] = dot * mv + (1.f - mv) * (-1e30f);
    }
    __syncthreads();
    float tmax = -INFINITY;
#pragma unroll 8
    for (int k = 0; k < 128; k++) tmax = fmaxf(tmax, Ss[ql][k]);
    float nm = fmaxf(m, tmax);
    float c = expf(m - nm);
    ssum *= c; a0 *= c; a1 *= c; a2 *= c; a3 *= c;
#pragma unroll 4
    for (int k = 0; k < 128; k++) {
      float p = expf(Ss[ql][k] - nm);
      ssum += p;
      a0 += p * Vs[k][g * 4 + 0];
      a1 += p * Vs[k][g * 4 + 1];
      a2 += p * Vs[k][g * 4 + 2];
      a3 += p * Vs[k][g * 4 + 3];
    }
    m = nm;
  }
  float inv = 1.f / ssum;
  size_t ob = ((size_t)b * D_ + h * 16 + g * 4) * L + q0 + ql;
  cur[ob] += a0 * inv;
  cur[ob + (size_t)L] += a1 * inv;
  cur[ob + 2 * (size_t)L] += a2 * inv;
  cur[ob + 3 * (size_t)L] += a3 * inv;
}

__global__ void k_concat2(const float* __restrict__ x1, const float* __restrict__ x2,
                          float* __restrict__ out, int L, int total) {
  int idx = blockIdx.x * 256 + threadIdx.x;
  if (idx >= total) return;
  int l = idx % L;
  int c = (idx / L) & 255;
  int b = idx / (L * 256);
  float v = (c < 128) ? x1[((size_t)b * 128 + c) * L + l]
                      : x2[((size_t)b * 128 + (c - 128)) * L + l];
  out[idx] = v;
}

__global__ void k_chandot(const float* __restrict__ X, const float* __restrict__ w,
                          float* __restrict__ out, int C, int L, int total) {
  int idx = blockIdx.x * 256 + threadIdx.x;
  if (idx >= total) return;
  int l = idx % L;
  int b = idx / L;
  const float* xb = X + (size_t)b * C * L + l;
  float s = 0.f;
  for (int j = 0; j < C; j++) s += xb[(size_t)j * L] * w[j];
  out[idx] = s;
}

// S build + fused row softmax (q = lane index -> wave shuffle softmax).
__global__ void k_cqSrow(const float* __restrict__ Ce, const float* __restrict__ Qe,
                         const float* __restrict__ s0, const float* __restrict__ s1,
                         const float* __restrict__ w4mlu, const float* __restrict__ cqb,
                         const float* __restrict__ qmask,
                         float* __restrict__ S, float* __restrict__ S1) {
  int idx = blockIdx.x * 256 + threadIdx.x;  // B*LC*LQ
  int q = idx & 63;
  int l = (idx >> 6) % LC_;
  int b = (idx >> 6) / LC_;
  const float* ce = Ce + (size_t)b * 256 * LC_ + l;
  const float* qe = Qe + (size_t)b * 256 * LQ_ + q;
  float acc = 0.f;
#pragma unroll 8
  for (int j = 0; j < 256; j++) acc += ce[(size_t)j * LC_] * w4mlu[j] * qe[(size_t)j * LQ_];
  float sv = acc + s0[b * LC_ + l] + s1[b * LQ_ + q] + cqb[0];
  S[idx] = sv;
  float mv = qmask[b * LQ_ + q];
  float v = sv * mv + (1.f - mv) * (-1e30f);
  float mx = v;
  for (int off = 32; off; off >>= 1) mx = fmaxf(mx, __shfl_xor(mx, off));
  float p = expf(v - mx);
  float s = p;
  for (int off = 32; off; off >>= 1) s += __shfl_xor(s, off);
  S1[idx] = p / s;
}

// column softmax over l (LC per column). grid (B*LQ) blocks, 256 threads.
__global__ __launch_bounds__(256) void k_softmax_col(
    const float* __restrict__ S, const float* __restrict__ cmask, float* __restrict__ S2) {
  int q = blockIdx.x & 63, b = blockIdx.x >> 6;
  int tid = threadIdx.x;
  __shared__ float redm[4], reds[4];
  const float* col = S + (size_t)b * LC_ * LQ_ + q;
  const float* mk = cmask + b * LC_;
  float vm[2];
#pragma unroll
  for (int k = 0; k < 2; k++) {
    int l = tid + 256 * k;
    float mv = mk[l];
    vm[k] = col[(size_t)l * LQ_] * mv + (1.f - mv) * (-1e30f);
  }
  float mx = fmaxf(vm[0], vm[1]);
  for (int off = 32; off; off >>= 1) mx = fmaxf(mx, __shfl_xor(mx, off));
  if ((tid & 63) == 0) redm[tid >> 6] = mx;
  __syncthreads();
  mx = fmaxf(fmaxf(redm[0], redm[1]), fmaxf(redm[2], redm[3]));
  float e0 = expf(vm[0] - mx), e1 = expf(vm[1] - mx);
  float s = e0 + e1;
  for (int off = 32; off; off >>= 1) s += __shfl_xor(s, off);
  if ((tid & 63) == 0) reds[tid >> 6] = s;
  __syncthreads();
  float invs = 1.f / (reds[0] + reds[1] + reds[2] + reds[3]);
  float* out = S2 + (size_t)b * LC_ * LQ_ + q;
  out[(size_t)tid * LQ_] = e0 * invs;
  out[(size_t)(tid + 256) * LQ_] = e1 * invs;
}

// Y[b,j,q] = sum_l S2[b,l,q] * Ce[b,j,l]
__global__ void k_cqY(const float* __restrict__ S2, const float* __restrict__ Ce,
                      float* __restrict__ Y) {
  int idx = blockIdx.x * 256 + threadIdx.x;  // B*256*LQ
  if (idx >= B_ * 256 * LQ_) return;
  int q = idx & 63;
  int j = (idx >> 6) & 255;
  int b = idx >> 14;
  const float* s2 = S2 + (size_t)b * LC_ * LQ_ + q;
  const float* ce = Ce + ((size_t)b * 256 + j) * LC_;
  float acc = 0.f;
  for (int l = 0; l < LC_; l++) acc += s2[(size_t)l * LQ_] * ce[l];
  Y[idx] = acc;
}

// A[b,j,l] = sum_q S1[b,l,q] Qe[b,j,q];  Bt[b,j,l] = sum_q S1[b,l,q] Y[b,j,q]
__global__ __launch_bounds__(256) void k_cqAB(
    const float* __restrict__ S1, const float* __restrict__ Qe, const float* __restrict__ Y,
    float* __restrict__ A, float* __restrict__ Bt) {
  __shared__ float s1s[64][65];
  int l0 = blockIdx.x * 64;
  int b = blockIdx.z;
  int tid = threadIdx.x;
  for (int idx = tid; idx < 64 * 64; idx += 256) {
    int l = idx >> 6, q = idx & 63;
    s1s[l][q] = S1[((size_t)b * LC_ + l0 + l) * LQ_ + q];
  }
  __syncthreads();
  int ll = tid & 63, jj = tid >> 6;
  int j = blockIdx.y * 4 + jj;
  const float* qe = Qe + ((size_t)b * 256 + j) * LQ_;
  const float* yb = Y + ((size_t)b * 256 + j) * LQ_;
  float a = 0.f, bt = 0.f;
#pragma unroll 8
  for (int q = 0; q < 64; q++) {
    float sv = s1s[ll][q];
    a += sv * qe[q];
    bt += sv * yb[q];
  }
  A[((size_t)b * 256 + j) * LC_ + l0 + ll] = a;
  Bt[((size_t)b * 256 + j) * LC_ + l0 + ll] = bt;
}

// M0 = resizer_w [128,1280] @ X where X rows: [Ce; A; Ce*A; Ce*Bt; Ce]
// grid (LC/32, 2, B); weights streamed as contiguous rows.
__global__ __launch_bounds__(256) void k_resizer(
    const float* __restrict__ Ce, const float* __restrict__ A, const float* __restrict__ Bt,
    const float* __restrict__ w, float* __restrict__ y) {
  __shared__ float xs[64 * 36];
  int l0 = blockIdx.x * 32;
  int o0 = blockIdx.y * 64;
  int b = blockIdx.z;
  int tid = threadIdx.x;
  int tx = tid & 7, ty = tid >> 3;
  int o = o0 + ty * 2;
  float a0[4] = {0, 0, 0, 0}, a1[4] = {0, 0, 0, 0};
  const float* w0 = w + (size_t)o * 1280;
  const float* w1 = w0 + 1280;
  for (int kt = 0; kt < 1280; kt += 64) {
    __syncthreads();
    for (int idx = tid; idx < 64 * 32; idx += 256) {
      int i = idx >> 5, cc = idx & 31;
      int ch = kt + i;
      int seg = ch >> 8;
      int j = ch & 255;
      size_t p = ((size_t)b * 256 + j) * LC_ + l0 + cc;
      float v;
      if (seg == 0 || seg == 4) v = Ce[p];
      else if (seg == 1) v = A[p];
      else if (seg == 2) v = Ce[p] * A[p];
      else v = Ce[p] * Bt[p];
      xs[i * 36 + cc] = v;
    }
    __syncthreads();
#pragma unroll 8
    for (int i = 0; i < 64; i++) {
      float4 xv = *(const float4*)&xs[i * 36 + tx * 4];
      float u0 = w0[kt + i], u1 = w1[kt + i];
      a0[0] += u0 * xv.x; a0[1] += u0 * xv.y; a0[2] += u0 * xv.z; a0[3] += u0 * xv.w;
      a1[0] += u1 * xv.x; a1[1] += u1 * xv.y; a1[2] += u1 * xv.z; a1[3] += u1 * xv.w;
    }
  }
  size_t base = ((size_t)b * D_ + o) * LC_ + l0 + tx * 4;
  *(float4*)&y[base] = make_float4(a0[0], a0[1], a0[2], a0[3]);
  *(float4*)&y[base + LC_] = make_float4(a1[0], a1[1], a1[2], a1[3]);
}

// ---------------------------------------------------------------- host side

struct BlkP {
  int n_conv, k;
  const float* lnc_g[4]; const float* lnc_b[4];
  const float* dw[4]; const float* pw[4]; const float* pw_b[4];
  const float* mem_w; const float* q_w;
  const float* ln1_g; const float* ln1_b;
  const float* ffn1_w; const float* ffn1_b;
  const float* ffn2_w; const float* ffn2_b;
  const float* ln2_g; const float* ln2_b;
};

static void encoder_block(hipStream_t st, const float* xin, float* cur, float* aux,
                          float* mkv, float* qpb, const float* mask, int L, const BlkP& P) {
  dim3 gc(L / 32, 2, B_);
  const float* in = xin;
  for (int i = 0; i < P.n_conv; i++) {
    float* ob = (i % 2 == 0) ? aux : cur;   // n_conv even -> ends in cur
    if (P.k == 7) {
      if (i == 0) k_convlayer<7, 1><<<gc, 256, 0, st>>>(in, ob, P.dw[i], P.pw[i], P.pw_b[i], P.lnc_g[i], P.lnc_b[i], L);
      else        k_convlayer<7, 0><<<gc, 256, 0, st>>>(in, ob, P.dw[i], P.pw[i], P.pw_b[i], P.lnc_g[i], P.lnc_b[i], L);
    } else {
      if (i == 0) k_convlayer<5, 1><<<gc, 256, 0, st>>>(in, ob, P.dw[i], P.pw[i], P.pw_b[i], P.lnc_g[i], P.lnc_b[i], L);
      else        k_convlayer<5, 0><<<gc, 256, 0, st>>>(in, ob, P.dw[i], P.pw[i], P.pw_b[i], P.lnc_g[i], P.lnc_b[i], L);
    }
    in = ob;
  }
  k_lnproj<<<dim3(L / 64, 6, B_), 256, 0, st>>>(cur, P.mem_w, P.q_w, mkv, qpb, P.ln1_g, P.ln1_b, L);
  k_attn<<<dim3(L / 64, H_, B_), 256, 0, st>>>(mkv, qpb, mask, cur, L);
  k_ffn<<<dim3(L / 16, 1, B_), 256, 0, st>>>(cur, P.ffn1_w, P.ffn1_b, P.ffn2_w, P.ffn2_b, P.ln2_g, P.ln2_b, L);
}

extern "C" void kernel_launch(void* const* d_in, const int* in_sizes, int n_in,
                              void* d_out, int out_size, void* d_ws, size_t ws_size,
                              hipStream_t stream) {
  (void)in_sizes; (void)n_in; (void)out_size; (void)ws_size;
  const float* C        = (const float*)d_in[0];
  const float* Q        = (const float*)d_in[1];
  const float* maskC    = (const float*)d_in[2];
  const float* maskQ    = (const float*)d_in[3];
  const float* e_dw     = (const float*)d_in[4];
  const float* e_pw     = (const float*)d_in[5];
  const float* e_pw_b   = (const float*)d_in[6];
  const float* e_lnc_g  = (const float*)d_in[7];
  const float* e_lnc_b  = (const float*)d_in[8];
  const float* e_mem_w  = (const float*)d_in[9];
  const float* e_q_w    = (const float*)d_in[10];
  const float* e_ffn1_w = (const float*)d_in[11];
  const float* e_ffn1_b = (const float*)d_in[12];
  const float* e_ffn2_w = (const float*)d_in[13];
  const float* e_ffn2_b = (const float*)d_in[14];
  const float* e_ln1_g  = (const float*)d_in[15];
  const float* e_ln1_b  = (const float*)d_in[16];
  const float* e_ln2_g  = (const float*)d_in[17];
  const float* e_ln2_b  = (const float*)d_in[18];
  const float* w4C      = (const float*)d_in[19];
  const float* w4Q      = (const float*)d_in[20];
  const float* w4mlu    = (const float*)d_in[21];
  const float* cq_b     = (const float*)d_in[22];
  const float* resizer_w= (const float*)d_in[23];
  const float* m_dw     = (const float*)d_in[24];
  const float* m_pw     = (const float*)d_in[25];
  const float* m_pw_b   = (const float*)d_in[26];
  const float* m_lnc_g  = (const float*)d_in[27];
  const float* m_lnc_b  = (const float*)d_in[28];
  const float* m_mem_w  = (const float*)d_in[29];
  const float* m_q_w    = (const float*)d_in[30];
  const float* m_ffn1_w = (const float*)d_in[31];
  const float* m_ffn1_b = (const float*)d_in[32];
  const float* m_ffn2_w = (const float*)d_in[33];
  const float* m_ffn2_b = (const float*)d_in[34];
  const float* m_ln1_g  = (const float*)d_in[35];
  const float* m_ln1_b  = (const float*)d_in[36];
  const float* m_ln2_g  = (const float*)d_in[37];
  const float* m_ln2_b  = (const float*)d_in[38];

  float* ws = (float*)d_ws;
  const size_t SB = (size_t)B_ * D_ * LC_;  // 524288
  float* cur  = ws;
  float* aux  = cur + SB;
  float* mkv  = aux + SB;                // 2*SB
  float* qpb  = mkv + 2 * SB;            // SB
  float* Ce   = qpb + SB;                // 2*SB
  float* Qe   = Ce + 2 * SB;             // B*256*LQ
  float* Sbuf = Qe + (size_t)B_ * 256 * LQ_;
  float* S1   = Sbuf + (size_t)B_ * LC_ * LQ_;
  float* S2   = S1 + (size_t)B_ * LC_ * LQ_;
  float* s0v  = S2 + (size_t)B_ * LC_ * LQ_;
  float* s1v  = s0v + (size_t)B_ * LC_;
  float* Yb   = s1v + (size_t)B_ * LQ_;
  float* Ab   = Yb + (size_t)B_ * 256 * LQ_;  // 2*SB
  float* Bb   = Ab + 2 * SB;                  // 2*SB
  float* Mb   = Bb + 2 * SB;                  // SB

  BlkP ep{};
  ep.n_conv = 4; ep.k = 7;
  for (int i = 0; i < 4; i++) {
    ep.lnc_g[i] = e_lnc_g + i * 128;
    ep.lnc_b[i] = e_lnc_b + i * 128;
    ep.dw[i]    = e_dw + i * 128 * 7;
    ep.pw[i]    = e_pw + (size_t)i * 128 * 128;
    ep.pw_b[i]  = e_pw_b + i * 128;
  }
  ep.mem_w = e_mem_w; ep.q_w = e_q_w;
  ep.ln1_g = e_ln1_g; ep.ln1_b = e_ln1_b;
  ep.ffn1_w = e_ffn1_w; ep.ffn1_b = e_ffn1_b;
  ep.ffn2_w = e_ffn2_w; ep.ffn2_b = e_ffn2_b;
  ep.ln2_g = e_ln2_g; ep.ln2_b = e_ln2_b;

  // ---- C encoder -> Ce ----
  encoder_block(stream, C, cur, aux, mkv, qpb, maskC, LC_, ep);
  {
    int tot = B_ * 256 * LC_;
    k_concat2<<<(tot + 255) / 256, 256, 0, stream>>>(cur, C, Ce, LC_, tot);
  }
  // ---- Q encoder -> Qe ----
  encoder_block(stream, Q, cur, aux, mkv, qpb, maskQ, LQ_, ep);
  {
    int tot = B_ * 256 * LQ_;
    k_concat2<<<(tot + 255) / 256, 256, 0, stream>>>(cur, Q, Qe, LQ_, tot);
  }

  // ---- CQ attention + resizer -> Mb (= M0) ----
  k_chandot<<<(B_ * LC_ + 255) / 256, 256, 0, stream>>>(Ce, w4C, s0v, 256, LC_, B_ * LC_);
  k_chandot<<<(B_ * LQ_ + 255) / 256, 256, 0, stream>>>(Qe, w4Q, s1v, 256, LQ_, B_ * LQ_);
  k_cqSrow<<<(B_ * LC_ * LQ_) / 256, 256, 0, stream>>>(Ce, Qe, s0v, s1v, w4mlu, cq_b, maskQ, Sbuf, S1);
  k_softmax_col<<<B_ * LQ_, 256, 0, stream>>>(Sbuf, maskC, S2);
  k_cqY<<<(B_ * 256 * LQ_) / 256, 256, 0, stream>>>(S2, Ce, Yb);
  k_cqAB<<<dim3(LC_ / 64, 64, B_), 256, 0, stream>>>(S1, Qe, Yb, Ab, Bb);
  k_resizer<<<dim3(LC_ / 32, 2, B_), 256, 0, stream>>>(Ce, Ab, Bb, resizer_w, Mb);

  // ---- model encoder: 3 runs of 7 blocks ----
  float* out = (float*)d_out;
  const float* src = Mb;
  for (int r = 0; r < 3; r++) {
    for (int bi = 0; bi < 7; bi++) {
      BlkP mp{};
      mp.n_conv = 2; mp.k = 5;
      for (int ci = 0; ci < 2; ci++) {
        int pc = bi * 2 + ci;
        mp.lnc_g[ci] = m_lnc_g + pc * 128;
        mp.lnc_b[ci] = m_lnc_b + pc * 128;
        mp.dw[ci]    = m_dw + pc * 128 * 5;
        mp.pw[ci]    = m_pw + (size_t)pc * 128 * 128;
        mp.pw_b[ci]  = m_pw_b + pc * 128;
      }
      mp.mem_w  = m_mem_w + (size_t)bi * 256 * 128;
      mp.q_w    = m_q_w + (size_t)bi * 128 * 128;
      mp.ffn1_w = m_ffn1_w + (size_t)bi * 128 * 128;
      mp.ffn1_b = m_ffn1_b + bi * 128;
      mp.ffn2_w = m_ffn2_w + (size_t)bi * 128 * 128;
      mp.ffn2_b = m_ffn2_b + bi * 128;
      mp.ln1_g = m_ln1_g + bi * 128; mp.ln1_b = m_ln1_b + bi * 128;
      mp.ln2_g = m_ln2_g + bi * 128; mp.ln2_b = m_ln2_b + bi * 128;
      encoder_block(stream, (bi == 0) ? src : cur, cur, aux, mkv, qpb, maskC, LC_, mp);
    }
    hipMemcpyAsync(out + (size_t)r * SB, cur, SB * sizeof(float),
                   hipMemcpyDeviceToDevice, stream);
    src = cur;
  }
}

// Round 4
// 2676.214 us; speedup vs baseline: 2.4760x; 1.5166x over previous
//
#include <hip/hip_runtime.h>
#include <math.h>

#define D_  128
#define B_  8
#define H_  8
#define LC_ 512
#define LQ_ 64

typedef float f32x4 __attribute__((ext_vector_type(4)));
typedef short bf16x8 __attribute__((ext_vector_type(8)));

__device__ inline short bfr(float x) {
  unsigned u = __float_as_uint(x);
  u += 0x7fff + ((u >> 16) & 1);
  return (short)(u >> 16);
}

// ---------------------------------------------------------------- kernels

// Fully fused conv layer: [pos-add +] LN + depthwise conv + pointwise GEMM
// + bias + relu + residual.  Block = (32-col tile, 64-out half, b).
template <int KK, int ADDPOS>
__global__ __launch_bounds__(256) void k_convlayer(
    const float* __restrict__ x, float* __restrict__ yout,
    const float* __restrict__ dwv, const float* __restrict__ pw,
    const float* __restrict__ pwb, const float* __restrict__ g,
    const float* __restrict__ be, int L) {
  const int HALO = KK / 2;
  const int W = 32 + 2 * HALO;
  __shared__ float raw[128 * 40];
  __shared__ float resid[128 * 36];
  __shared__ float mu_s[40], rs_s[40];
  __shared__ float ps[160], ps2[160];
  int l0 = blockIdx.x * 32;
  int o0 = blockIdx.y * 64;
  int b = blockIdx.z;
  int tid = threadIdx.x;
  for (int idx = tid; idx < 128 * W; idx += 256) {
    int d = idx / W, c = idx - d * W;
    int l = l0 + c - HALO;
    float v = 0.f;
    if (l >= 0 && l < L) {
      v = x[((size_t)b * 128 + d) * L + l];
      if (ADDPOS) {
        int j = d & 63;
        float arg = (float)l * expf(-(float)j * 0.14619588f);
        v += (d < 64) ? sinf(arg) : cosf(arg);
      }
    }
    raw[d * 40 + c] = v;
  }
  __syncthreads();
  if (tid < 4 * W) {
    int c = tid % W, hh = tid / W;
    float s = 0.f, s2 = 0.f;
    for (int d = hh * 32; d < hh * 32 + 32; d++) {
      float v = raw[d * 40 + c];
      s += v; s2 += v * v;
    }
    ps[tid] = s; ps2[tid] = s2;
  }
  __syncthreads();
  if (tid < W) {
    float s = ps[tid] + ps[tid + W] + ps[tid + 2 * W] + ps[tid + 3 * W];
    float s2 = ps2[tid] + ps2[tid + W] + ps2[tid + 2 * W] + ps2[tid + 3 * W];
    float mu = s * (1.f / 128.f);
    float var = fmaxf(s2 * (1.f / 128.f) - mu * mu, 0.f);
    mu_s[tid] = mu; rs_s[tid] = rsqrtf(var + 1e-5f);
  }
  __syncthreads();
  int cc0 = tid & 31;
  int dbase = tid >> 5;
  float dv[16];
#pragma unroll
  for (int k = 0; k < 16; k++) {
    int d = dbase + 8 * k;
    float gg = g[d], bb = be[d];
    const float* wr = dwv + d * KK;
    float acc = 0.f;
#pragma unroll
    for (int t = 0; t < KK; t++) {
      int c = cc0 + t;
      int l = l0 + c - HALO;
      float lv = 0.f;
      if (l >= 0 && l < L)
        lv = (raw[d * 40 + c] - mu_s[c]) * rs_s[c] * gg + bb;
      acc += wr[t] * lv;
    }
    dv[k] = acc;
    resid[d * 36 + cc0] = raw[d * 40 + cc0 + HALO];
  }
  __syncthreads();
#pragma unroll
  for (int k = 0; k < 16; k++) {
    int d = dbase + 8 * k;
    raw[d * 40 + cc0] = dv[k];
  }
  __syncthreads();
  int tx = tid & 7, ty = tid >> 3;
  int o = o0 + ty * 2;
  float a0[4] = {0, 0, 0, 0}, a1[4] = {0, 0, 0, 0};
  const float* w0 = pw + (size_t)o * 128;
  const float* w1 = w0 + 128;
#pragma unroll 8
  for (int i = 0; i < 128; i++) {
    float4 xv = *(const float4*)&raw[i * 40 + tx * 4];
    float u0 = w0[i], u1 = w1[i];
    a0[0] += u0 * xv.x; a0[1] += u0 * xv.y; a0[2] += u0 * xv.z; a0[3] += u0 * xv.w;
    a1[0] += u1 * xv.x; a1[1] += u1 * xv.y; a1[2] += u1 * xv.z; a1[3] += u1 * xv.w;
  }
  float bb0 = pwb[o], bb1 = pwb[o + 1];
  float4 rr0 = *(const float4*)&resid[o * 36 + tx * 4];
  float4 rr1 = *(const float4*)&resid[(o + 1) * 36 + tx * 4];
  size_t base = ((size_t)b * 128 + o) * L + l0 + tx * 4;
  float4 v0, v1;
  v0.x = fmaxf(a0[0] + bb0, 0.f) + rr0.x; v0.y = fmaxf(a0[1] + bb0, 0.f) + rr0.y;
  v0.z = fmaxf(a0[2] + bb0, 0.f) + rr0.z; v0.w = fmaxf(a0[3] + bb0, 0.f) + rr0.w;
  v1.x = fmaxf(a1[0] + bb1, 0.f) + rr1.x; v1.y = fmaxf(a1[1] + bb1, 0.f) + rr1.y;
  v1.z = fmaxf(a1[2] + bb1, 0.f) + rr1.z; v1.w = fmaxf(a1[3] + bb1, 0.f) + rr1.w;
  *(float4*)&yout[base] = v0;
  *(float4*)&yout[base + L] = v1;
}

// Fused LN + both attention projections. grid (L/64, 6, B).
__global__ __launch_bounds__(256) void k_lnproj(
    const float* __restrict__ x, const float* __restrict__ memw, const float* __restrict__ qw,
    float* __restrict__ mkv, float* __restrict__ qp,
    const float* __restrict__ g, const float* __restrict__ be, int L) {
  __shared__ float xs[128 * 68];
  __shared__ float mu_s[64], rs_s[64];
  __shared__ float ps[256], ps2[256];
  int l0 = blockIdx.x * 64;
  int b = blockIdx.z;
  int yb = blockIdx.y;
  const float* w; float* out; int o0, O;
  if (yb < 4) { w = memw; out = mkv; o0 = yb * 64; O = 256; }
  else        { w = qw;   out = qp;  o0 = (yb - 4) * 64; O = 128; }
  int tid = threadIdx.x;
  for (int idx = tid; idx < 128 * 64; idx += 256) {
    int d = idx >> 6, c = idx & 63;
    xs[d * 68 + c] = x[((size_t)b * 128 + d) * L + l0 + c];
  }
  __syncthreads();
  {
    int c = tid & 63, qq = tid >> 6;
    float s = 0.f, s2 = 0.f;
    for (int d = qq * 32; d < qq * 32 + 32; d++) {
      float v = xs[d * 68 + c];
      s += v; s2 += v * v;
    }
    ps[tid] = s; ps2[tid] = s2;
  }
  __syncthreads();
  if (tid < 64) {
    float s = ps[tid] + ps[tid + 64] + ps[tid + 128] + ps[tid + 192];
    float s2 = ps2[tid] + ps2[tid + 64] + ps2[tid + 128] + ps2[tid + 192];
    float mu = s * (1.f / 128.f);
    float var = fmaxf(s2 * (1.f / 128.f) - mu * mu, 0.f);
    mu_s[tid] = mu; rs_s[tid] = rsqrtf(var + 1e-5f);
  }
  __syncthreads();
  for (int idx = tid; idx < 128 * 64; idx += 256) {
    int d = idx >> 6, c = idx & 63;
    xs[d * 68 + c] = (xs[d * 68 + c] - mu_s[c]) * rs_s[c] * g[d] + be[d];
  }
  __syncthreads();
  int tx = tid & 15, ty = tid >> 4;
  const float* r0 = w + (size_t)(o0 + ty * 4) * 128;
  const float* r1 = r0 + 128;
  const float* r2 = r0 + 256;
  const float* r3 = r0 + 384;
  float acc[4][4] = {};
#pragma unroll 8
  for (int i = 0; i < 128; i++) {
    float4 xv = *(const float4*)&xs[i * 68 + tx * 4];
    float u0 = r0[i], u1 = r1[i], u2 = r2[i], u3 = r3[i];
    acc[0][0] += u0 * xv.x; acc[0][1] += u0 * xv.y; acc[0][2] += u0 * xv.z; acc[0][3] += u0 * xv.w;
    acc[1][0] += u1 * xv.x; acc[1][1] += u1 * xv.y; acc[1][2] += u1 * xv.z; acc[1][3] += u1 * xv.w;
    acc[2][0] += u2 * xv.x; acc[2][1] += u2 * xv.y; acc[2][2] += u2 * xv.z; acc[2][3] += u2 * xv.w;
    acc[3][0] += u3 * xv.x; acc[3][1] += u3 * xv.y; acc[3][2] += u3 * xv.z; acc[3][3] += u3 * xv.w;
  }
  for (int j = 0; j < 4; j++) {
    int o = o0 + ty * 4 + j;
    *(float4*)&out[((size_t)b * O + o) * L + l0 + tx * 4] =
        make_float4(acc[j][0], acc[j][1], acc[j][2], acc[j][3]);
  }
}

// Fused LN + FFN1 + relu + FFN2 + bias + residual, in-place on cur.
__global__ __launch_bounds__(256) void k_ffn(
    float* __restrict__ cur, const float* __restrict__ w1, const float* __restrict__ b1,
    const float* __restrict__ w2, const float* __restrict__ b2,
    const float* __restrict__ g, const float* __restrict__ be, int L) {
  __shared__ float xs[128 * 20];
  __shared__ float mid[128 * 20];
  __shared__ float mu_s[16], rs_s[16];
  __shared__ float ps[256], ps2[256];
  int l0 = blockIdx.x * 16;
  int b = blockIdx.z;
  int tid = threadIdx.x;
  for (int idx = tid; idx < 128 * 16; idx += 256) {
    int d = idx >> 4, c = idx & 15;
    xs[d * 20 + c] = cur[((size_t)b * 128 + d) * L + l0 + c];
  }
  __syncthreads();
  {
    int c = tid & 15, hh = tid >> 4;
    float s = 0.f, s2 = 0.f;
    for (int d = hh * 8; d < hh * 8 + 8; d++) {
      float v = xs[d * 20 + c];
      s += v; s2 += v * v;
    }
    ps[tid] = s; ps2[tid] = s2;
  }
  __syncthreads();
  if (tid < 16) {
    float s = 0.f, s2 = 0.f;
    for (int hh = 0; hh < 16; hh++) { s += ps[hh * 16 + tid]; s2 += ps2[hh * 16 + tid]; }
    float mu = s * (1.f / 128.f);
    float var = fmaxf(s2 * (1.f / 128.f) - mu * mu, 0.f);
    mu_s[tid] = mu; rs_s[tid] = rsqrtf(var + 1e-5f);
  }
  __syncthreads();
  for (int idx = tid; idx < 128 * 16; idx += 256) {
    int d = idx >> 4, c = idx & 15;
    xs[d * 20 + c] = (xs[d * 20 + c] - mu_s[c]) * rs_s[c] * g[d] + be[d];
  }
  __syncthreads();
  int tx = tid & 3, ty = tid >> 2;
  int o = ty * 2;
  {
    float a0[4] = {0, 0, 0, 0}, a1[4] = {0, 0, 0, 0};
    const float* r0 = w1 + (size_t)o * 128;
    const float* r1 = r0 + 128;
#pragma unroll 8
    for (int i = 0; i < 128; i++) {
      float4 xv = *(const float4*)&xs[i * 20 + tx * 4];
      float u0 = r0[i], u1 = r1[i];
      a0[0] += u0 * xv.x; a0[1] += u0 * xv.y; a0[2] += u0 * xv.z; a0[3] += u0 * xv.w;
      a1[0] += u1 * xv.x; a1[1] += u1 * xv.y; a1[2] += u1 * xv.z; a1[3] += u1 * xv.w;
    }
    float bb0 = b1[o], bb1 = b1[o + 1];
    mid[o * 20 + tx * 4 + 0] = fmaxf(a0[0] + bb0, 0.f);
    mid[o * 20 + tx * 4 + 1] = fmaxf(a0[1] + bb0, 0.f);
    mid[o * 20 + tx * 4 + 2] = fmaxf(a0[2] + bb0, 0.f);
    mid[o * 20 + tx * 4 + 3] = fmaxf(a0[3] + bb0, 0.f);
    mid[(o + 1) * 20 + tx * 4 + 0] = fmaxf(a1[0] + bb1, 0.f);
    mid[(o + 1) * 20 + tx * 4 + 1] = fmaxf(a1[1] + bb1, 0.f);
    mid[(o + 1) * 20 + tx * 4 + 2] = fmaxf(a1[2] + bb1, 0.f);
    mid[(o + 1) * 20 + tx * 4 + 3] = fmaxf(a1[3] + bb1, 0.f);
  }
  __syncthreads();
  {
    float a0[4] = {0, 0, 0, 0}, a1[4] = {0, 0, 0, 0};
    const float* r0 = w2 + (size_t)o * 128;
    const float* r1 = r0 + 128;
#pragma unroll 8
    for (int i = 0; i < 128; i++) {
      float4 xv = *(const float4*)&mid[i * 20 + tx * 4];
      float u0 = r0[i], u1 = r1[i];
      a0[0] += u0 * xv.x; a0[1] += u0 * xv.y; a0[2] += u0 * xv.z; a0[3] += u0 * xv.w;
      a1[0] += u1 * xv.x; a1[1] += u1 * xv.y; a1[2] += u1 * xv.z; a1[3] += u1 * xv.w;
    }
    float bb0 = b2[o], bb1 = b2[o + 1];
    size_t base = ((size_t)b * 128 + o) * L + l0 + tx * 4;
    float4 res0 = *(const float4*)&cur[base];
    float4 res1 = *(const float4*)&cur[base + L];
    float4 v0, v1;
    v0.x = a0[0] + bb0 + res0.x; v0.y = a0[1] + bb0 + res0.y;
    v0.z = a0[2] + bb0 + res0.z; v0.w = a0[3] + bb0 + res0.w;
    v1.x = a1[0] + bb1 + res1.x; v1.y = a1[1] + bb1 + res1.y;
    v1.z = a1[2] + bb1 + res1.z; v1.w = a1[3] + bb1 + res1.w;
    *(float4*)&cur[base] = v0;
    *(float4*)&cur[base + L] = v1;
  }
}

// MFMA flash attention (swapped-operand S^T trick), residual fused.
// grid (L/64, H, B), 256 threads = 4 independent waves (16 queries each).
// NCH = key chunks (16 keys each) per k-tile: 8 for L%128==0, else 4.
template <int NCH>
__global__ __launch_bounds__(256) void k_attn_mfma(
    const float* __restrict__ memKV, const float* __restrict__ qp,
    const float* __restrict__ mask, float* __restrict__ cur, int L) {
  int q0 = blockIdx.x * 64;
  int h = blockIdx.y, b = blockIdx.z;
  int tid = threadIdx.x;
  int w = tid >> 6;
  int lane = tid & 63;
  int g = lane >> 4, r = lane & 15;
  const float* qb = qp + ((size_t)b * 128 + h * 16) * L;
  const float* kb = memKV + ((size_t)b * 256 + h * 16) * L;
  const float* vb = memKV + ((size_t)b * 256 + 128 + h * 16) * L;
  const float* mk = mask + (size_t)b * L;

  // Q B-frag: B[k=e][n=q], lane: q = q0+16w+r, e = g*4+j (j<4), 0 pad j>=4
  int qcol = q0 + 16 * w + r;
  bf16x8 qf;
#pragma unroll
  for (int j = 0; j < 4; j++)
    qf[j] = bfr(qb[(size_t)(g * 4 + j) * L + qcol] * 0.25f);
  qf[4] = 0; qf[5] = 0; qf[6] = 0; qf[7] = 0;

  float m_run = -INFINITY, ssum = 0.f;
  f32x4 O = {0.f, 0.f, 0.f, 0.f};

  for (int k0 = 0; k0 < L; k0 += NCH * 16) {
    f32x4 sd[NCH];
    // S^T tiles: D[m=key][n=q] = sum_e K[e][key] * Qs[e][q]
#pragma unroll
    for (int mc = 0; mc < NCH; mc++) {
      bf16x8 kf;
      int krow = k0 + mc * 16 + r;
#pragma unroll
      for (int j = 0; j < 4; j++)
        kf[j] = bfr(kb[(size_t)(g * 4 + j) * L + krow]);
      kf[4] = 0; kf[5] = 0; kf[6] = 0; kf[7] = 0;
      f32x4 z = {0.f, 0.f, 0.f, 0.f};
      sd[mc] = __builtin_amdgcn_mfma_f32_16x16x32_bf16(kf, qf, z, 0, 0, 0);
    }
    // mask + tile max (this lane's q = qcol; its keys: k0+mc*16+g*4+p)
    float tm = -INFINITY;
#pragma unroll
    for (int mc = 0; mc < NCH; mc++) {
#pragma unroll
      for (int p = 0; p < 4; p++) {
        float mv = mk[k0 + mc * 16 + g * 4 + p];
        float sv = sd[mc][p] * mv + (1.f - mv) * (-1e30f);
        sd[mc][p] = sv;
        tm = fmaxf(tm, sv);
      }
    }
    tm = fmaxf(tm, __shfl_xor(tm, 16));
    tm = fmaxf(tm, __shfl_xor(tm, 32));
    float nm = fmaxf(m_run, tm);
    float c = __expf(m_run - nm);
    ssum *= c;
    O[0] *= c; O[1] *= c; O[2] *= c; O[3] *= c;
    // P = exp(S^T - nm); pack directly as PV B-frags (P^T layout matches!)
    float psum = 0.f;
    bf16x8 pf[NCH / 2];
#pragma unroll
    for (int c2 = 0; c2 < NCH / 2; c2++) {
#pragma unroll
      for (int j = 0; j < 4; j++) {
        float e0 = __expf(sd[2 * c2][j] - nm);
        float e1 = __expf(sd[2 * c2 + 1][j] - nm);
        psum += e0 + e1;
        pf[c2][j] = bfr(e0);
        pf[c2][j + 4] = bfr(e1);
      }
    }
    psum += __shfl_xor(psum, 16);
    psum += __shfl_xor(psum, 32);
    ssum += psum;
    // PV: D[m=e][n=q] += sum_key V[e][key] * P^T[key][q]
#pragma unroll
    for (int c2 = 0; c2 < NCH / 2; c2++) {
      const float* vrow = vb + (size_t)r * L + k0 + c2 * 32 + g * 4;
      float4 v0 = *(const float4*)vrow;
      float4 v1 = *(const float4*)(vrow + 16);
      bf16x8 vf;
      vf[0] = bfr(v0.x); vf[1] = bfr(v0.y); vf[2] = bfr(v0.z); vf[3] = bfr(v0.w);
      vf[4] = bfr(v1.x); vf[5] = bfr(v1.y); vf[6] = bfr(v1.z); vf[7] = bfr(v1.w);
      O = __builtin_amdgcn_mfma_f32_16x16x32_bf16(vf, pf[c2], O, 0, 0, 0);
    }
    m_run = nm;
  }
  float inv = 1.f / ssum;
  size_t ob = ((size_t)b * 128 + h * 16) * L + qcol;
#pragma unroll
  for (int p = 0; p < 4; p++)
    cur[ob + (size_t)(g * 4 + p) * L] += O[p] * inv;
}

__global__ void k_concat2(const float* __restrict__ x1, const float* __restrict__ x2,
                          float* __restrict__ out, int L, int total) {
  int idx = blockIdx.x * 256 + threadIdx.x;
  if (idx >= total) return;
  int l = idx % L;
  int c = (idx / L) & 255;
  int b = idx / (L * 256);
  float v = (c < 128) ? x1[((size_t)b * 128 + c) * L + l]
                      : x2[((size_t)b * 128 + (c - 128)) * L + l];
  out[idx] = v;
}

__global__ void k_chandot(const float* __restrict__ X, const float* __restrict__ w,
                          float* __restrict__ out, int C, int L, int total) {
  int idx = blockIdx.x * 256 + threadIdx.x;
  if (idx >= total) return;
  int l = idx % L;
  int b = idx / L;
  const float* xb = X + (size_t)b * C * L + l;
  float s = 0.f;
  for (int j = 0; j < C; j++) s += xb[(size_t)j * L] * w[j];
  out[idx] = s;
}

// S build + fused row softmax (q = lane index -> wave shuffle softmax).
__global__ void k_cqSrow(const float* __restrict__ Ce, const float* __restrict__ Qe,
                         const float* __restrict__ s0, const float* __restrict__ s1,
                         const float* __restrict__ w4mlu, const float* __restrict__ cqb,
                         const float* __restrict__ qmask,
                         float* __restrict__ S, float* __restrict__ S1) {
  int idx = blockIdx.x * 256 + threadIdx.x;  // B*LC*LQ
  int q = idx & 63;
  int l = (idx >> 6) % LC_;
  int b = (idx >> 6) / LC_;
  const float* ce = Ce + (size_t)b * 256 * LC_ + l;
  const float* qe = Qe + (size_t)b * 256 * LQ_ + q;
  float acc = 0.f;
#pragma unroll 8
  for (int j = 0; j < 256; j++) acc += ce[(size_t)j * LC_] * w4mlu[j] * qe[(size_t)j * LQ_];
  float sv = acc + s0[b * LC_ + l] + s1[b * LQ_ + q] + cqb[0];
  S[idx] = sv;
  float mv = qmask[b * LQ_ + q];
  float v = sv * mv + (1.f - mv) * (-1e30f);
  float mx = v;
  for (int off = 32; off; off >>= 1) mx = fmaxf(mx, __shfl_xor(mx, off));
  float p = expf(v - mx);
  float s = p;
  for (int off = 32; off; off >>= 1) s += __shfl_xor(s, off);
  S1[idx] = p / s;
}

// column softmax over l. grid (B*LQ) blocks, 256 threads.
__global__ __launch_bounds__(256) void k_softmax_col(
    const float* __restrict__ S, const float* __restrict__ cmask, float* __restrict__ S2) {
  int q = blockIdx.x & 63, b = blockIdx.x >> 6;
  int tid = threadIdx.x;
  __shared__ float redm[4], reds[4];
  const float* col = S + (size_t)b * LC_ * LQ_ + q;
  const float* mk = cmask + b * LC_;
  float vm[2];
#pragma unroll
  for (int k = 0; k < 2; k++) {
    int l = tid + 256 * k;
    float mv = mk[l];
    vm[k] = col[(size_t)l * LQ_] * mv + (1.f - mv) * (-1e30f);
  }
  float mx = fmaxf(vm[0], vm[1]);
  for (int off = 32; off; off >>= 1) mx = fmaxf(mx, __shfl_xor(mx, off));
  if ((tid & 63) == 0) redm[tid >> 6] = mx;
  __syncthreads();
  mx = fmaxf(fmaxf(redm[0], redm[1]), fmaxf(redm[2], redm[3]));
  float e0 = expf(vm[0] - mx), e1 = expf(vm[1] - mx);
  float s = e0 + e1;
  for (int off = 32; off; off >>= 1) s += __shfl_xor(s, off);
  if ((tid & 63) == 0) reds[tid >> 6] = s;
  __syncthreads();
  float invs = 1.f / (reds[0] + reds[1] + reds[2] + reds[3]);
  float* out = S2 + (size_t)b * LC_ * LQ_ + q;
  out[(size_t)tid * LQ_] = e0 * invs;
  out[(size_t)(tid + 256) * LQ_] = e1 * invs;
}

// Y[b,j,q] = sum_l S2[b,l,q] * Ce[b,j,l]
__global__ void k_cqY(const float* __restrict__ S2, const float* __restrict__ Ce,
                      float* __restrict__ Y) {
  int idx = blockIdx.x * 256 + threadIdx.x;
  if (idx >= B_ * 256 * LQ_) return;
  int q = idx & 63;
  int j = (idx >> 6) & 255;
  int b = idx >> 14;
  const float* s2 = S2 + (size_t)b * LC_ * LQ_ + q;
  const float* ce = Ce + ((size_t)b * 256 + j) * LC_;
  float acc = 0.f;
  for (int l = 0; l < LC_; l++) acc += s2[(size_t)l * LQ_] * ce[l];
  Y[idx] = acc;
}

// A[b,j,l] = sum_q S1[b,l,q] Qe[b,j,q];  Bt[b,j,l] = sum_q S1[b,l,q] Y[b,j,q]
__global__ __launch_bounds__(256) void k_cqAB(
    const float* __restrict__ S1, const float* __restrict__ Qe, const float* __restrict__ Y,
    float* __restrict__ A, float* __restrict__ Bt) {
  __shared__ float s1s[64][65];
  int l0 = blockIdx.x * 64;
  int b = blockIdx.z;
  int tid = threadIdx.x;
  for (int idx = tid; idx < 64 * 64; idx += 256) {
    int l = idx >> 6, q = idx & 63;
    s1s[l][q] = S1[((size_t)b * LC_ + l0 + l) * LQ_ + q];
  }
  __syncthreads();
  int ll = tid & 63, jj = tid >> 6;
  int j = blockIdx.y * 4 + jj;
  const float* qe = Qe + ((size_t)b * 256 + j) * LQ_;
  const float* yb = Y + ((size_t)b * 256 + j) * LQ_;
  float a = 0.f, bt = 0.f;
#pragma unroll 8
  for (int q = 0; q < 64; q++) {
    float sv = s1s[ll][q];
    a += sv * qe[q];
    bt += sv * yb[q];
  }
  A[((size_t)b * 256 + j) * LC_ + l0 + ll] = a;
  Bt[((size_t)b * 256 + j) * LC_ + l0 + ll] = bt;
}

// M0 = resizer_w [128,1280] @ X where X rows: [Ce; A; Ce*A; Ce*Bt; Ce]
__global__ __launch_bounds__(256) void k_resizer(
    const float* __restrict__ Ce, const float* __restrict__ A, const float* __restrict__ Bt,
    const float* __restrict__ w, float* __restrict__ y) {
  __shared__ float xs[64 * 36];
  int l0 = blockIdx.x * 32;
  int o0 = blockIdx.y * 64;
  int b = blockIdx.z;
  int tid = threadIdx.x;
  int tx = tid & 7, ty = tid >> 3;
  int o = o0 + ty * 2;
  float a0[4] = {0, 0, 0, 0}, a1[4] = {0, 0, 0, 0};
  const float* w0 = w + (size_t)o * 1280;
  const float* w1 = w0 + 1280;
  for (int kt = 0; kt < 1280; kt += 64) {
    __syncthreads();
    for (int idx = tid; idx < 64 * 32; idx += 256) {
      int i = idx >> 5, cc = idx & 31;
      int ch = kt + i;
      int seg = ch >> 8;
      int j = ch & 255;
      size_t p = ((size_t)b * 256 + j) * LC_ + l0 + cc;
      float v;
      if (seg == 0 || seg == 4) v = Ce[p];
      else if (seg == 1) v = A[p];
      else if (seg == 2) v = Ce[p] * A[p];
      else v = Ce[p] * Bt[p];
      xs[i * 36 + cc] = v;
    }
    __syncthreads();
#pragma unroll 8
    for (int i = 0; i < 64; i++) {
      float4 xv = *(const float4*)&xs[i * 36 + tx * 4];
      float u0 = w0[kt + i], u1 = w1[kt + i];
      a0[0] += u0 * xv.x; a0[1] += u0 * xv.y; a0[2] += u0 * xv.z; a0[3] += u0 * xv.w;
      a1[0] += u1 * xv.x; a1[1] += u1 * xv.y; a1[2] += u1 * xv.z; a1[3] += u1 * xv.w;
    }
  }
  size_t base = ((size_t)b * D_ + o) * LC_ + l0 + tx * 4;
  *(float4*)&y[base] = make_float4(a0[0], a0[1], a0[2], a0[3]);
  *(float4*)&y[base + LC_] = make_float4(a1[0], a1[1], a1[2], a1[3]);
}

// ---------------------------------------------------------------- host side

struct BlkP {
  int n_conv, k;
  const float* lnc_g[4]; const float* lnc_b[4];
  const float* dw[4]; const float* pw[4]; const float* pw_b[4];
  const float* mem_w; const float* q_w;
  const float* ln1_g; const float* ln1_b;
  const float* ffn1_w; const float* ffn1_b;
  const float* ffn2_w; const float* ffn2_b;
  const float* ln2_g; const float* ln2_b;
};

static void encoder_block(hipStream_t st, const float* xin, float* cur, float* aux,
                          float* mkv, float* qpb, const float* mask, int L, const BlkP& P) {
  dim3 gc(L / 32, 2, B_);
  const float* in = xin;
  for (int i = 0; i < P.n_conv; i++) {
    float* ob = (i % 2 == 0) ? aux : cur;
    if (P.k == 7) {
      if (i == 0) k_convlayer<7, 1><<<gc, 256, 0, st>>>(in, ob, P.dw[i], P.pw[i], P.pw_b[i], P.lnc_g[i], P.lnc_b[i], L);
      else        k_convlayer<7, 0><<<gc, 256, 0, st>>>(in, ob, P.dw[i], P.pw[i], P.pw_b[i], P.lnc_g[i], P.lnc_b[i], L);
    } else {
      if (i == 0) k_convlayer<5, 1><<<gc, 256, 0, st>>>(in, ob, P.dw[i], P.pw[i], P.pw_b[i], P.lnc_g[i], P.lnc_b[i], L);
      else        k_convlayer<5, 0><<<gc, 256, 0, st>>>(in, ob, P.dw[i], P.pw[i], P.pw_b[i], P.lnc_g[i], P.lnc_b[i], L);
    }
    in = ob;
  }
  k_lnproj<<<dim3(L / 64, 6, B_), 256, 0, st>>>(cur, P.mem_w, P.q_w, mkv, qpb, P.ln1_g, P.ln1_b, L);
  if (L % 128 == 0)
    k_attn_mfma<8><<<dim3(L / 64, H_, B_), 256, 0, st>>>(mkv, qpb, mask, cur, L);
  else
    k_attn_mfma<4><<<dim3(L / 64, H_, B_), 256, 0, st>>>(mkv, qpb, mask, cur, L);
  k_ffn<<<dim3(L / 16, 1, B_), 256, 0, st>>>(cur, P.ffn1_w, P.ffn1_b, P.ffn2_w, P.ffn2_b, P.ln2_g, P.ln2_b, L);
}

extern "C" void kernel_launch(void* const* d_in, const int* in_sizes, int n_in,
                              void* d_out, int out_size, void* d_ws, size_t ws_size,
                              hipStream_t stream) {
  (void)in_sizes; (void)n_in; (void)out_size; (void)ws_size;
  const float* C        = (const float*)d_in[0];
  const float* Q        = (const float*)d_in[1];
  const float* maskC    = (const float*)d_in[2];
  const float* maskQ    = (const float*)d_in[3];
  const float* e_dw     = (const float*)d_in[4];
  const float* e_pw     = (const float*)d_in[5];
  const float* e_pw_b   = (const float*)d_in[6];
  const float* e_lnc_g  = (const float*)d_in[7];
  const float* e_lnc_b  = (const float*)d_in[8];
  const float* e_mem_w  = (const float*)d_in[9];
  const float* e_q_w    = (const float*)d_in[10];
  const float* e_ffn1_w = (const float*)d_in[11];
  const float* e_ffn1_b = (const float*)d_in[12];
  const float* e_ffn2_w = (const float*)d_in[13];
  const float* e_ffn2_b = (const float*)d_in[14];
  const float* e_ln1_g  = (const float*)d_in[15];
  const float* e_ln1_b  = (const float*)d_in[16];
  const float* e_ln2_g  = (const float*)d_in[17];
  const float* e_ln2_b  = (const float*)d_in[18];
  const float* w4C      = (const float*)d_in[19];
  const float* w4Q      = (const float*)d_in[20];
  const float* w4mlu    = (const float*)d_in[21];
  const float* cq_b     = (const float*)d_in[22];
  const float* resizer_w= (const float*)d_in[23];
  const float* m_dw     = (const float*)d_in[24];
  const float* m_pw     = (const float*)d_in[25];
  const float* m_pw_b   = (const float*)d_in[26];
  const float* m_lnc_g  = (const float*)d_in[27];
  const float* m_lnc_b  = (const float*)d_in[28];
  const float* m_mem_w  = (const float*)d_in[29];
  const float* m_q_w    = (const float*)d_in[30];
  const float* m_ffn1_w = (const float*)d_in[31];
  const float* m_ffn1_b = (const float*)d_in[32];
  const float* m_ffn2_w = (const float*)d_in[33];
  const float* m_ffn2_b = (const float*)d_in[34];
  const float* m_ln1_g  = (const float*)d_in[35];
  const float* m_ln1_b  = (const float*)d_in[36];
  const float* m_ln2_g  = (const float*)d_in[37];
  const float* m_ln2_b  = (const float*)d_in[38];

  float* ws = (float*)d_ws;
  const size_t SB = (size_t)B_ * D_ * LC_;
  float* cur  = ws;
  float* aux  = cur + SB;
  float* mkv  = aux + SB;
  float* qpb  = mkv + 2 * SB;
  float* Ce   = qpb + SB;
  float* Qe   = Ce + 2 * SB;
  float* Sbuf = Qe + (size_t)B_ * 256 * LQ_;
  float* S1   = Sbuf + (size_t)B_ * LC_ * LQ_;
  float* S2   = S1 + (size_t)B_ * LC_ * LQ_;
  float* s0v  = S2 + (size_t)B_ * LC_ * LQ_;
  float* s1v  = s0v + (size_t)B_ * LC_;
  float* Yb   = s1v + (size_t)B_ * LQ_;
  float* Ab   = Yb + (size_t)B_ * 256 * LQ_;
  float* Bb   = Ab + 2 * SB;
  float* Mb   = Bb + 2 * SB;

  BlkP ep{};
  ep.n_conv = 4; ep.k = 7;
  for (int i = 0; i < 4; i++) {
    ep.lnc_g[i] = e_lnc_g + i * 128;
    ep.lnc_b[i] = e_lnc_b + i * 128;
    ep.dw[i]    = e_dw + i * 128 * 7;
    ep.pw[i]    = e_pw + (size_t)i * 128 * 128;
    ep.pw_b[i]  = e_pw_b + i * 128;
  }
  ep.mem_w = e_mem_w; ep.q_w = e_q_w;
  ep.ln1_g = e_ln1_g; ep.ln1_b = e_ln1_b;
  ep.ffn1_w = e_ffn1_w; ep.ffn1_b = e_ffn1_b;
  ep.ffn2_w = e_ffn2_w; ep.ffn2_b = e_ffn2_b;
  ep.ln2_g = e_ln2_g; ep.ln2_b = e_ln2_b;

  // ---- C encoder -> Ce ----
  encoder_block(stream, C, cur, aux, mkv, qpb, maskC, LC_, ep);
  {
    int tot = B_ * 256 * LC_;
    k_concat2<<<(tot + 255) / 256, 256, 0, stream>>>(cur, C, Ce, LC_, tot);
  }
  // ---- Q encoder -> Qe ----
  encoder_block(stream, Q, cur, aux, mkv, qpb, maskQ, LQ_, ep);
  {
    int tot = B_ * 256 * LQ_;
    k_concat2<<<(tot + 255) / 256, 256, 0, stream>>>(cur, Q, Qe, LQ_, tot);
  }

  // ---- CQ attention + resizer -> Mb (= M0) ----
  k_chandot<<<(B_ * LC_ + 255) / 256, 256, 0, stream>>>(Ce, w4C, s0v, 256, LC_, B_ * LC_);
  k_chandot<<<(B_ * LQ_ + 255) / 256, 256, 0, stream>>>(Qe, w4Q, s1v, 256, LQ_, B_ * LQ_);
  k_cqSrow<<<(B_ * LC_ * LQ_) / 256, 256, 0, stream>>>(Ce, Qe, s0v, s1v, w4mlu, cq_b, maskQ, Sbuf, S1);
  k_softmax_col<<<B_ * LQ_, 256, 0, stream>>>(Sbuf, maskC, S2);
  k_cqY<<<(B_ * 256 * LQ_) / 256, 256, 0, stream>>>(S2, Ce, Yb);
  k_cqAB<<<dim3(LC_ / 64, 64, B_), 256, 0, stream>>>(S1, Qe, Yb, Ab, Bb);
  k_resizer<<<dim3(LC_ / 32, 2, B_), 256, 0, stream>>>(Ce, Ab, Bb, resizer_w, Mb);

  // ---- model encoder: 3 runs of 7 blocks ----
  float* out = (float*)d_out;
  const float* src = Mb;
  for (int r = 0; r < 3; r++) {
    for (int bi = 0; bi < 7; bi++) {
      BlkP mp{};
      mp.n_conv = 2; mp.k = 5;
      for (int ci = 0; ci < 2; ci++) {
        int pc = bi * 2 + ci;
        mp.lnc_g[ci] = m_lnc_g + pc * 128;
        mp.lnc_b[ci] = m_lnc_b + pc * 128;
        mp.dw[ci]    = m_dw + pc * 128 * 5;
        mp.pw[ci]    = m_pw + (size_t)pc * 128 * 128;
        mp.pw_b[ci]  = m_pw_b + pc * 128;
      }
      mp.mem_w  = m_mem_w + (size_t)bi * 256 * 128;
      mp.q_w    = m_q_w + (size_t)bi * 128 * 128;
      mp.ffn1_w = m_ffn1_w + (size_t)bi * 128 * 128;
      mp.ffn1_b = m_ffn1_b + bi * 128;
      mp.ffn2_w = m_ffn2_w + (size_t)bi * 128 * 128;
      mp.ffn2_b = m_ffn2_b + bi * 128;
      mp.ln1_g = m_ln1_g + bi * 128; mp.ln1_b = m_ln1_b + bi * 128;
      mp.ln2_g = m_ln2_g + bi * 128; mp.ln2_b = m_ln2_b + bi * 128;
      encoder_block(stream, (bi == 0) ? src : cur, cur, aux, mkv, qpb, maskC, LC_, mp);
    }
    hipMemcpyAsync(out + (size_t)r * SB, cur, SB * sizeof(float),
                   hipMemcpyDeviceToDevice, stream);
    src = cur;
  }
}

// Round 5
// 2414.855 us; speedup vs baseline: 2.7440x; 1.1082x over previous
//
#include <hip/hip_runtime.h>
#include <math.h>

#define D_  128
#define B_  8
#define H_  8
#define LC_ 512
#define LQ_ 64

typedef float f32x4 __attribute__((ext_vector_type(4)));
typedef short bf16x8 __attribute__((ext_vector_type(8)));
typedef short short4v __attribute__((ext_vector_type(4)));
typedef unsigned short ushortT;

__device__ inline short bfr(float x) {
  unsigned u = __float_as_uint(x);
  u += 0x7fff + ((u >> 16) & 1);
  return (short)(u >> 16);
}

__device__ inline bf16x8 mk8(short4v lo, short4v hi) {
  bf16x8 r;
  r[0] = lo[0]; r[1] = lo[1]; r[2] = lo[2]; r[3] = lo[3];
  r[4] = hi[0]; r[5] = hi[1]; r[6] = hi[2]; r[7] = hi[3];
  return r;
}

// A-frag: W[m=lane&15][k], k = koff + g*4 + (j&3) + 16*(j>>2)
__device__ inline bf16x8 ldA(const ushortT* row, int koff) {
  short4v lo = *(const short4v*)(row + koff);
  short4v hi = *(const short4v*)(row + koff + 16);
  return mk8(lo, hi);
}
__device__ inline bf16x8 ldB2(const ushortT* plo, const ushortT* phi) {
  short4v lo = *(const short4v*)plo;
  short4v hi = *(const short4v*)phi;
  return mk8(lo, hi);
}

// ---------------------------------------------------------------- weight prep
// Convert all GEMM weights fp32 -> bf16 into ws (layouts preserved row-major).
__global__ void k_prep(const float* a0, const float* a1, const float* a2,
                       const float* a3, const float* a4, const float* a5,
                       const float* a6, const float* a7, const float* a8,
                       const float* a9, const float* a10, ushortT* dst) {
  int i = blockIdx.x * 256 + threadIdx.x;
  if (i >= 1114112) return;
  const float* s; int lo;
  if      (i <   65536) { s = a0;  lo = i; }
  else if (i <   98304) { s = a1;  lo = i - 65536; }
  else if (i <  114688) { s = a2;  lo = i - 98304; }
  else if (i <  131072) { s = a3;  lo = i - 114688; }
  else if (i <  147456) { s = a4;  lo = i - 131072; }
  else if (i <  311296) { s = a5;  lo = i - 147456; }
  else if (i <  540672) { s = a6;  lo = i - 311296; }
  else if (i <  770048) { s = a7;  lo = i - 540672; }
  else if (i <  884736) { s = a8;  lo = i - 770048; }
  else if (i <  999424) { s = a9;  lo = i - 884736; }
  else                  { s = a10; lo = i - 999424; }
  dst[i] = (ushortT)bfr(s[lo]);
}

// ---------------------------------------------------------------- conv layer
// [pos +] LN + dwconv (fp32) -> bf16 LDS -> MFMA pointwise + bias+relu+resid.
// grid (L/32, 2, B), 256 thr. x != yout (halo).
template <int KK, int ADDPOS>
__global__ __launch_bounds__(256) void k_convlayer_mfma(
    const float* __restrict__ x, float* __restrict__ yout,
    const float* __restrict__ dwv, const ushortT* __restrict__ pwbf,
    const float* __restrict__ pwb, const float* __restrict__ g,
    const float* __restrict__ be, int L) {
  const int HALO = KK / 2;
  const int W = 32 + 2 * HALO;
  __shared__ float raw[128 * 40];
  __shared__ __align__(16) ushortT xbf[32 * 32 * 4];  // [kg][c][4]
  __shared__ float mu_s[40], rs_s[40], ps[160], ps2[160];
  int l0 = blockIdx.x * 32;
  int o0 = blockIdx.y * 64;
  int b = blockIdx.z;
  int tid = threadIdx.x;
  for (int idx = tid; idx < 128 * W; idx += 256) {
    int d = idx / W, c = idx - d * W;
    int l = l0 + c - HALO;
    float v = 0.f;
    if (l >= 0 && l < L) {
      v = x[((size_t)b * 128 + d) * L + l];
      if (ADDPOS) {
        int j = d & 63;
        float arg = (float)l * expf(-(float)j * 0.14619588f);
        v += (d < 64) ? sinf(arg) : cosf(arg);
      }
    }
    raw[d * 40 + c] = v;
  }
  __syncthreads();
  if (tid < 4 * W) {
    int c = tid % W, hh = tid / W;
    float s = 0.f, s2 = 0.f;
    for (int d = hh * 32; d < hh * 32 + 32; d++) {
      float v = raw[d * 40 + c];
      s += v; s2 += v * v;
    }
    ps[tid] = s; ps2[tid] = s2;
  }
  __syncthreads();
  if (tid < W) {
    float s = ps[tid] + ps[tid + W] + ps[tid + 2 * W] + ps[tid + 3 * W];
    float s2 = ps2[tid] + ps2[tid + W] + ps2[tid + 2 * W] + ps2[tid + 3 * W];
    float mu = s * (1.f / 128.f);
    float var = fmaxf(s2 * (1.f / 128.f) - mu * mu, 0.f);
    mu_s[tid] = mu; rs_s[tid] = rsqrtf(var + 1e-5f);
  }
  __syncthreads();
  // dwconv of LN(x) -> bf16 packed LDS
  int cc0 = tid & 31, dg = tid >> 5;
#pragma unroll
  for (int kq = 0; kq < 4; kq++) {
    short4v pk;
#pragma unroll
    for (int e = 0; e < 4; e++) {
      int d = dg * 16 + kq * 4 + e;
      float gg = g[d], bb = be[d];
      const float* wr = dwv + d * KK;
      float acc = 0.f;
#pragma unroll
      for (int t = 0; t < KK; t++) {
        int c = cc0 + t;
        int l = l0 + c - HALO;
        float lv = 0.f;
        if (l >= 0 && l < L)
          lv = (raw[d * 40 + c] - mu_s[c]) * rs_s[c] * gg + bb;
        acc += wr[t] * lv;
      }
      pk[e] = bfr(acc);
    }
    *(short4v*)&xbf[(((dg * 4 + kq) * 32) + cc0) * 4] = pk;
  }
  __syncthreads();
  // MFMA pointwise: 64 outs x 32 cols; wave w -> o-tile w
  int w = tid >> 6, lane = tid & 63, g2 = lane >> 4, r = lane & 15;
  const ushortT* arow = pwbf + (size_t)(o0 + 16 * w + r) * 128;
  f32x4 acc0 = {0.f, 0.f, 0.f, 0.f}, acc1 = {0.f, 0.f, 0.f, 0.f};
#pragma unroll
  for (int kk = 0; kk < 4; kk++) {
    bf16x8 a = ldA(arow, kk * 32 + g2 * 4);
    bf16x8 b0 = ldB2(&xbf[(((kk * 8 + g2) * 32) + r) * 4],
                     &xbf[(((kk * 8 + 4 + g2) * 32) + r) * 4]);
    acc0 = __builtin_amdgcn_mfma_f32_16x16x32_bf16(a, b0, acc0, 0, 0, 0);
    bf16x8 b1 = ldB2(&xbf[(((kk * 8 + g2) * 32) + 16 + r) * 4],
                     &xbf[(((kk * 8 + 4 + g2) * 32) + 16 + r) * 4]);
    acc1 = __builtin_amdgcn_mfma_f32_16x16x32_bf16(a, b1, acc1, 0, 0, 0);
  }
#pragma unroll
  for (int p = 0; p < 4; p++) {
    int o = o0 + 16 * w + g2 * 4 + p;
    float bv = pwb[o];
    float r0 = raw[o * 40 + r + HALO];
    float r1 = raw[o * 40 + 16 + r + HALO];
    size_t base = ((size_t)b * 128 + o) * L + l0;
    yout[base + r] = fmaxf(acc0[p] + bv, 0.f) + r0;
    yout[base + 16 + r] = fmaxf(acc1[p] + bv, 0.f) + r1;
  }
}

// ---------------------------------------------------------------- ln + proj
// grid (L/64, 6, B): yb<4 -> mem outputs (256), yb>=4 -> q outputs (128).
__global__ __launch_bounds__(256) void k_lnproj_mfma(
    const float* __restrict__ x, const ushortT* __restrict__ memw,
    const ushortT* __restrict__ qw, float* __restrict__ mkv,
    float* __restrict__ qp, const float* __restrict__ g,
    const float* __restrict__ be, int L) {
  __shared__ float xs[128 * 68];
  __shared__ __align__(16) ushortT xbf[32 * 64 * 4];
  __shared__ float mu_s[64], rs_s[64], ps[256], ps2[256];
  int l0 = blockIdx.x * 64;
  int b = blockIdx.z;
  int yb = blockIdx.y;
  const ushortT* wsel; float* out; int o0, O;
  if (yb < 4) { wsel = memw; out = mkv; o0 = yb * 64; O = 256; }
  else        { wsel = qw;   out = qp;  o0 = (yb - 4) * 64; O = 128; }
  int tid = threadIdx.x;
  for (int idx = tid; idx < 128 * 64; idx += 256) {
    int d = idx >> 6, c = idx & 63;
    xs[d * 68 + c] = x[((size_t)b * 128 + d) * L + l0 + c];
  }
  __syncthreads();
  {
    int c = tid & 63, qq = tid >> 6;
    float s = 0.f, s2 = 0.f;
    for (int d = qq * 32; d < qq * 32 + 32; d++) {
      float v = xs[d * 68 + c];
      s += v; s2 += v * v;
    }
    ps[tid] = s; ps2[tid] = s2;
  }
  __syncthreads();
  if (tid < 64) {
    float s = ps[tid] + ps[tid + 64] + ps[tid + 128] + ps[tid + 192];
    float s2 = ps2[tid] + ps2[tid + 64] + ps2[tid + 128] + ps2[tid + 192];
    float mu = s * (1.f / 128.f);
    float var = fmaxf(s2 * (1.f / 128.f) - mu * mu, 0.f);
    mu_s[tid] = mu; rs_s[tid] = rsqrtf(var + 1e-5f);
  }
  __syncthreads();
  for (int idx = tid; idx < 128 * 64; idx += 256) {
    int d = idx >> 6, c = idx & 63;
    float val = (xs[d * 68 + c] - mu_s[c]) * rs_s[c] * g[d] + be[d];
    xbf[(((d >> 2) * 64) + c) * 4 + (d & 3)] = (ushortT)bfr(val);
  }
  __syncthreads();
  int w = tid >> 6, lane = tid & 63, g2 = lane >> 4, r = lane & 15;
  const ushortT* arow = wsel + (size_t)(o0 + 16 * w + r) * 128;
  f32x4 acc[4];
#pragma unroll
  for (int nt = 0; nt < 4; nt++) acc[nt] = (f32x4){0.f, 0.f, 0.f, 0.f};
#pragma unroll
  for (int kk = 0; kk < 4; kk++) {
    bf16x8 a = ldA(arow, kk * 32 + g2 * 4);
#pragma unroll
    for (int nt = 0; nt < 4; nt++) {
      bf16x8 bb = ldB2(&xbf[(((kk * 8 + g2) * 64) + nt * 16 + r) * 4],
                       &xbf[(((kk * 8 + 4 + g2) * 64) + nt * 16 + r) * 4]);
      acc[nt] = __builtin_amdgcn_mfma_f32_16x16x32_bf16(a, bb, acc[nt], 0, 0, 0);
    }
  }
#pragma unroll
  for (int nt = 0; nt < 4; nt++) {
#pragma unroll
    for (int p = 0; p < 4; p++) {
      int o = o0 + 16 * w + g2 * 4 + p;
      out[((size_t)b * O + o) * L + l0 + nt * 16 + r] = acc[nt][p];
    }
  }
}

// ---------------------------------------------------------------- ffn
// LN + FFN1(relu) + FFN2 + bias + residual, in-place. grid (L/16, 1, B).
__global__ __launch_bounds__(256) void k_ffn_mfma(
    float* __restrict__ cur, const ushortT* __restrict__ w1bf,
    const float* __restrict__ b1, const ushortT* __restrict__ w2bf,
    const float* __restrict__ b2, const float* __restrict__ g,
    const float* __restrict__ be, int L) {
  __shared__ float xs[128 * 20];
  __shared__ __align__(16) ushortT xbf[32 * 16 * 4];
  __shared__ __align__(16) ushortT midbf[32 * 16 * 4];
  __shared__ float mu_s[16], rs_s[16], ps[256], ps2[256];
  int l0 = blockIdx.x * 16;
  int b = blockIdx.z;
  int tid = threadIdx.x;
  for (int idx = tid; idx < 128 * 16; idx += 256) {
    int d = idx >> 4, c = idx & 15;
    xs[d * 20 + c] = cur[((size_t)b * 128 + d) * L + l0 + c];
  }
  __syncthreads();
  {
    int c = tid & 15, hh = tid >> 4;
    float s = 0.f, s2 = 0.f;
    for (int d = hh * 8; d < hh * 8 + 8; d++) {
      float v = xs[d * 20 + c];
      s += v; s2 += v * v;
    }
    ps[tid] = s; ps2[tid] = s2;
  }
  __syncthreads();
  if (tid < 16) {
    float s = 0.f, s2 = 0.f;
    for (int hh = 0; hh < 16; hh++) { s += ps[hh * 16 + tid]; s2 += ps2[hh * 16 + tid]; }
    float mu = s * (1.f / 128.f);
    float var = fmaxf(s2 * (1.f / 128.f) - mu * mu, 0.f);
    mu_s[tid] = mu; rs_s[tid] = rsqrtf(var + 1e-5f);
  }
  __syncthreads();
  for (int idx = tid; idx < 128 * 16; idx += 256) {
    int d = idx >> 4, c = idx & 15;
    float val = (xs[d * 20 + c] - mu_s[c]) * rs_s[c] * g[d] + be[d];
    xbf[(((d >> 2) * 16) + c) * 4 + (d & 3)] = (ushortT)bfr(val);
  }
  __syncthreads();
  int w = tid >> 6, lane = tid & 63, g2 = lane >> 4, r = lane & 15;
  // GEMM1: wave w -> o-tiles {w, w+4}
  f32x4 acc[2];
#pragma unroll
  for (int h = 0; h < 2; h++) {
    acc[h] = (f32x4){0.f, 0.f, 0.f, 0.f};
    const ushortT* ar = w1bf + (size_t)(16 * (w + 4 * h) + r) * 128;
#pragma unroll
    for (int kk = 0; kk < 4; kk++) {
      bf16x8 a = ldA(ar, kk * 32 + g2 * 4);
      bf16x8 bb = ldB2(&xbf[(((kk * 8 + g2) * 16) + r) * 4],
                       &xbf[(((kk * 8 + 4 + g2) * 16) + r) * 4]);
      acc[h] = __builtin_amdgcn_mfma_f32_16x16x32_bf16(a, bb, acc[h], 0, 0, 0);
    }
  }
#pragma unroll
  for (int h = 0; h < 2; h++) {
#pragma unroll
    for (int p = 0; p < 4; p++) {
      int dmid = 16 * (w + 4 * h) + g2 * 4 + p;
      float val = fmaxf(acc[h][p] + b1[dmid], 0.f);
      midbf[(((4 * (w + 4 * h) + g2) * 16) + r) * 4 + p] = (ushortT)bfr(val);
    }
  }
  __syncthreads();
  // GEMM2 + bias + residual
#pragma unroll
  for (int h = 0; h < 2; h++) {
    f32x4 a2 = {0.f, 0.f, 0.f, 0.f};
    const ushortT* ar = w2bf + (size_t)(16 * (w + 4 * h) + r) * 128;
#pragma unroll
    for (int kk = 0; kk < 4; kk++) {
      bf16x8 a = ldA(ar, kk * 32 + g2 * 4);
      bf16x8 bb = ldB2(&midbf[(((kk * 8 + g2) * 16) + r) * 4],
                       &midbf[(((kk * 8 + 4 + g2) * 16) + r) * 4]);
      a2 = __builtin_amdgcn_mfma_f32_16x16x32_bf16(a, bb, a2, 0, 0, 0);
    }
#pragma unroll
    for (int p = 0; p < 4; p++) {
      int o = 16 * (w + 4 * h) + g2 * 4 + p;
      size_t pos = ((size_t)b * 128 + o) * L + l0 + r;
      cur[pos] = a2[p] + b2[o] + cur[pos];
    }
  }
}

// ---------------------------------------------------------------- attention
// MFMA flash attention (swapped-operand S^T), residual fused. grid (L/64,H,B).
template <int NCH>
__global__ __launch_bounds__(256) void k_attn_mfma(
    const float* __restrict__ memKV, const float* __restrict__ qp,
    const float* __restrict__ mask, float* __restrict__ cur, int L) {
  int q0 = blockIdx.x * 64;
  int h = blockIdx.y, b = blockIdx.z;
  int tid = threadIdx.x;
  int w = tid >> 6;
  int lane = tid & 63;
  int g = lane >> 4, r = lane & 15;
  const float* qb = qp + ((size_t)b * 128 + h * 16) * L;
  const float* kb = memKV + ((size_t)b * 256 + h * 16) * L;
  const float* vb = memKV + ((size_t)b * 256 + 128 + h * 16) * L;
  const float* mk = mask + (size_t)b * L;
  int qcol = q0 + 16 * w + r;
  bf16x8 qf;
#pragma unroll
  for (int j = 0; j < 4; j++)
    qf[j] = bfr(qb[(size_t)(g * 4 + j) * L + qcol] * 0.25f);
  qf[4] = 0; qf[5] = 0; qf[6] = 0; qf[7] = 0;
  float m_run = -INFINITY, ssum = 0.f;
  f32x4 O = {0.f, 0.f, 0.f, 0.f};
  for (int k0 = 0; k0 < L; k0 += NCH * 16) {
    f32x4 sd[NCH];
#pragma unroll
    for (int mc = 0; mc < NCH; mc++) {
      bf16x8 kf;
      int krow = k0 + mc * 16 + r;
#pragma unroll
      for (int j = 0; j < 4; j++)
        kf[j] = bfr(kb[(size_t)(g * 4 + j) * L + krow]);
      kf[4] = 0; kf[5] = 0; kf[6] = 0; kf[7] = 0;
      f32x4 z = {0.f, 0.f, 0.f, 0.f};
      sd[mc] = __builtin_amdgcn_mfma_f32_16x16x32_bf16(kf, qf, z, 0, 0, 0);
    }
    float tm = -INFINITY;
#pragma unroll
    for (int mc = 0; mc < NCH; mc++) {
#pragma unroll
      for (int p = 0; p < 4; p++) {
        float mv = mk[k0 + mc * 16 + g * 4 + p];
        float sv = sd[mc][p] * mv + (1.f - mv) * (-1e30f);
        sd[mc][p] = sv;
        tm = fmaxf(tm, sv);
      }
    }
    tm = fmaxf(tm, __shfl_xor(tm, 16));
    tm = fmaxf(tm, __shfl_xor(tm, 32));
    float nm = fmaxf(m_run, tm);
    float c = __expf(m_run - nm);
    ssum *= c;
    O[0] *= c; O[1] *= c; O[2] *= c; O[3] *= c;
    float psum = 0.f;
    bf16x8 pf[NCH / 2];
#pragma unroll
    for (int c2 = 0; c2 < NCH / 2; c2++) {
#pragma unroll
      for (int j = 0; j < 4; j++) {
        float e0 = __expf(sd[2 * c2][j] - nm);
        float e1 = __expf(sd[2 * c2 + 1][j] - nm);
        psum += e0 + e1;
        pf[c2][j] = bfr(e0);
        pf[c2][j + 4] = bfr(e1);
      }
    }
    psum += __shfl_xor(psum, 16);
    psum += __shfl_xor(psum, 32);
    ssum += psum;
#pragma unroll
    for (int c2 = 0; c2 < NCH / 2; c2++) {
      const float* vrow = vb + (size_t)r * L + k0 + c2 * 32 + g * 4;
      float4 v0 = *(const float4*)vrow;
      float4 v1 = *(const float4*)(vrow + 16);
      bf16x8 vf;
      vf[0] = bfr(v0.x); vf[1] = bfr(v0.y); vf[2] = bfr(v0.z); vf[3] = bfr(v0.w);
      vf[4] = bfr(v1.x); vf[5] = bfr(v1.y); vf[6] = bfr(v1.z); vf[7] = bfr(v1.w);
      O = __builtin_amdgcn_mfma_f32_16x16x32_bf16(vf, pf[c2], O, 0, 0, 0);
    }
    m_run = nm;
  }
  float inv = 1.f / ssum;
  size_t ob = ((size_t)b * 128 + h * 16) * L + qcol;
#pragma unroll
  for (int p = 0; p < 4; p++)
    cur[ob + (size_t)(g * 4 + p) * L] += O[p] * inv;
}

// ---------------------------------------------------------------- CQ section

__global__ void k_concat2(const float* __restrict__ x1, const float* __restrict__ x2,
                          float* __restrict__ out, int L, int total) {
  int idx = blockIdx.x * 256 + threadIdx.x;
  if (idx >= total) return;
  int l = idx % L;
  int c = (idx / L) & 255;
  int b = idx / (L * 256);
  float v = (c < 128) ? x1[((size_t)b * 128 + c) * L + l]
                      : x2[((size_t)b * 128 + (c - 128)) * L + l];
  out[idx] = v;
}

__global__ void k_chandot(const float* __restrict__ X, const float* __restrict__ w,
                          float* __restrict__ out, int C, int L, int total) {
  int idx = blockIdx.x * 256 + threadIdx.x;
  if (idx >= total) return;
  int l = idx % L;
  int b = idx / L;
  const float* xb = X + (size_t)b * C * L + l;
  float s = 0.f;
  for (int j = 0; j < C; j++) s += xb[(size_t)j * L] * w[j];
  out[idx] = s;
}

__global__ void k_cqSrow(const float* __restrict__ Ce, const float* __restrict__ Qe,
                         const float* __restrict__ s0, const float* __restrict__ s1,
                         const float* __restrict__ w4mlu, const float* __restrict__ cqb,
                         const float* __restrict__ qmask,
                         float* __restrict__ S, float* __restrict__ S1) {
  int idx = blockIdx.x * 256 + threadIdx.x;
  int q = idx & 63;
  int l = (idx >> 6) % LC_;
  int b = (idx >> 6) / LC_;
  const float* ce = Ce + (size_t)b * 256 * LC_ + l;
  const float* qe = Qe + (size_t)b * 256 * LQ_ + q;
  float acc = 0.f;
#pragma unroll 8
  for (int j = 0; j < 256; j++) acc += ce[(size_t)j * LC_] * w4mlu[j] * qe[(size_t)j * LQ_];
  float sv = acc + s0[b * LC_ + l] + s1[b * LQ_ + q] + cqb[0];
  S[idx] = sv;
  float mv = qmask[b * LQ_ + q];
  float v = sv * mv + (1.f - mv) * (-1e30f);
  float mx = v;
  for (int off = 32; off; off >>= 1) mx = fmaxf(mx, __shfl_xor(mx, off));
  float p = expf(v - mx);
  float s = p;
  for (int off = 32; off; off >>= 1) s += __shfl_xor(s, off);
  S1[idx] = p / s;
}

__global__ __launch_bounds__(256) void k_softmax_col(
    const float* __restrict__ S, const float* __restrict__ cmask, float* __restrict__ S2) {
  int q = blockIdx.x & 63, b = blockIdx.x >> 6;
  int tid = threadIdx.x;
  __shared__ float redm[4], reds[4];
  const float* col = S + (size_t)b * LC_ * LQ_ + q;
  const float* mk = cmask + b * LC_;
  float vm[2];
#pragma unroll
  for (int k = 0; k < 2; k++) {
    int l = tid + 256 * k;
    float mv = mk[l];
    vm[k] = col[(size_t)l * LQ_] * mv + (1.f - mv) * (-1e30f);
  }
  float mx = fmaxf(vm[0], vm[1]);
  for (int off = 32; off; off >>= 1) mx = fmaxf(mx, __shfl_xor(mx, off));
  if ((tid & 63) == 0) redm[tid >> 6] = mx;
  __syncthreads();
  mx = fmaxf(fmaxf(redm[0], redm[1]), fmaxf(redm[2], redm[3]));
  float e0 = expf(vm[0] - mx), e1 = expf(vm[1] - mx);
  float s = e0 + e1;
  for (int off = 32; off; off >>= 1) s += __shfl_xor(s, off);
  if ((tid & 63) == 0) reds[tid >> 6] = s;
  __syncthreads();
  float invs = 1.f / (reds[0] + reds[1] + reds[2] + reds[3]);
  float* out = S2 + (size_t)b * LC_ * LQ_ + q;
  out[(size_t)tid * LQ_] = e0 * invs;
  out[(size_t)(tid + 256) * LQ_] = e1 * invs;
}

__global__ void k_cqY(const float* __restrict__ S2, const float* __restrict__ Ce,
                      float* __restrict__ Y) {
  int idx = blockIdx.x * 256 + threadIdx.x;
  if (idx >= B_ * 256 * LQ_) return;
  int q = idx & 63;
  int j = (idx >> 6) & 255;
  int b = idx >> 14;
  const float* s2 = S2 + (size_t)b * LC_ * LQ_ + q;
  const float* ce = Ce + ((size_t)b * 256 + j) * LC_;
  float acc = 0.f;
  for (int l = 0; l < LC_; l++) acc += s2[(size_t)l * LQ_] * ce[l];
  Y[idx] = acc;
}

__global__ __launch_bounds__(256) void k_cqAB(
    const float* __restrict__ S1, const float* __restrict__ Qe, const float* __restrict__ Y,
    float* __restrict__ A, float* __restrict__ Bt) {
  __shared__ float s1s[64][65];
  int l0 = blockIdx.x * 64;
  int b = blockIdx.z;
  int tid = threadIdx.x;
  for (int idx = tid; idx < 64 * 64; idx += 256) {
    int l = idx >> 6, q = idx & 63;
    s1s[l][q] = S1[((size_t)b * LC_ + l0 + l) * LQ_ + q];
  }
  __syncthreads();
  int ll = tid & 63, jj = tid >> 6;
  int j = blockIdx.y * 4 + jj;
  const float* qe = Qe + ((size_t)b * 256 + j) * LQ_;
  const float* yb = Y + ((size_t)b * 256 + j) * LQ_;
  float a = 0.f, bt = 0.f;
#pragma unroll 8
  for (int q = 0; q < 64; q++) {
    float sv = s1s[ll][q];
    a += sv * qe[q];
    bt += sv * yb[q];
  }
  A[((size_t)b * 256 + j) * LC_ + l0 + ll] = a;
  Bt[((size_t)b * 256 + j) * LC_ + l0 + ll] = bt;
}

// M0 = resizer_w [128,1280] @ X, X rows: [Ce; A; Ce*A; Ce*Bt; Ce]. MFMA.
// grid (LC/32, 2, B), 256 thr.
__global__ __launch_bounds__(256) void k_resizer_mfma(
    const float* __restrict__ Ce, const float* __restrict__ A,
    const float* __restrict__ Bt, const ushortT* __restrict__ wbf,
    float* __restrict__ y) {
  __shared__ __align__(16) ushortT xbf[16 * 32 * 4];  // [kg][c][4]
  int l0 = blockIdx.x * 32;
  int o0 = blockIdx.y * 64;
  int b = blockIdx.z;
  int tid = threadIdx.x;
  int w = tid >> 6, lane = tid & 63, g2 = lane >> 4, r = lane & 15;
  const ushortT* arow = wbf + (size_t)(o0 + 16 * w + r) * 1280;
  f32x4 acc0 = {0.f, 0.f, 0.f, 0.f}, acc1 = {0.f, 0.f, 0.f, 0.f};
  for (int kt = 0; kt < 1280; kt += 64) {
    __syncthreads();
    for (int idx = tid; idx < 2048; idx += 256) {
      int kloc = idx >> 5, cc = idx & 31;
      int ch = kt + kloc;
      int seg = ch >> 8;
      int j = ch & 255;
      size_t p = ((size_t)b * 256 + j) * LC_ + l0 + cc;
      float v;
      if (seg == 0 || seg == 4) v = Ce[p];
      else if (seg == 1) v = A[p];
      else if (seg == 2) v = Ce[p] * A[p];
      else v = Ce[p] * Bt[p];
      xbf[(((kloc >> 2) * 32) + cc) * 4 + (kloc & 3)] = (ushortT)bfr(v);
    }
    __syncthreads();
#pragma unroll
    for (int kk2 = 0; kk2 < 2; kk2++) {
      bf16x8 a = ldA(arow, kt + kk2 * 32 + g2 * 4);
      bf16x8 b0 = ldB2(&xbf[(((kk2 * 8 + g2) * 32) + r) * 4],
                       &xbf[(((kk2 * 8 + 4 + g2) * 32) + r) * 4]);
      acc0 = __builtin_amdgcn_mfma_f32_16x16x32_bf16(a, b0, acc0, 0, 0, 0);
      bf16x8 b1 = ldB2(&xbf[(((kk2 * 8 + g2) * 32) + 16 + r) * 4],
                       &xbf[(((kk2 * 8 + 4 + g2) * 32) + 16 + r) * 4]);
      acc1 = __builtin_amdgcn_mfma_f32_16x16x32_bf16(a, b1, acc1, 0, 0, 0);
    }
  }
#pragma unroll
  for (int p = 0; p < 4; p++) {
    int o = o0 + 16 * w + g2 * 4 + p;
    size_t base = ((size_t)b * D_ + o) * LC_ + l0;
    y[base + r] = acc0[p];
    y[base + 16 + r] = acc1[p];
  }
}

// ---------------------------------------------------------------- host side

struct BlkP {
  int n_conv, k;
  const float* lnc_g[4]; const float* lnc_b[4];
  const float* dw[4]; const ushortT* pw[4]; const float* pw_b[4];
  const ushortT* mem_w; const ushortT* q_w;
  const float* ln1_g; const float* ln1_b;
  const ushortT* ffn1_w; const float* ffn1_b;
  const ushortT* ffn2_w; const float* ffn2_b;
  const float* ln2_g; const float* ln2_b;
};

static void encoder_block(hipStream_t st, const float* xin, float* cur, float* aux,
                          float* mkv, float* qpb, const float* mask, int L, const BlkP& P) {
  dim3 gc(L / 32, 2, B_);
  const float* in = xin;
  for (int i = 0; i < P.n_conv; i++) {
    float* ob = (i % 2 == 0) ? aux : cur;
    if (P.k == 7) {
      if (i == 0) k_convlayer_mfma<7, 1><<<gc, 256, 0, st>>>(in, ob, P.dw[i], P.pw[i], P.pw_b[i], P.lnc_g[i], P.lnc_b[i], L);
      else        k_convlayer_mfma<7, 0><<<gc, 256, 0, st>>>(in, ob, P.dw[i], P.pw[i], P.pw_b[i], P.lnc_g[i], P.lnc_b[i], L);
    } else {
      if (i == 0) k_convlayer_mfma<5, 1><<<gc, 256, 0, st>>>(in, ob, P.dw[i], P.pw[i], P.pw_b[i], P.lnc_g[i], P.lnc_b[i], L);
      else        k_convlayer_mfma<5, 0><<<gc, 256, 0, st>>>(in, ob, P.dw[i], P.pw[i], P.pw_b[i], P.lnc_g[i], P.lnc_b[i], L);
    }
    in = ob;
  }
  k_lnproj_mfma<<<dim3(L / 64, 6, B_), 256, 0, st>>>(cur, P.mem_w, P.q_w, mkv, qpb, P.ln1_g, P.ln1_b, L);
  if (L % 128 == 0)
    k_attn_mfma<8><<<dim3(L / 64, H_, B_), 256, 0, st>>>(mkv, qpb, mask, cur, L);
  else
    k_attn_mfma<4><<<dim3(L / 64, H_, B_), 256, 0, st>>>(mkv, qpb, mask, cur, L);
  k_ffn_mfma<<<dim3(L / 16, 1, B_), 256, 0, st>>>(cur, P.ffn1_w, P.ffn1_b, P.ffn2_w, P.ffn2_b, P.ln2_g, P.ln2_b, L);
}

extern "C" void kernel_launch(void* const* d_in, const int* in_sizes, int n_in,
                              void* d_out, int out_size, void* d_ws, size_t ws_size,
                              hipStream_t stream) {
  (void)in_sizes; (void)n_in; (void)out_size; (void)ws_size;
  const float* C        = (const float*)d_in[0];
  const float* Q        = (const float*)d_in[1];
  const float* maskC    = (const float*)d_in[2];
  const float* maskQ    = (const float*)d_in[3];
  const float* e_dw     = (const float*)d_in[4];
  const float* e_pw     = (const float*)d_in[5];
  const float* e_pw_b   = (const float*)d_in[6];
  const float* e_lnc_g  = (const float*)d_in[7];
  const float* e_lnc_b  = (const float*)d_in[8];
  const float* e_mem_w  = (const float*)d_in[9];
  const float* e_q_w    = (const float*)d_in[10];
  const float* e_ffn1_w = (const float*)d_in[11];
  const float* e_ffn1_b = (const float*)d_in[12];
  const float* e_ffn2_w = (const float*)d_in[13];
  const float* e_ffn2_b = (const float*)d_in[14];
  const float* e_ln1_g  = (const float*)d_in[15];
  const float* e_ln1_b  = (const float*)d_in[16];
  const float* e_ln2_g  = (const float*)d_in[17];
  const float* e_ln2_b  = (const float*)d_in[18];
  const float* w4C      = (const float*)d_in[19];
  const float* w4Q      = (const float*)d_in[20];
  const float* w4mlu    = (const float*)d_in[21];
  const float* cq_b     = (const float*)d_in[22];
  const float* resizer_w= (const float*)d_in[23];
  const float* m_dw     = (const float*)d_in[24];
  const float* m_pw     = (const float*)d_in[25];
  const float* m_pw_b   = (const float*)d_in[26];
  const float* m_lnc_g  = (const float*)d_in[27];
  const float* m_lnc_b  = (const float*)d_in[28];
  const float* m_mem_w  = (const float*)d_in[29];
  const float* m_q_w    = (const float*)d_in[30];
  const float* m_ffn1_w = (const float*)d_in[31];
  const float* m_ffn1_b = (const float*)d_in[32];
  const float* m_ffn2_w = (const float*)d_in[33];
  const float* m_ffn2_b = (const float*)d_in[34];
  const float* m_ln1_g  = (const float*)d_in[35];
  const float* m_ln1_b  = (const float*)d_in[36];
  const float* m_ln2_g  = (const float*)d_in[37];
  const float* m_ln2_b  = (const float*)d_in[38];

  float* ws = (float*)d_ws;
  const size_t SB = (size_t)B_ * D_ * LC_;  // 524288
  float* cur  = ws;              // SB  (also aliased as Bb low half)
  float* aux  = cur + SB;        // SB  (Bb high half)
  float* mkv  = aux + SB;        // 2SB (also aliased as Ab)
  float* qpb  = mkv + 2 * SB;    // SB
  float* Ce   = qpb + SB;        // 2SB
  float* Qe   = Ce + 2 * SB;     // B*256*LQ = 131072
  float* Sbuf = Qe + (size_t)B_ * 256 * LQ_;       // 262144
  float* S1   = Sbuf + (size_t)B_ * LC_ * LQ_;     // 262144
  float* S2   = S1 + (size_t)B_ * LC_ * LQ_;       // 262144
  float* s0v  = S2 + (size_t)B_ * LC_ * LQ_;       // 4096
  float* s1v  = s0v + (size_t)B_ * LC_;            // 512
  float* Yb   = s1v + (size_t)B_ * LQ_;            // 131072
  float* Mb   = Yb + (size_t)B_ * 256 * LQ_;       // SB
  float* Ab   = mkv;             // alias: free during CQ section
  float* Bb   = cur;             // alias: cur+aux contiguous 2SB
  // bf16 weights after all float buffers (ends at Mb+SB = 5,247,488 floats)
  ushortT* wb = (ushortT*)(Mb + SB);
  ushortT* w_epw  = wb;            // 4*16384
  ushortT* w_emem = wb + 65536;    // 32768
  ushortT* w_eq   = wb + 98304;    // 16384
  ushortT* w_ef1  = wb + 114688;
  ushortT* w_ef2  = wb + 131072;
  ushortT* w_rsz  = wb + 147456;   // 163840
  ushortT* w_mpw  = wb + 311296;   // 14*16384
  ushortT* w_mmem = wb + 540672;   // 7*32768
  ushortT* w_mq   = wb + 770048;   // 7*16384
  ushortT* w_mf1  = wb + 884736;
  ushortT* w_mf2  = wb + 999424;   // end 1114112

  k_prep<<<(1114112 + 255) / 256, 256, 0, stream>>>(
      e_pw, e_mem_w, e_q_w, e_ffn1_w, e_ffn2_w, resizer_w,
      m_pw, m_mem_w, m_q_w, m_ffn1_w, m_ffn2_w, wb);

  BlkP ep{};
  ep.n_conv = 4; ep.k = 7;
  for (int i = 0; i < 4; i++) {
    ep.lnc_g[i] = e_lnc_g + i * 128;
    ep.lnc_b[i] = e_lnc_b + i * 128;
    ep.dw[i]    = e_dw + i * 128 * 7;
    ep.pw[i]    = w_epw + (size_t)i * 128 * 128;
    ep.pw_b[i]  = e_pw_b + i * 128;
  }
  ep.mem_w = w_emem; ep.q_w = w_eq;
  ep.ln1_g = e_ln1_g; ep.ln1_b = e_ln1_b;
  ep.ffn1_w = w_ef1; ep.ffn1_b = e_ffn1_b;
  ep.ffn2_w = w_ef2; ep.ffn2_b = e_ffn2_b;
  ep.ln2_g = e_ln2_g; ep.ln2_b = e_ln2_b;

  // ---- C encoder -> Ce ----
  encoder_block(stream, C, cur, aux, mkv, qpb, maskC, LC_, ep);
  {
    int tot = B_ * 256 * LC_;
    k_concat2<<<(tot + 255) / 256, 256, 0, stream>>>(cur, C, Ce, LC_, tot);
  }
  // ---- Q encoder -> Qe ----
  encoder_block(stream, Q, cur, aux, mkv, qpb, maskQ, LQ_, ep);
  {
    int tot = B_ * 256 * LQ_;
    k_concat2<<<(tot + 255) / 256, 256, 0, stream>>>(cur, Q, Qe, LQ_, tot);
  }

  // ---- CQ attention + resizer -> Mb ----
  k_chandot<<<(B_ * LC_ + 255) / 256, 256, 0, stream>>>(Ce, w4C, s0v, 256, LC_, B_ * LC_);
  k_chandot<<<(B_ * LQ_ + 255) / 256, 256, 0, stream>>>(Qe, w4Q, s1v, 256, LQ_, B_ * LQ_);
  k_cqSrow<<<(B_ * LC_ * LQ_) / 256, 256, 0, stream>>>(Ce, Qe, s0v, s1v, w4mlu, cq_b, maskQ, Sbuf, S1);
  k_softmax_col<<<B_ * LQ_, 256, 0, stream>>>(Sbuf, maskC, S2);
  k_cqY<<<(B_ * 256 * LQ_) / 256, 256, 0, stream>>>(S2, Ce, Yb);
  k_cqAB<<<dim3(LC_ / 64, 64, B_), 256, 0, stream>>>(S1, Qe, Yb, Ab, Bb);
  k_resizer_mfma<<<dim3(LC_ / 32, 2, B_), 256, 0, stream>>>(Ce, Ab, Bb, w_rsz, Mb);

  // ---- model encoder: 3 runs of 7 blocks ----
  float* out = (float*)d_out;
  const float* src = Mb;
  for (int r = 0; r < 3; r++) {
    for (int bi = 0; bi < 7; bi++) {
      BlkP mp{};
      mp.n_conv = 2; mp.k = 5;
      for (int ci = 0; ci < 2; ci++) {
        int pc = bi * 2 + ci;
        mp.lnc_g[ci] = m_lnc_g + pc * 128;
        mp.lnc_b[ci] = m_lnc_b + pc * 128;
        mp.dw[ci]    = m_dw + pc * 128 * 5;
        mp.pw[ci]    = w_mpw + (size_t)pc * 128 * 128;
        mp.pw_b[ci]  = m_pw_b + pc * 128;
      }
      mp.mem_w  = w_mmem + (size_t)bi * 256 * 128;
      mp.q_w    = w_mq + (size_t)bi * 128 * 128;
      mp.ffn1_w = w_mf1 + (size_t)bi * 128 * 128;
      mp.ffn1_b = m_ffn1_b + bi * 128;
      mp.ffn2_w = w_mf2 + (size_t)bi * 128 * 128;
      mp.ffn2_b = m_ffn2_b + bi * 128;
      mp.ln1_g = m_ln1_g + bi * 128; mp.ln1_b = m_ln1_b + bi * 128;
      mp.ln2_g = m_ln2_g + bi * 128; mp.ln2_b = m_ln2_b + bi * 128;
      encoder_block(stream, (bi == 0) ? src : cur, cur, aux, mkv, qpb, maskC, LC_, mp);
    }
    hipMemcpyAsync(out + (size_t)r * SB, cur, SB * sizeof(float),
                   hipMemcpyDeviceToDevice, stream);
    src = cur;
  }
}

// Round 6
// 1834.639 us; speedup vs baseline: 3.6118x; 1.3163x over previous
//
#include <hip/hip_runtime.h>
#include <math.h>

#define D_  128
#define B_  8
#define H_  8
#define LC_ 512
#define LQ_ 64

typedef float f32x4 __attribute__((ext_vector_type(4)));
typedef short bf16x8 __attribute__((ext_vector_type(8)));
typedef short short4v __attribute__((ext_vector_type(4)));
typedef unsigned short ushortT;

__device__ inline short bfr(float x) {
  unsigned u = __float_as_uint(x);
  u += 0x7fff + ((u >> 16) & 1);
  return (short)(u >> 16);
}

__device__ inline bf16x8 mk8(short4v lo, short4v hi) {
  bf16x8 r;
  r[0] = lo[0]; r[1] = lo[1]; r[2] = lo[2]; r[3] = lo[3];
  r[4] = hi[0]; r[5] = hi[1]; r[6] = hi[2]; r[7] = hi[3];
  return r;
}

// A-frag: W[m=lane&15][k], k = koff + g*4 + (j&3) + 16*(j>>2)
__device__ inline bf16x8 ldA(const ushortT* row, int koff) {
  short4v lo = *(const short4v*)(row + koff);
  short4v hi = *(const short4v*)(row + koff + 16);
  return mk8(lo, hi);
}
__device__ inline bf16x8 ldB2(const ushortT* plo, const ushortT* phi) {
  short4v lo = *(const short4v*)plo;
  short4v hi = *(const short4v*)phi;
  return mk8(lo, hi);
}

// ---------------------------------------------------------------- weight prep
__global__ void k_prep(const float* a0, const float* a1, const float* a2,
                       const float* a3, const float* a4, const float* a5,
                       const float* a6, const float* a7, const float* a8,
                       const float* a9, const float* a10, ushortT* dst) {
  int i = blockIdx.x * 256 + threadIdx.x;
  if (i >= 1114112) return;
  const float* s; int lo;
  if      (i <   65536) { s = a0;  lo = i; }
  else if (i <   98304) { s = a1;  lo = i - 65536; }
  else if (i <  114688) { s = a2;  lo = i - 98304; }
  else if (i <  131072) { s = a3;  lo = i - 114688; }
  else if (i <  147456) { s = a4;  lo = i - 131072; }
  else if (i <  311296) { s = a5;  lo = i - 147456; }
  else if (i <  540672) { s = a6;  lo = i - 311296; }
  else if (i <  770048) { s = a7;  lo = i - 540672; }
  else if (i <  884736) { s = a8;  lo = i - 770048; }
  else if (i <  999424) { s = a9;  lo = i - 884736; }
  else                  { s = a10; lo = i - 999424; }
  dst[i] = (ushortT)bfr(s[lo]);
}

// ---------------------------------------------------------------- conv layer
// [pos +] LN + dwconv (fp32) -> bf16 LDS -> MFMA pointwise + bias+relu+resid.
// grid (L/16, 2, B), 256 thr, 16-col tiles (occupancy). x != yout (halo).
template <int KK, int ADDPOS>
__global__ __launch_bounds__(256) void k_convlayer_mfma(
    const float* __restrict__ x, float* __restrict__ yout,
    const float* __restrict__ dwv, const ushortT* __restrict__ pwbf,
    const float* __restrict__ pwb, const float* __restrict__ g,
    const float* __restrict__ be, int L) {
  const int HALO = KK / 2;
  const int W = 16 + 2 * HALO;          // 22 (k=7) or 20 (k=5)
  __shared__ float raw[128 * 24];
  __shared__ __align__(16) ushortT xbf[32 * 16 * 4];  // [kg][c][4]
  __shared__ float mu_s[24], rs_s[24], ps[96], ps2[96];
  int l0 = blockIdx.x * 16;
  int o0 = blockIdx.y * 64;
  int b = blockIdx.z;
  int tid = threadIdx.x;
  for (int idx = tid; idx < 128 * W; idx += 256) {
    int d = idx / W, c = idx - d * W;
    int l = l0 + c - HALO;
    float v = 0.f;
    if (l >= 0 && l < L) {
      v = x[((size_t)b * 128 + d) * L + l];
      if (ADDPOS) {
        int j = d & 63;
        float arg = (float)l * expf(-(float)j * 0.14619588f);
        v += (d < 64) ? sinf(arg) : cosf(arg);
      }
    }
    raw[d * 24 + c] = v;
  }
  __syncthreads();
  if (tid < 4 * W) {
    int c = tid % W, hh = tid / W;
    float s = 0.f, s2 = 0.f;
    for (int d = hh * 32; d < hh * 32 + 32; d++) {
      float v = raw[d * 24 + c];
      s += v; s2 += v * v;
    }
    ps[tid] = s; ps2[tid] = s2;
  }
  __syncthreads();
  if (tid < W) {
    float s = ps[tid] + ps[tid + W] + ps[tid + 2 * W] + ps[tid + 3 * W];
    float s2 = ps2[tid] + ps2[tid + W] + ps2[tid + 2 * W] + ps2[tid + 3 * W];
    float mu = s * (1.f / 128.f);
    float var = fmaxf(s2 * (1.f / 128.f) - mu * mu, 0.f);
    mu_s[tid] = mu; rs_s[tid] = rsqrtf(var + 1e-5f);
  }
  __syncthreads();
  // dwconv of LN(x) -> bf16 packed LDS; thread: col cc0, channels dbase*8..+7
  int cc0 = tid & 15, dbase = tid >> 4;
#pragma unroll
  for (int kq = 0; kq < 2; kq++) {
    short4v pk;
#pragma unroll
    for (int e = 0; e < 4; e++) {
      int d = dbase * 8 + kq * 4 + e;
      float gg = g[d], bb = be[d];
      const float* wr = dwv + d * KK;
      float acc = 0.f;
#pragma unroll
      for (int t = 0; t < KK; t++) {
        int c = cc0 + t;
        int l = l0 + c - HALO;
        float lv = 0.f;
        if (l >= 0 && l < L)
          lv = (raw[d * 24 + c] - mu_s[c]) * rs_s[c] * gg + bb;
        acc += wr[t] * lv;
      }
      pk[e] = bfr(acc);
    }
    *(short4v*)&xbf[(((dbase * 2 + kq) * 16) + cc0) * 4] = pk;
  }
  __syncthreads();
  // MFMA pointwise: wave w -> o-tile o0+16w, 16 cols
  int w = tid >> 6, lane = tid & 63, g2 = lane >> 4, r = lane & 15;
  const ushortT* arow = pwbf + (size_t)(o0 + 16 * w + r) * 128;
  f32x4 acc0 = {0.f, 0.f, 0.f, 0.f};
#pragma unroll
  for (int kk = 0; kk < 4; kk++) {
    bf16x8 a = ldA(arow, kk * 32 + g2 * 4);
    bf16x8 b0 = ldB2(&xbf[(((kk * 8 + g2) * 16) + r) * 4],
                     &xbf[(((kk * 8 + 4 + g2) * 16) + r) * 4]);
    acc0 = __builtin_amdgcn_mfma_f32_16x16x32_bf16(a, b0, acc0, 0, 0, 0);
  }
#pragma unroll
  for (int p = 0; p < 4; p++) {
    int o = o0 + 16 * w + g2 * 4 + p;
    float bv = pwb[o];
    float r0 = raw[o * 24 + r + HALO];
    yout[((size_t)b * 128 + o) * L + l0 + r] = fmaxf(acc0[p] + bv, 0.f) + r0;
  }
}

// ---------------------------------------------------------------- ln + proj
// grid (L/32, 6, B), 32-col tiles: yb<4 -> mem (256 outs), yb>=4 -> q (128).
__global__ __launch_bounds__(256) void k_lnproj_mfma(
    const float* __restrict__ x, const ushortT* __restrict__ memw,
    const ushortT* __restrict__ qw, float* __restrict__ mkv,
    float* __restrict__ qp, const float* __restrict__ g,
    const float* __restrict__ be, int L) {
  __shared__ float xs[128 * 36];
  __shared__ __align__(16) ushortT xbf[32 * 32 * 4];
  __shared__ float mu_s[32], rs_s[32], ps[256], ps2[256];
  int l0 = blockIdx.x * 32;
  int b = blockIdx.z;
  int yb = blockIdx.y;
  const ushortT* wsel; float* out; int o0, O;
  if (yb < 4) { wsel = memw; out = mkv; o0 = yb * 64; O = 256; }
  else        { wsel = qw;   out = qp;  o0 = (yb - 4) * 64; O = 128; }
  int tid = threadIdx.x;
  for (int idx = tid; idx < 128 * 32; idx += 256) {
    int d = idx >> 5, c = idx & 31;
    xs[d * 36 + c] = x[((size_t)b * 128 + d) * L + l0 + c];
  }
  __syncthreads();
  {
    int c = tid & 31, qq = tid >> 5;
    float s = 0.f, s2 = 0.f;
    for (int d = qq * 16; d < qq * 16 + 16; d++) {
      float v = xs[d * 36 + c];
      s += v; s2 += v * v;
    }
    ps[tid] = s; ps2[tid] = s2;
  }
  __syncthreads();
  if (tid < 32) {
    float s = 0.f, s2 = 0.f;
#pragma unroll
    for (int qq = 0; qq < 8; qq++) { s += ps[qq * 32 + tid]; s2 += ps2[qq * 32 + tid]; }
    float mu = s * (1.f / 128.f);
    float var = fmaxf(s2 * (1.f / 128.f) - mu * mu, 0.f);
    mu_s[tid] = mu; rs_s[tid] = rsqrtf(var + 1e-5f);
  }
  __syncthreads();
  for (int idx = tid; idx < 128 * 32; idx += 256) {
    int d = idx >> 5, c = idx & 31;
    float val = (xs[d * 36 + c] - mu_s[c]) * rs_s[c] * g[d] + be[d];
    xbf[(((d >> 2) * 32) + c) * 4 + (d & 3)] = (ushortT)bfr(val);
  }
  __syncthreads();
  int w = tid >> 6, lane = tid & 63, g2 = lane >> 4, r = lane & 15;
  const ushortT* arow = wsel + (size_t)(o0 + 16 * w + r) * 128;
  f32x4 acc[2];
  acc[0] = (f32x4){0.f, 0.f, 0.f, 0.f};
  acc[1] = (f32x4){0.f, 0.f, 0.f, 0.f};
#pragma unroll
  for (int kk = 0; kk < 4; kk++) {
    bf16x8 a = ldA(arow, kk * 32 + g2 * 4);
#pragma unroll
    for (int nt = 0; nt < 2; nt++) {
      bf16x8 bb = ldB2(&xbf[(((kk * 8 + g2) * 32) + nt * 16 + r) * 4],
                       &xbf[(((kk * 8 + 4 + g2) * 32) + nt * 16 + r) * 4]);
      acc[nt] = __builtin_amdgcn_mfma_f32_16x16x32_bf16(a, bb, acc[nt], 0, 0, 0);
    }
  }
#pragma unroll
  for (int nt = 0; nt < 2; nt++) {
#pragma unroll
    for (int p = 0; p < 4; p++) {
      int o = o0 + 16 * w + g2 * 4 + p;
      out[((size_t)b * O + o) * L + l0 + nt * 16 + r] = acc[nt][p];
    }
  }
}

// ---------------------------------------------------------------- ffn
// LN + FFN1(relu) + FFN2 + bias + residual, in-place. grid (L/16, 1, B), 512 thr.
__global__ __launch_bounds__(512) void k_ffn_mfma(
    float* __restrict__ cur, const ushortT* __restrict__ w1bf,
    const float* __restrict__ b1, const ushortT* __restrict__ w2bf,
    const float* __restrict__ b2, const float* __restrict__ g,
    const float* __restrict__ be, int L) {
  __shared__ float xs[128 * 20];
  __shared__ __align__(16) ushortT xbf[32 * 16 * 4];
  __shared__ __align__(16) ushortT midbf[32 * 16 * 4];
  __shared__ float mu_s[16], rs_s[16], ps[512], ps2[512];
  int l0 = blockIdx.x * 16;
  int b = blockIdx.z;
  int tid = threadIdx.x;
  for (int idx = tid; idx < 128 * 16; idx += 512) {
    int d = idx >> 4, c = idx & 15;
    xs[d * 20 + c] = cur[((size_t)b * 128 + d) * L + l0 + c];
  }
  __syncthreads();
  {
    int c = tid & 15, hh = tid >> 4;   // hh 0..31, 4 channels each
    float s = 0.f, s2 = 0.f;
    for (int d = hh * 4; d < hh * 4 + 4; d++) {
      float v = xs[d * 20 + c];
      s += v; s2 += v * v;
    }
    ps[tid] = s; ps2[tid] = s2;
  }
  __syncthreads();
  if (tid < 16) {
    float s = 0.f, s2 = 0.f;
#pragma unroll
    for (int hh = 0; hh < 32; hh++) { s += ps[hh * 16 + tid]; s2 += ps2[hh * 16 + tid]; }
    float mu = s * (1.f / 128.f);
    float var = fmaxf(s2 * (1.f / 128.f) - mu * mu, 0.f);
    mu_s[tid] = mu; rs_s[tid] = rsqrtf(var + 1e-5f);
  }
  __syncthreads();
  for (int idx = tid; idx < 128 * 16; idx += 512) {
    int d = idx >> 4, c = idx & 15;
    float val = (xs[d * 20 + c] - mu_s[c]) * rs_s[c] * g[d] + be[d];
    xbf[(((d >> 2) * 16) + c) * 4 + (d & 3)] = (ushortT)bfr(val);
  }
  __syncthreads();
  int w = tid >> 6, lane = tid & 63, g2 = lane >> 4, r = lane & 15;  // w 0..7
  // GEMM1: wave w -> o-tile 16w
  {
    f32x4 acc = {0.f, 0.f, 0.f, 0.f};
    const ushortT* ar = w1bf + (size_t)(16 * w + r) * 128;
#pragma unroll
    for (int kk = 0; kk < 4; kk++) {
      bf16x8 a = ldA(ar, kk * 32 + g2 * 4);
      bf16x8 bb = ldB2(&xbf[(((kk * 8 + g2) * 16) + r) * 4],
                       &xbf[(((kk * 8 + 4 + g2) * 16) + r) * 4]);
      acc = __builtin_amdgcn_mfma_f32_16x16x32_bf16(a, bb, acc, 0, 0, 0);
    }
#pragma unroll
    for (int p = 0; p < 4; p++) {
      int dmid = 16 * w + g2 * 4 + p;
      float val = fmaxf(acc[p] + b1[dmid], 0.f);
      midbf[(((4 * w + g2) * 16) + r) * 4 + p] = (ushortT)bfr(val);
    }
  }
  __syncthreads();
  // GEMM2 + bias + residual
  {
    f32x4 a2 = {0.f, 0.f, 0.f, 0.f};
    const ushortT* ar = w2bf + (size_t)(16 * w + r) * 128;
#pragma unroll
    for (int kk = 0; kk < 4; kk++) {
      bf16x8 a = ldA(ar, kk * 32 + g2 * 4);
      bf16x8 bb = ldB2(&midbf[(((kk * 8 + g2) * 16) + r) * 4],
                       &midbf[(((kk * 8 + 4 + g2) * 16) + r) * 4]);
      a2 = __builtin_amdgcn_mfma_f32_16x16x32_bf16(a, bb, a2, 0, 0, 0);
    }
#pragma unroll
    for (int p = 0; p < 4; p++) {
      int o = 16 * w + g2 * 4 + p;
      size_t pos = ((size_t)b * 128 + o) * L + l0 + r;
      cur[pos] = a2[p] + b2[o] + cur[pos];
    }
  }
}

// ---------------------------------------------------------------- attention
// MFMA flash attention, key-split across wave pairs (flash-decoding merge).
// grid (L/32, H, B), 256 thr = 4 waves: qg = w&1 (16-query group), kh = w>>1.
template <int NCH>   // key chunks (16 keys) per inner tile; half-keys = multiple of NCH*16
__global__ __launch_bounds__(256) void k_attn_mfma(
    const float* __restrict__ memKV, const float* __restrict__ qp,
    const float* __restrict__ mask, float* __restrict__ cur, int L) {
  __shared__ float msh[4][64], ssh[4][64], Osh[4][64][4];
  int q0 = blockIdx.x * 32;
  int h = blockIdx.y, b = blockIdx.z;
  int tid = threadIdx.x;
  int w = tid >> 6;
  int qg = w & 1, kh = w >> 1;
  int lane = tid & 63;
  int g = lane >> 4, r = lane & 15;
  const float* qb = qp + ((size_t)b * 128 + h * 16) * L;
  const float* kb = memKV + ((size_t)b * 256 + h * 16) * L;
  const float* vb = memKV + ((size_t)b * 256 + 128 + h * 16) * L;
  const float* mk = mask + (size_t)b * L;
  int qcol = q0 + 16 * qg + r;
  bf16x8 qf;
#pragma unroll
  for (int j = 0; j < 4; j++)
    qf[j] = bfr(qb[(size_t)(g * 4 + j) * L + qcol] * 0.25f);
  qf[4] = 0; qf[5] = 0; qf[6] = 0; qf[7] = 0;
  float m_run = -INFINITY, ssum = 0.f;
  f32x4 O = {0.f, 0.f, 0.f, 0.f};
  int kbeg = kh * (L / 2), kend = (kh + 1) * (L / 2);
  for (int k0 = kbeg; k0 < kend; k0 += NCH * 16) {
    f32x4 sd[NCH];
#pragma unroll
    for (int mc = 0; mc < NCH; mc++) {
      bf16x8 kf;
      int krow = k0 + mc * 16 + r;
#pragma unroll
      for (int j = 0; j < 4; j++)
        kf[j] = bfr(kb[(size_t)(g * 4 + j) * L + krow]);
      kf[4] = 0; kf[5] = 0; kf[6] = 0; kf[7] = 0;
      f32x4 z = {0.f, 0.f, 0.f, 0.f};
      sd[mc] = __builtin_amdgcn_mfma_f32_16x16x32_bf16(kf, qf, z, 0, 0, 0);
    }
    float tm = -INFINITY;
#pragma unroll
    for (int mc = 0; mc < NCH; mc++) {
#pragma unroll
      for (int p = 0; p < 4; p++) {
        float mv = mk[k0 + mc * 16 + g * 4 + p];
        float sv = sd[mc][p] * mv + (1.f - mv) * (-1e30f);
        sd[mc][p] = sv;
        tm = fmaxf(tm, sv);
      }
    }
    tm = fmaxf(tm, __shfl_xor(tm, 16));
    tm = fmaxf(tm, __shfl_xor(tm, 32));
    float nm = fmaxf(m_run, tm);
    float c = __expf(m_run - nm);
    ssum *= c;
    O[0] *= c; O[1] *= c; O[2] *= c; O[3] *= c;
    float psum = 0.f;
    bf16x8 pf[NCH / 2];
#pragma unroll
    for (int c2 = 0; c2 < NCH / 2; c2++) {
#pragma unroll
      for (int j = 0; j < 4; j++) {
        float e0 = __expf(sd[2 * c2][j] - nm);
        float e1 = __expf(sd[2 * c2 + 1][j] - nm);
        psum += e0 + e1;
        pf[c2][j] = bfr(e0);
        pf[c2][j + 4] = bfr(e1);
      }
    }
    psum += __shfl_xor(psum, 16);
    psum += __shfl_xor(psum, 32);
    ssum += psum;
#pragma unroll
    for (int c2 = 0; c2 < NCH / 2; c2++) {
      const float* vrow = vb + (size_t)r * L + k0 + c2 * 32 + g * 4;
      float4 v0 = *(const float4*)vrow;
      float4 v1 = *(const float4*)(vrow + 16);
      bf16x8 vf;
      vf[0] = bfr(v0.x); vf[1] = bfr(v0.y); vf[2] = bfr(v0.z); vf[3] = bfr(v0.w);
      vf[4] = bfr(v1.x); vf[5] = bfr(v1.y); vf[6] = bfr(v1.z); vf[7] = bfr(v1.w);
      O = __builtin_amdgcn_mfma_f32_16x16x32_bf16(vf, pf[c2], O, 0, 0, 0);
    }
    m_run = nm;
  }
  // merge key-halves: wave pair (qg, kh=0) <- (qg, kh=1)
  msh[w][lane] = m_run;
  ssh[w][lane] = ssum;
#pragma unroll
  for (int p = 0; p < 4; p++) Osh[w][lane][p] = O[p];
  __syncthreads();
  if (kh == 0) {
    float mB = msh[w + 2][lane], sB = ssh[w + 2][lane];
    float nm = fmaxf(m_run, mB);
    float cA = __expf(m_run - nm), cB = __expf(mB - nm);
    float inv = 1.f / (ssum * cA + sB * cB);
    size_t ob = ((size_t)b * 128 + h * 16) * L + qcol;
#pragma unroll
    for (int p = 0; p < 4; p++) {
      float ov = (O[p] * cA + Osh[w + 2][lane][p] * cB) * inv;
      cur[ob + (size_t)(g * 4 + p) * L] += ov;
    }
  }
}

// ---------------------------------------------------------------- CQ section

__global__ void k_concat2(const float* __restrict__ x1, const float* __restrict__ x2,
                          float* __restrict__ out, int L, int total) {
  int idx = blockIdx.x * 256 + threadIdx.x;
  if (idx >= total) return;
  int l = idx % L;
  int c = (idx / L) & 255;
  int b = idx / (L * 256);
  float v = (c < 128) ? x1[((size_t)b * 128 + c) * L + l]
                      : x2[((size_t)b * 128 + (c - 128)) * L + l];
  out[idx] = v;
}

__global__ void k_chandot(const float* __restrict__ X, const float* __restrict__ w,
                          float* __restrict__ out, int C, int L, int total) {
  int idx = blockIdx.x * 256 + threadIdx.x;
  if (idx >= total) return;
  int l = idx % L;
  int b = idx / L;
  const float* xb = X + (size_t)b * C * L + l;
  float s = 0.f;
  for (int j = 0; j < C; j++) s += xb[(size_t)j * L] * w[j];
  out[idx] = s;
}

__global__ void k_cqSrow(const float* __restrict__ Ce, const float* __restrict__ Qe,
                         const float* __restrict__ s0, const float* __restrict__ s1,
                         const float* __restrict__ w4mlu, const float* __restrict__ cqb,
                         const float* __restrict__ qmask,
                         float* __restrict__ S, float* __restrict__ S1) {
  int idx = blockIdx.x * 256 + threadIdx.x;
  int q = idx & 63;
  int l = (idx >> 6) % LC_;
  int b = (idx >> 6) / LC_;
  const float* ce = Ce + (size_t)b * 256 * LC_ + l;
  const float* qe = Qe + (size_t)b * 256 * LQ_ + q;
  float acc = 0.f;
#pragma unroll 8
  for (int j = 0; j < 256; j++) acc += ce[(size_t)j * LC_] * w4mlu[j] * qe[(size_t)j * LQ_];
  float sv = acc + s0[b * LC_ + l] + s1[b * LQ_ + q] + cqb[0];
  S[idx] = sv;
  float mv = qmask[b * LQ_ + q];
  float v = sv * mv + (1.f - mv) * (-1e30f);
  float mx = v;
  for (int off = 32; off; off >>= 1) mx = fmaxf(mx, __shfl_xor(mx, off));
  float p = expf(v - mx);
  float s = p;
  for (int off = 32; off; off >>= 1) s += __shfl_xor(s, off);
  S1[idx] = p / s;
}

__global__ __launch_bounds__(256) void k_softmax_col(
    const float* __restrict__ S, const float* __restrict__ cmask, float* __restrict__ S2) {
  int q = blockIdx.x & 63, b = blockIdx.x >> 6;
  int tid = threadIdx.x;
  __shared__ float redm[4], reds[4];
  const float* col = S + (size_t)b * LC_ * LQ_ + q;
  const float* mk = cmask + b * LC_;
  float vm[2];
#pragma unroll
  for (int k = 0; k < 2; k++) {
    int l = tid + 256 * k;
    float mv = mk[l];
    vm[k] = col[(size_t)l * LQ_] * mv + (1.f - mv) * (-1e30f);
  }
  float mx = fmaxf(vm[0], vm[1]);
  for (int off = 32; off; off >>= 1) mx = fmaxf(mx, __shfl_xor(mx, off));
  if ((tid & 63) == 0) redm[tid >> 6] = mx;
  __syncthreads();
  mx = fmaxf(fmaxf(redm[0], redm[1]), fmaxf(redm[2], redm[3]));
  float e0 = expf(vm[0] - mx), e1 = expf(vm[1] - mx);
  float s = e0 + e1;
  for (int off = 32; off; off >>= 1) s += __shfl_xor(s, off);
  if ((tid & 63) == 0) reds[tid >> 6] = s;
  __syncthreads();
  float invs = 1.f / (reds[0] + reds[1] + reds[2] + reds[3]);
  float* out = S2 + (size_t)b * LC_ * LQ_ + q;
  out[(size_t)tid * LQ_] = e0 * invs;
  out[(size_t)(tid + 256) * LQ_] = e1 * invs;
}

__global__ void k_cqY(const float* __restrict__ S2, const float* __restrict__ Ce,
                      float* __restrict__ Y) {
  int idx = blockIdx.x * 256 + threadIdx.x;
  if (idx >= B_ * 256 * LQ_) return;
  int q = idx & 63;
  int j = (idx >> 6) & 255;
  int b = idx >> 14;
  const float* s2 = S2 + (size_t)b * LC_ * LQ_ + q;
  const float* ce = Ce + ((size_t)b * 256 + j) * LC_;
  float acc = 0.f;
  for (int l = 0; l < LC_; l++) acc += s2[(size_t)l * LQ_] * ce[l];
  Y[idx] = acc;
}

__global__ __launch_bounds__(256) void k_cqAB(
    const float* __restrict__ S1, const float* __restrict__ Qe, const float* __restrict__ Y,
    float* __restrict__ A, float* __restrict__ Bt) {
  __shared__ float s1s[64][65];
  int l0 = blockIdx.x * 64;
  int b = blockIdx.z;
  int tid = threadIdx.x;
  for (int idx = tid; idx < 64 * 64; idx += 256) {
    int l = idx >> 6, q = idx & 63;
    s1s[l][q] = S1[((size_t)b * LC_ + l0 + l) * LQ_ + q];
  }
  __syncthreads();
  int ll = tid & 63, jj = tid >> 6;
  int j = blockIdx.y * 4 + jj;
  const float* qe = Qe + ((size_t)b * 256 + j) * LQ_;
  const float* yb = Y + ((size_t)b * 256 + j) * LQ_;
  float a = 0.f, bt = 0.f;
#pragma unroll 8
  for (int q = 0; q < 64; q++) {
    float sv = s1s[ll][q];
    a += sv * qe[q];
    bt += sv * yb[q];
  }
  A[((size_t)b * 256 + j) * LC_ + l0 + ll] = a;
  Bt[((size_t)b * 256 + j) * LC_ + l0 + ll] = bt;
}

// M0 = resizer_w [128,1280] @ X, X rows: [Ce; A; Ce*A; Ce*Bt; Ce]. MFMA.
// grid (LC/16, 2, B), 16-col tiles (occupancy).
__global__ __launch_bounds__(256) void k_resizer_mfma(
    const float* __restrict__ Ce, const float* __restrict__ A,
    const float* __restrict__ Bt, const ushortT* __restrict__ wbf,
    float* __restrict__ y) {
  __shared__ __align__(16) ushortT xbf[16 * 16 * 4];  // [kg][c][4]
  int l0 = blockIdx.x * 16;
  int o0 = blockIdx.y * 64;
  int b = blockIdx.z;
  int tid = threadIdx.x;
  int w = tid >> 6, lane = tid & 63, g2 = lane >> 4, r = lane & 15;
  const ushortT* arow = wbf + (size_t)(o0 + 16 * w + r) * 1280;
  f32x4 acc0 = {0.f, 0.f, 0.f, 0.f};
  for (int kt = 0; kt < 1280; kt += 64) {
    __syncthreads();
    for (int idx = tid; idx < 1024; idx += 256) {
      int kloc = idx >> 4, cc = idx & 15;
      int ch = kt + kloc;
      int seg = ch >> 8;
      int j = ch & 255;
      size_t p = ((size_t)b * 256 + j) * LC_ + l0 + cc;
      float v;
      if (seg == 0 || seg == 4) v = Ce[p];
      else if (seg == 1) v = A[p];
      else if (seg == 2) v = Ce[p] * A[p];
      else v = Ce[p] * Bt[p];
      xbf[(((kloc >> 2) * 16) + cc) * 4 + (kloc & 3)] = (ushortT)bfr(v);
    }
    __syncthreads();
#pragma unroll
    for (int kk2 = 0; kk2 < 2; kk2++) {
      bf16x8 a = ldA(arow, kt + kk2 * 32 + g2 * 4);
      bf16x8 b0 = ldB2(&xbf[(((kk2 * 8 + g2) * 16) + r) * 4],
                       &xbf[(((kk2 * 8 + 4 + g2) * 16) + r) * 4]);
      acc0 = __builtin_amdgcn_mfma_f32_16x16x32_bf16(a, b0, acc0, 0, 0, 0);
    }
  }
#pragma unroll
  for (int p = 0; p < 4; p++) {
    int o = o0 + 16 * w + g2 * 4 + p;
    y[((size_t)b * D_ + o) * LC_ + l0 + r] = acc0[p];
  }
}

// ---------------------------------------------------------------- host side

struct BlkP {
  int n_conv, k;
  const float* lnc_g[4]; const float* lnc_b[4];
  const float* dw[4]; const ushortT* pw[4]; const float* pw_b[4];
  const ushortT* mem_w; const ushortT* q_w;
  const float* ln1_g; const float* ln1_b;
  const ushortT* ffn1_w; const float* ffn1_b;
  const ushortT* ffn2_w; const float* ffn2_b;
  const float* ln2_g; const float* ln2_b;
};

static void encoder_block(hipStream_t st, const float* xin, float* cur, float* aux,
                          float* mkv, float* qpb, const float* mask, int L, const BlkP& P) {
  dim3 gc(L / 16, 2, B_);
  const float* in = xin;
  for (int i = 0; i < P.n_conv; i++) {
    float* ob = (i % 2 == 0) ? aux : cur;
    if (P.k == 7) {
      if (i == 0) k_convlayer_mfma<7, 1><<<gc, 256, 0, st>>>(in, ob, P.dw[i], P.pw[i], P.pw_b[i], P.lnc_g[i], P.lnc_b[i], L);
      else        k_convlayer_mfma<7, 0><<<gc, 256, 0, st>>>(in, ob, P.dw[i], P.pw[i], P.pw_b[i], P.lnc_g[i], P.lnc_b[i], L);
    } else {
      if (i == 0) k_convlayer_mfma<5, 1><<<gc, 256, 0, st>>>(in, ob, P.dw[i], P.pw[i], P.pw_b[i], P.lnc_g[i], P.lnc_b[i], L);
      else        k_convlayer_mfma<5, 0><<<gc, 256, 0, st>>>(in, ob, P.dw[i], P.pw[i], P.pw_b[i], P.lnc_g[i], P.lnc_b[i], L);
    }
    in = ob;
  }
  k_lnproj_mfma<<<dim3(L / 32, 6, B_), 256, 0, st>>>(cur, P.mem_w, P.q_w, mkv, qpb, P.ln1_g, P.ln1_b, L);
  if (L == LC_)
    k_attn_mfma<8><<<dim3(L / 32, H_, B_), 256, 0, st>>>(mkv, qpb, mask, cur, L);
  else
    k_attn_mfma<2><<<dim3(L / 32, H_, B_), 256, 0, st>>>(mkv, qpb, mask, cur, L);
  k_ffn_mfma<<<dim3(L / 16, 1, B_), 512, 0, st>>>(cur, P.ffn1_w, P.ffn1_b, P.ffn2_w, P.ffn2_b, P.ln2_g, P.ln2_b, L);
}

extern "C" void kernel_launch(void* const* d_in, const int* in_sizes, int n_in,
                              void* d_out, int out_size, void* d_ws, size_t ws_size,
                              hipStream_t stream) {
  (void)in_sizes; (void)n_in; (void)out_size; (void)ws_size;
  const float* C        = (const float*)d_in[0];
  const float* Q        = (const float*)d_in[1];
  const float* maskC    = (const float*)d_in[2];
  const float* maskQ    = (const float*)d_in[3];
  const float* e_dw     = (const float*)d_in[4];
  const float* e_pw     = (const float*)d_in[5];
  const float* e_pw_b   = (const float*)d_in[6];
  const float* e_lnc_g  = (const float*)d_in[7];
  const float* e_lnc_b  = (const float*)d_in[8];
  const float* e_mem_w  = (const float*)d_in[9];
  const float* e_q_w    = (const float*)d_in[10];
  const float* e_ffn1_w = (const float*)d_in[11];
  const float* e_ffn1_b = (const float*)d_in[12];
  const float* e_ffn2_w = (const float*)d_in[13];
  const float* e_ffn2_b = (const float*)d_in[14];
  const float* e_ln1_g  = (const float*)d_in[15];
  const float* e_ln1_b  = (const float*)d_in[16];
  const float* e_ln2_g  = (const float*)d_in[17];
  const float* e_ln2_b  = (const float*)d_in[18];
  const float* w4C      = (const float*)d_in[19];
  const float* w4Q      = (const float*)d_in[20];
  const float* w4mlu    = (const float*)d_in[21];
  const float* cq_b     = (const float*)d_in[22];
  const float* resizer_w= (const float*)d_in[23];
  const float* m_dw     = (const float*)d_in[24];
  const float* m_pw     = (const float*)d_in[25];
  const float* m_pw_b   = (const float*)d_in[26];
  const float* m_lnc_g  = (const float*)d_in[27];
  const float* m_lnc_b  = (const float*)d_in[28];
  const float* m_mem_w  = (const float*)d_in[29];
  const float* m_q_w    = (const float*)d_in[30];
  const float* m_ffn1_w = (const float*)d_in[31];
  const float* m_ffn1_b = (const float*)d_in[32];
  const float* m_ffn2_w = (const float*)d_in[33];
  const float* m_ffn2_b = (const float*)d_in[34];
  const float* m_ln1_g  = (const float*)d_in[35];
  const float* m_ln1_b  = (const float*)d_in[36];
  const float* m_ln2_g  = (const float*)d_in[37];
  const float* m_ln2_b  = (const float*)d_in[38];

  float* ws = (float*)d_ws;
  const size_t SB = (size_t)B_ * D_ * LC_;  // 524288
  float* cur  = ws;
  float* aux  = cur + SB;
  float* mkv  = aux + SB;
  float* qpb  = mkv + 2 * SB;
  float* Ce   = qpb + SB;
  float* Qe   = Ce + 2 * SB;
  float* Sbuf = Qe + (size_t)B_ * 256 * LQ_;
  float* S1   = Sbuf + (size_t)B_ * LC_ * LQ_;
  float* S2   = S1 + (size_t)B_ * LC_ * LQ_;
  float* s0v  = S2 + (size_t)B_ * LC_ * LQ_;
  float* s1v  = s0v + (size_t)B_ * LC_;
  float* Yb   = s1v + (size_t)B_ * LQ_;
  float* Mb   = Yb + (size_t)B_ * 256 * LQ_;
  float* Ab   = mkv;   // alias: free during CQ section
  float* Bb   = cur;   // alias: cur+aux contiguous 2SB
  ushortT* wb = (ushortT*)(Mb + SB);
  ushortT* w_epw  = wb;
  ushortT* w_emem = wb + 65536;
  ushortT* w_eq   = wb + 98304;
  ushortT* w_ef1  = wb + 114688;
  ushortT* w_ef2  = wb + 131072;
  ushortT* w_rsz  = wb + 147456;
  ushortT* w_mpw  = wb + 311296;
  ushortT* w_mmem = wb + 540672;
  ushortT* w_mq   = wb + 770048;
  ushortT* w_mf1  = wb + 884736;
  ushortT* w_mf2  = wb + 999424;

  k_prep<<<(1114112 + 255) / 256, 256, 0, stream>>>(
      e_pw, e_mem_w, e_q_w, e_ffn1_w, e_ffn2_w, resizer_w,
      m_pw, m_mem_w, m_q_w, m_ffn1_w, m_ffn2_w, wb);

  BlkP ep{};
  ep.n_conv = 4; ep.k = 7;
  for (int i = 0; i < 4; i++) {
    ep.lnc_g[i] = e_lnc_g + i * 128;
    ep.lnc_b[i] = e_lnc_b + i * 128;
    ep.dw[i]    = e_dw + i * 128 * 7;
    ep.pw[i]    = w_epw + (size_t)i * 128 * 128;
    ep.pw_b[i]  = e_pw_b + i * 128;
  }
  ep.mem_w = w_emem; ep.q_w = w_eq;
  ep.ln1_g = e_ln1_g; ep.ln1_b = e_ln1_b;
  ep.ffn1_w = w_ef1; ep.ffn1_b = e_ffn1_b;
  ep.ffn2_w = w_ef2; ep.ffn2_b = e_ffn2_b;
  ep.ln2_g = e_ln2_g; ep.ln2_b = e_ln2_b;

  // ---- C encoder -> Ce ----
  encoder_block(stream, C, cur, aux, mkv, qpb, maskC, LC_, ep);
  {
    int tot = B_ * 256 * LC_;
    k_concat2<<<(tot + 255) / 256, 256, 0, stream>>>(cur, C, Ce, LC_, tot);
  }
  // ---- Q encoder -> Qe ----
  encoder_block(stream, Q, cur, aux, mkv, qpb, maskQ, LQ_, ep);
  {
    int tot = B_ * 256 * LQ_;
    k_concat2<<<(tot + 255) / 256, 256, 0, stream>>>(cur, Q, Qe, LQ_, tot);
  }

  // ---- CQ attention + resizer -> Mb ----
  k_chandot<<<(B_ * LC_ + 255) / 256, 256, 0, stream>>>(Ce, w4C, s0v, 256, LC_, B_ * LC_);
  k_chandot<<<(B_ * LQ_ + 255) / 256, 256, 0, stream>>>(Qe, w4Q, s1v, 256, LQ_, B_ * LQ_);
  k_cqSrow<<<(B_ * LC_ * LQ_) / 256, 256, 0, stream>>>(Ce, Qe, s0v, s1v, w4mlu, cq_b, maskQ, Sbuf, S1);
  k_softmax_col<<<B_ * LQ_, 256, 0, stream>>>(Sbuf, maskC, S2);
  k_cqY<<<(B_ * 256 * LQ_) / 256, 256, 0, stream>>>(S2, Ce, Yb);
  k_cqAB<<<dim3(LC_ / 64, 64, B_), 256, 0, stream>>>(S1, Qe, Yb, Ab, Bb);
  k_resizer_mfma<<<dim3(LC_ / 16, 2, B_), 256, 0, stream>>>(Ce, Ab, Bb, w_rsz, Mb);

  // ---- model encoder: 3 runs of 7 blocks ----
  float* out = (float*)d_out;
  const float* src = Mb;
  for (int r = 0; r < 3; r++) {
    for (int bi = 0; bi < 7; bi++) {
      BlkP mp{};
      mp.n_conv = 2; mp.k = 5;
      for (int ci = 0; ci < 2; ci++) {
        int pc = bi * 2 + ci;
        mp.lnc_g[ci] = m_lnc_g + pc * 128;
        mp.lnc_b[ci] = m_lnc_b + pc * 128;
        mp.dw[ci]    = m_dw + pc * 128 * 5;
        mp.pw[ci]    = w_mpw + (size_t)pc * 128 * 128;
        mp.pw_b[ci]  = m_pw_b + pc * 128;
      }
      mp.mem_w  = w_mmem + (size_t)bi * 256 * 128;
      mp.q_w    = w_mq + (size_t)bi * 128 * 128;
      mp.ffn1_w = w_mf1 + (size_t)bi * 128 * 128;
      mp.ffn1_b = m_ffn1_b + bi * 128;
      mp.ffn2_w = w_mf2 + (size_t)bi * 128 * 128;
      mp.ffn2_b = m_ffn2_b + bi * 128;
      mp.ln1_g = m_ln1_g + bi * 128; mp.ln1_b = m_ln1_b + bi * 128;
      mp.ln2_g = m_ln2_g + bi * 128; mp.ln2_b = m_ln2_b + bi * 128;
      encoder_block(stream, (bi == 0) ? src : cur, cur, aux, mkv, qpb, maskC, LC_, mp);
    }
    hipMemcpyAsync(out + (size_t)r * SB, cur, SB * sizeof(float),
                   hipMemcpyDeviceToDevice, stream);
    src = cur;
  }
}

// Round 7
// 1758.287 us; speedup vs baseline: 3.7687x; 1.0434x over previous
//
#include <hip/hip_runtime.h>
#include <math.h>

#define D_  128
#define B_  8
#define H_  8
#define LC_ 512
#define LQ_ 64

typedef float f32x4 __attribute__((ext_vector_type(4)));
typedef short bf16x8 __attribute__((ext_vector_type(8)));
typedef short short4v __attribute__((ext_vector_type(4)));
typedef unsigned short ushortT;

__device__ inline short bfr(float x) {
  unsigned u = __float_as_uint(x);
  u += 0x7fff + ((u >> 16) & 1);
  return (short)(u >> 16);
}

__device__ inline bf16x8 mk8(short4v lo, short4v hi) {
  bf16x8 r;
  r[0] = lo[0]; r[1] = lo[1]; r[2] = lo[2]; r[3] = lo[3];
  r[4] = hi[0]; r[5] = hi[1]; r[6] = hi[2]; r[7] = hi[3];
  return r;
}

// A-frag: W[m=lane&15][k], k = koff + g*4 + (j&3) + 16*(j>>2)
__device__ inline bf16x8 ldA(const ushortT* row, int koff) {
  short4v lo = *(const short4v*)(row + koff);
  short4v hi = *(const short4v*)(row + koff + 16);
  return mk8(lo, hi);
}
__device__ inline bf16x8 ldB2(const ushortT* plo, const ushortT* phi) {
  short4v lo = *(const short4v*)plo;
  short4v hi = *(const short4v*)phi;
  return mk8(lo, hi);
}

// ---------------------------------------------------------------- weight prep
__global__ void k_prep(const float* a0, const float* a1, const float* a2,
                       const float* a3, const float* a4, const float* a5,
                       const float* a6, const float* a7, const float* a8,
                       const float* a9, const float* a10, ushortT* dst) {
  int i = blockIdx.x * 256 + threadIdx.x;
  if (i >= 1114112) return;
  const float* s; int lo;
  if      (i <   65536) { s = a0;  lo = i; }
  else if (i <   98304) { s = a1;  lo = i - 65536; }
  else if (i <  114688) { s = a2;  lo = i - 98304; }
  else if (i <  131072) { s = a3;  lo = i - 114688; }
  else if (i <  147456) { s = a4;  lo = i - 131072; }
  else if (i <  311296) { s = a5;  lo = i - 147456; }
  else if (i <  540672) { s = a6;  lo = i - 311296; }
  else if (i <  770048) { s = a7;  lo = i - 540672; }
  else if (i <  884736) { s = a8;  lo = i - 770048; }
  else if (i <  999424) { s = a9;  lo = i - 884736; }
  else                  { s = a10; lo = i - 999424; }
  dst[i] = (ushortT)bfr(s[lo]);
}

// ---------------------------------------------------------------- fused double conv
// Two conv layers ([pos+]LN+dwconv+PW+relu+residual each) in one kernel.
// Layer1 computed on a 32-col window [l0-8, l0+24) (all 128 outs, in LDS);
// layer2 on the interior 16 cols [l0, l0+16), outs [o0, o0+64).
// grid (L/16, 2, B), 256 thr. x != yout.
template <int KK, int ADDPOS>
__global__ __launch_bounds__(256) void k_fusedconv(
    const float* __restrict__ x, float* __restrict__ yout,
    const float* __restrict__ dw1, const ushortT* __restrict__ pw1,
    const float* __restrict__ pb1, const float* __restrict__ g1,
    const float* __restrict__ be1,
    const float* __restrict__ dw2, const ushortT* __restrict__ pw2,
    const float* __restrict__ pb2, const float* __restrict__ g2w,
    const float* __restrict__ be2, int L) {
  const int HALO = KK / 2;
  const int W1 = 32 + 2 * HALO;                 // raw window (38 / 36)
  __shared__ float raw[128 * 40];               // x(+pos), col ci <-> gl = l0-8-HALO+ci
  __shared__ float l1o[128 * 36];               // layer1 out, col c1 <-> gl = l0-8+c1
  __shared__ __align__(16) ushortT xbf1[32 * 32 * 4];
  __shared__ __align__(16) ushortT xbf2[32 * 16 * 4];
  __shared__ float mu1[40], rs1[40], mu2[32], rs2[32], ps[160], psq[160];
  int l0 = blockIdx.x * 16;
  int o0 = blockIdx.y * 64;
  int b = blockIdx.z;
  int tid = threadIdx.x;
  // ---- stage raw (+pos) ----
  for (int idx = tid; idx < 128 * W1; idx += 256) {
    int d = idx / W1, c = idx - d * W1;
    int gl = l0 - 8 - HALO + c;
    float v = 0.f;
    if (gl >= 0 && gl < L) {
      v = x[((size_t)b * 128 + d) * L + gl];
      if (ADDPOS) {
        int j = d & 63;
        float arg = (float)gl * expf(-(float)j * 0.14619588f);
        v += (d < 64) ? sinf(arg) : cosf(arg);
      }
    }
    raw[d * 40 + c] = v;
  }
  __syncthreads();
  // ---- LN1 stats ----
  if (tid < 4 * W1) {
    int c = tid % W1, hh = tid / W1;
    float s = 0.f, s2 = 0.f;
    for (int d = hh * 32; d < hh * 32 + 32; d++) {
      float v = raw[d * 40 + c];
      s += v; s2 += v * v;
    }
    ps[tid] = s; psq[tid] = s2;
  }
  __syncthreads();
  if (tid < W1) {
    float s = ps[tid] + ps[tid + W1] + ps[tid + 2 * W1] + ps[tid + 3 * W1];
    float s2 = psq[tid] + psq[tid + W1] + psq[tid + 2 * W1] + psq[tid + 3 * W1];
    float mu = s * (1.f / 128.f);
    float var = fmaxf(s2 * (1.f / 128.f) - mu * mu, 0.f);
    mu1[tid] = mu; rs1[tid] = rsqrtf(var + 1e-5f);
  }
  __syncthreads();
  // ---- dwconv1 (all 128 ch x 32 cols) -> bf16 xbf1 ----
  {
    int cc0 = tid & 31, dbase = tid >> 5;       // 32 cols x 8 ch-groups (16 ch each)
#pragma unroll
    for (int kq = 0; kq < 4; kq++) {
      short4v pk;
#pragma unroll
      for (int e = 0; e < 4; e++) {
        int d = dbase * 16 + kq * 4 + e;
        float gg = g1[d], bb = be1[d];
        const float* wr = dw1 + d * KK;
        float acc = 0.f;
#pragma unroll
        for (int t = 0; t < KK; t++) {
          int ci = cc0 + t;
          int gl = l0 - 8 - HALO + ci;
          float lv = 0.f;
          if (gl >= 0 && gl < L)
            lv = (raw[d * 40 + ci] - mu1[ci]) * rs1[ci] * gg + bb;
          acc += wr[t] * lv;
        }
        pk[e] = bfr(acc);
      }
      *(short4v*)&xbf1[(((dbase * 4 + kq) * 32) + cc0) * 4] = pk;
    }
  }
  __syncthreads();
  // ---- GEMM1: 128 outs x 32 cols; wave w -> m-tiles {2w, 2w+1} ----
  int w = tid >> 6, lane = tid & 63, g2 = lane >> 4, r = lane & 15;
  {
    f32x4 acc[2][2];
#pragma unroll
    for (int i = 0; i < 2; i++)
#pragma unroll
      for (int nt = 0; nt < 2; nt++) acc[i][nt] = (f32x4){0.f, 0.f, 0.f, 0.f};
#pragma unroll
    for (int i = 0; i < 2; i++) {
      const ushortT* arow = pw1 + (size_t)((2 * w + i) * 16 + r) * 128;
#pragma unroll
      for (int kk = 0; kk < 4; kk++) {
        bf16x8 a = ldA(arow, kk * 32 + g2 * 4);
#pragma unroll
        for (int nt = 0; nt < 2; nt++) {
          bf16x8 bb = ldB2(&xbf1[(((kk * 8 + g2) * 32) + nt * 16 + r) * 4],
                           &xbf1[(((kk * 8 + 4 + g2) * 32) + nt * 16 + r) * 4]);
          acc[i][nt] = __builtin_amdgcn_mfma_f32_16x16x32_bf16(a, bb, acc[i][nt], 0, 0, 0);
        }
      }
    }
    // l1out = relu(acc+b)+resid, zero outside [0,L)
#pragma unroll
    for (int i = 0; i < 2; i++)
#pragma unroll
      for (int nt = 0; nt < 2; nt++)
#pragma unroll
        for (int p = 0; p < 4; p++) {
          int o = (2 * w + i) * 16 + g2 * 4 + p;
          int c1 = nt * 16 + r;
          int gl = l0 - 8 + c1;
          float val = 0.f;
          if (gl >= 0 && gl < L)
            val = fmaxf(acc[i][nt][p] + pb1[o], 0.f) + raw[o * 40 + c1 + HALO];
          l1o[o * 36 + c1] = val;
        }
  }
  __syncthreads();
  // ---- LN2 stats (32 cols) ----
  if (tid < 128) {
    int c = tid & 31, hh = tid >> 5;
    float s = 0.f, s2 = 0.f;
    for (int d = hh * 32; d < hh * 32 + 32; d++) {
      float v = l1o[d * 36 + c];
      s += v; s2 += v * v;
    }
    ps[tid] = s; psq[tid] = s2;
  }
  __syncthreads();
  if (tid < 32) {
    float s = ps[tid] + ps[tid + 32] + ps[tid + 64] + ps[tid + 96];
    float s2 = psq[tid] + psq[tid + 32] + psq[tid + 64] + psq[tid + 96];
    float mu = s * (1.f / 128.f);
    float var = fmaxf(s2 * (1.f / 128.f) - mu * mu, 0.f);
    mu2[tid] = mu; rs2[tid] = rsqrtf(var + 1e-5f);
  }
  __syncthreads();
  // ---- dwconv2 (128 ch x 16 cols) -> bf16 xbf2 ----
  {
    int cc2 = tid & 15, db2 = tid >> 4;         // 16 cols x 16 ch-groups (8 ch each)
#pragma unroll
    for (int kq = 0; kq < 2; kq++) {
      short4v pk;
#pragma unroll
      for (int e = 0; e < 4; e++) {
        int d = db2 * 8 + kq * 4 + e;
        float gg = g2w[d], bb = be2[d];
        const float* wr = dw2 + d * KK;
        float acc = 0.f;
#pragma unroll
        for (int t = 0; t < KK; t++) {
          int c1 = cc2 + 8 + t - HALO;
          int gl = l0 + cc2 + t - HALO;
          float lv = 0.f;
          if (gl >= 0 && gl < L)
            lv = (l1o[d * 36 + c1] - mu2[c1]) * rs2[c1] * gg + bb;
          acc += wr[t] * lv;
        }
        pk[e] = bfr(acc);
      }
      *(short4v*)&xbf2[(((db2 * 2 + kq) * 16) + cc2) * 4] = pk;
    }
  }
  __syncthreads();
  // ---- GEMM2: 64 outs (o0..o0+64) x 16 cols; wave w -> 1 m-tile ----
  {
    f32x4 a2 = {0.f, 0.f, 0.f, 0.f};
    const ushortT* arow = pw2 + (size_t)(o0 + 16 * w + r) * 128;
#pragma unroll
    for (int kk = 0; kk < 4; kk++) {
      bf16x8 a = ldA(arow, kk * 32 + g2 * 4);
      bf16x8 bb = ldB2(&xbf2[(((kk * 8 + g2) * 16) + r) * 4],
                       &xbf2[(((kk * 8 + 4 + g2) * 16) + r) * 4]);
      a2 = __builtin_amdgcn_mfma_f32_16x16x32_bf16(a, bb, a2, 0, 0, 0);
    }
#pragma unroll
    for (int p = 0; p < 4; p++) {
      int o = o0 + 16 * w + g2 * 4 + p;
      yout[((size_t)b * 128 + o) * L + l0 + r] =
          fmaxf(a2[p] + pb2[o], 0.f) + l1o[o * 36 + 8 + r];
    }
  }
}

// ---------------------------------------------------------------- ln + proj
__global__ __launch_bounds__(256) void k_lnproj_mfma(
    const float* __restrict__ x, const ushortT* __restrict__ memw,
    const ushortT* __restrict__ qw, float* __restrict__ mkv,
    float* __restrict__ qp, const float* __restrict__ g,
    const float* __restrict__ be, int L) {
  __shared__ float xs[128 * 36];
  __shared__ __align__(16) ushortT xbf[32 * 32 * 4];
  __shared__ float mu_s[32], rs_s[32], ps[256], ps2[256];
  int l0 = blockIdx.x * 32;
  int b = blockIdx.z;
  int yb = blockIdx.y;
  const ushortT* wsel; float* out; int o0, O;
  if (yb < 4) { wsel = memw; out = mkv; o0 = yb * 64; O = 256; }
  else        { wsel = qw;   out = qp;  o0 = (yb - 4) * 64; O = 128; }
  int tid = threadIdx.x;
  for (int idx = tid; idx < 128 * 32; idx += 256) {
    int d = idx >> 5, c = idx & 31;
    xs[d * 36 + c] = x[((size_t)b * 128 + d) * L + l0 + c];
  }
  __syncthreads();
  {
    int c = tid & 31, qq = tid >> 5;
    float s = 0.f, s2 = 0.f;
    for (int d = qq * 16; d < qq * 16 + 16; d++) {
      float v = xs[d * 36 + c];
      s += v; s2 += v * v;
    }
    ps[tid] = s; ps2[tid] = s2;
  }
  __syncthreads();
  if (tid < 32) {
    float s = 0.f, s2 = 0.f;
#pragma unroll
    for (int qq = 0; qq < 8; qq++) { s += ps[qq * 32 + tid]; s2 += ps2[qq * 32 + tid]; }
    float mu = s * (1.f / 128.f);
    float var = fmaxf(s2 * (1.f / 128.f) - mu * mu, 0.f);
    mu_s[tid] = mu; rs_s[tid] = rsqrtf(var + 1e-5f);
  }
  __syncthreads();
  for (int idx = tid; idx < 128 * 32; idx += 256) {
    int d = idx >> 5, c = idx & 31;
    float val = (xs[d * 36 + c] - mu_s[c]) * rs_s[c] * g[d] + be[d];
    xbf[(((d >> 2) * 32) + c) * 4 + (d & 3)] = (ushortT)bfr(val);
  }
  __syncthreads();
  int w = tid >> 6, lane = tid & 63, g2 = lane >> 4, r = lane & 15;
  const ushortT* arow = wsel + (size_t)(o0 + 16 * w + r) * 128;
  f32x4 acc[2];
  acc[0] = (f32x4){0.f, 0.f, 0.f, 0.f};
  acc[1] = (f32x4){0.f, 0.f, 0.f, 0.f};
#pragma unroll
  for (int kk = 0; kk < 4; kk++) {
    bf16x8 a = ldA(arow, kk * 32 + g2 * 4);
#pragma unroll
    for (int nt = 0; nt < 2; nt++) {
      bf16x8 bb = ldB2(&xbf[(((kk * 8 + g2) * 32) + nt * 16 + r) * 4],
                       &xbf[(((kk * 8 + 4 + g2) * 32) + nt * 16 + r) * 4]);
      acc[nt] = __builtin_amdgcn_mfma_f32_16x16x32_bf16(a, bb, acc[nt], 0, 0, 0);
    }
  }
#pragma unroll
  for (int nt = 0; nt < 2; nt++) {
#pragma unroll
    for (int p = 0; p < 4; p++) {
      int o = o0 + 16 * w + g2 * 4 + p;
      out[((size_t)b * O + o) * L + l0 + nt * 16 + r] = acc[nt][p];
    }
  }
}

// ---------------------------------------------------------------- ffn
__global__ __launch_bounds__(512) void k_ffn_mfma(
    float* __restrict__ cur, const ushortT* __restrict__ w1bf,
    const float* __restrict__ b1, const ushortT* __restrict__ w2bf,
    const float* __restrict__ b2, const float* __restrict__ g,
    const float* __restrict__ be, int L) {
  __shared__ float xs[128 * 20];
  __shared__ __align__(16) ushortT xbf[32 * 16 * 4];
  __shared__ __align__(16) ushortT midbf[32 * 16 * 4];
  __shared__ float mu_s[16], rs_s[16], ps[512], ps2[512];
  int l0 = blockIdx.x * 16;
  int b = blockIdx.z;
  int tid = threadIdx.x;
  for (int idx = tid; idx < 128 * 16; idx += 512) {
    int d = idx >> 4, c = idx & 15;
    xs[d * 20 + c] = cur[((size_t)b * 128 + d) * L + l0 + c];
  }
  __syncthreads();
  {
    int c = tid & 15, hh = tid >> 4;
    float s = 0.f, s2 = 0.f;
    for (int d = hh * 4; d < hh * 4 + 4; d++) {
      float v = xs[d * 20 + c];
      s += v; s2 += v * v;
    }
    ps[tid] = s; ps2[tid] = s2;
  }
  __syncthreads();
  if (tid < 16) {
    float s = 0.f, s2 = 0.f;
#pragma unroll
    for (int hh = 0; hh < 32; hh++) { s += ps[hh * 16 + tid]; s2 += ps2[hh * 16 + tid]; }
    float mu = s * (1.f / 128.f);
    float var = fmaxf(s2 * (1.f / 128.f) - mu * mu, 0.f);
    mu_s[tid] = mu; rs_s[tid] = rsqrtf(var + 1e-5f);
  }
  __syncthreads();
  for (int idx = tid; idx < 128 * 16; idx += 512) {
    int d = idx >> 4, c = idx & 15;
    float val = (xs[d * 20 + c] - mu_s[c]) * rs_s[c] * g[d] + be[d];
    xbf[(((d >> 2) * 16) + c) * 4 + (d & 3)] = (ushortT)bfr(val);
  }
  __syncthreads();
  int w = tid >> 6, lane = tid & 63, g2 = lane >> 4, r = lane & 15;
  {
    f32x4 acc = {0.f, 0.f, 0.f, 0.f};
    const ushortT* ar = w1bf + (size_t)(16 * w + r) * 128;
#pragma unroll
    for (int kk = 0; kk < 4; kk++) {
      bf16x8 a = ldA(ar, kk * 32 + g2 * 4);
      bf16x8 bb = ldB2(&xbf[(((kk * 8 + g2) * 16) + r) * 4],
                       &xbf[(((kk * 8 + 4 + g2) * 16) + r) * 4]);
      acc = __builtin_amdgcn_mfma_f32_16x16x32_bf16(a, bb, acc, 0, 0, 0);
    }
#pragma unroll
    for (int p = 0; p < 4; p++) {
      int dmid = 16 * w + g2 * 4 + p;
      float val = fmaxf(acc[p] + b1[dmid], 0.f);
      midbf[(((4 * w + g2) * 16) + r) * 4 + p] = (ushortT)bfr(val);
    }
  }
  __syncthreads();
  {
    f32x4 a2 = {0.f, 0.f, 0.f, 0.f};
    const ushortT* ar = w2bf + (size_t)(16 * w + r) * 128;
#pragma unroll
    for (int kk = 0; kk < 4; kk++) {
      bf16x8 a = ldA(ar, kk * 32 + g2 * 4);
      bf16x8 bb = ldB2(&midbf[(((kk * 8 + g2) * 16) + r) * 4],
                       &midbf[(((kk * 8 + 4 + g2) * 16) + r) * 4]);
      a2 = __builtin_amdgcn_mfma_f32_16x16x32_bf16(a, bb, a2, 0, 0, 0);
    }
#pragma unroll
    for (int p = 0; p < 4; p++) {
      int o = 16 * w + g2 * 4 + p;
      size_t pos = ((size_t)b * 128 + o) * L + l0 + r;
      cur[pos] = a2[p] + b2[o] + cur[pos];
    }
  }
}

// ---------------------------------------------------------------- attention
template <int NCH>
__global__ __launch_bounds__(256) void k_attn_mfma(
    const float* __restrict__ memKV, const float* __restrict__ qp,
    const float* __restrict__ mask, float* __restrict__ cur, int L) {
  __shared__ float msh[4][64], ssh[4][64], Osh[4][64][4];
  int q0 = blockIdx.x * 32;
  int h = blockIdx.y, b = blockIdx.z;
  int tid = threadIdx.x;
  int w = tid >> 6;
  int qg = w & 1, kh = w >> 1;
  int lane = tid & 63;
  int g = lane >> 4, r = lane & 15;
  const float* qb = qp + ((size_t)b * 128 + h * 16) * L;
  const float* kb = memKV + ((size_t)b * 256 + h * 16) * L;
  const float* vb = memKV + ((size_t)b * 256 + 128 + h * 16) * L;
  const float* mk = mask + (size_t)b * L;
  int qcol = q0 + 16 * qg + r;
  bf16x8 qf;
#pragma unroll
  for (int j = 0; j < 4; j++)
    qf[j] = bfr(qb[(size_t)(g * 4 + j) * L + qcol] * 0.25f);
  qf[4] = 0; qf[5] = 0; qf[6] = 0; qf[7] = 0;
  float m_run = -INFINITY, ssum = 0.f;
  f32x4 O = {0.f, 0.f, 0.f, 0.f};
  int kbeg = kh * (L / 2), kend = (kh + 1) * (L / 2);
  for (int k0 = kbeg; k0 < kend; k0 += NCH * 16) {
    f32x4 sd[NCH];
#pragma unroll
    for (int mc = 0; mc < NCH; mc++) {
      bf16x8 kf;
      int krow = k0 + mc * 16 + r;
#pragma unroll
      for (int j = 0; j < 4; j++)
        kf[j] = bfr(kb[(size_t)(g * 4 + j) * L + krow]);
      kf[4] = 0; kf[5] = 0; kf[6] = 0; kf[7] = 0;
      f32x4 z = {0.f, 0.f, 0.f, 0.f};
      sd[mc] = __builtin_amdgcn_mfma_f32_16x16x32_bf16(kf, qf, z, 0, 0, 0);
    }
    float tm = -INFINITY;
#pragma unroll
    for (int mc = 0; mc < NCH; mc++) {
#pragma unroll
      for (int p = 0; p < 4; p++) {
        float mv = mk[k0 + mc * 16 + g * 4 + p];
        float sv = sd[mc][p] * mv + (1.f - mv) * (-1e30f);
        sd[mc][p] = sv;
        tm = fmaxf(tm, sv);
      }
    }
    tm = fmaxf(tm, __shfl_xor(tm, 16));
    tm = fmaxf(tm, __shfl_xor(tm, 32));
    float nm = fmaxf(m_run, tm);
    float c = __expf(m_run - nm);
    ssum *= c;
    O[0] *= c; O[1] *= c; O[2] *= c; O[3] *= c;
    float psum = 0.f;
    bf16x8 pf[NCH / 2];
#pragma unroll
    for (int c2 = 0; c2 < NCH / 2; c2++) {
#pragma unroll
      for (int j = 0; j < 4; j++) {
        float e0 = __expf(sd[2 * c2][j] - nm);
        float e1 = __expf(sd[2 * c2 + 1][j] - nm);
        psum += e0 + e1;
        pf[c2][j] = bfr(e0);
        pf[c2][j + 4] = bfr(e1);
      }
    }
    psum += __shfl_xor(psum, 16);
    psum += __shfl_xor(psum, 32);
    ssum += psum;
#pragma unroll
    for (int c2 = 0; c2 < NCH / 2; c2++) {
      const float* vrow = vb + (size_t)r * L + k0 + c2 * 32 + g * 4;
      float4 v0 = *(const float4*)vrow;
      float4 v1 = *(const float4*)(vrow + 16);
      bf16x8 vf;
      vf[0] = bfr(v0.x); vf[1] = bfr(v0.y); vf[2] = bfr(v0.z); vf[3] = bfr(v0.w);
      vf[4] = bfr(v1.x); vf[5] = bfr(v1.y); vf[6] = bfr(v1.z); vf[7] = bfr(v1.w);
      O = __builtin_amdgcn_mfma_f32_16x16x32_bf16(vf, pf[c2], O, 0, 0, 0);
    }
    m_run = nm;
  }
  msh[w][lane] = m_run;
  ssh[w][lane] = ssum;
#pragma unroll
  for (int p = 0; p < 4; p++) Osh[w][lane][p] = O[p];
  __syncthreads();
  if (kh == 0) {
    float mB = msh[w + 2][lane], sB = ssh[w + 2][lane];
    float nm = fmaxf(m_run, mB);
    float cA = __expf(m_run - nm), cB = __expf(mB - nm);
    float inv = 1.f / (ssum * cA + sB * cB);
    size_t ob = ((size_t)b * 128 + h * 16) * L + qcol;
#pragma unroll
    for (int p = 0; p < 4; p++) {
      float ov = (O[p] * cA + Osh[w + 2][lane][p] * cB) * inv;
      cur[ob + (size_t)(g * 4 + p) * L] += ov;
    }
  }
}

// ---------------------------------------------------------------- CQ section

__global__ void k_concat2(const float* __restrict__ x1, const float* __restrict__ x2,
                          float* __restrict__ out, int L, int total) {
  int idx = blockIdx.x * 256 + threadIdx.x;
  if (idx >= total) return;
  int l = idx % L;
  int c = (idx / L) & 255;
  int b = idx / (L * 256);
  float v = (c < 128) ? x1[((size_t)b * 128 + c) * L + l]
                      : x2[((size_t)b * 128 + (c - 128)) * L + l];
  out[idx] = v;
}

// S build + s0/s1 inline + fused row softmax.
__global__ void k_cqSrow(const float* __restrict__ Ce, const float* __restrict__ Qe,
                         const float* __restrict__ w4C, const float* __restrict__ w4Q,
                         const float* __restrict__ w4mlu, const float* __restrict__ cqb,
                         const float* __restrict__ qmask,
                         float* __restrict__ S, float* __restrict__ S1) {
  int idx = blockIdx.x * 256 + threadIdx.x;
  int q = idx & 63;
  int l = (idx >> 6) % LC_;
  int b = (idx >> 6) / LC_;
  const float* ce = Ce + (size_t)b * 256 * LC_ + l;
  const float* qe = Qe + (size_t)b * 256 * LQ_ + q;
  float acc = 0.f, a0 = 0.f, a1 = 0.f;
#pragma unroll 8
  for (int j = 0; j < 256; j++) {
    float cv = ce[(size_t)j * LC_];
    float qv = qe[(size_t)j * LQ_];
    acc += cv * w4mlu[j] * qv;
    a0 += cv * w4C[j];
    a1 += qv * w4Q[j];
  }
  float sv = acc + a0 + a1 + cqb[0];
  S[idx] = sv;
  float mv = qmask[b * LQ_ + q];
  float v = sv * mv + (1.f - mv) * (-1e30f);
  float mx = v;
  for (int off = 32; off; off >>= 1) mx = fmaxf(mx, __shfl_xor(mx, off));
  float p = expf(v - mx);
  float s = p;
  for (int off = 32; off; off >>= 1) s += __shfl_xor(s, off);
  S1[idx] = p / s;
}

__global__ __launch_bounds__(256) void k_softmax_col(
    const float* __restrict__ S, const float* __restrict__ cmask, float* __restrict__ S2) {
  int q = blockIdx.x & 63, b = blockIdx.x >> 6;
  int tid = threadIdx.x;
  __shared__ float redm[4], reds[4];
  const float* col = S + (size_t)b * LC_ * LQ_ + q;
  const float* mk = cmask + b * LC_;
  float vm[2];
#pragma unroll
  for (int k = 0; k < 2; k++) {
    int l = tid + 256 * k;
    float mv = mk[l];
    vm[k] = col[(size_t)l * LQ_] * mv + (1.f - mv) * (-1e30f);
  }
  float mx = fmaxf(vm[0], vm[1]);
  for (int off = 32; off; off >>= 1) mx = fmaxf(mx, __shfl_xor(mx, off));
  if ((tid & 63) == 0) redm[tid >> 6] = mx;
  __syncthreads();
  mx = fmaxf(fmaxf(redm[0], redm[1]), fmaxf(redm[2], redm[3]));
  float e0 = expf(vm[0] - mx), e1 = expf(vm[1] - mx);
  float s = e0 + e1;
  for (int off = 32; off; off >>= 1) s += __shfl_xor(s, off);
  if ((tid & 63) == 0) reds[tid >> 6] = s;
  __syncthreads();
  float invs = 1.f / (reds[0] + reds[1] + reds[2] + reds[3]);
  float* out = S2 + (size_t)b * LC_ * LQ_ + q;
  out[(size_t)tid * LQ_] = e0 * invs;
  out[(size_t)(tid + 256) * LQ_] = e1 * invs;
}

__global__ void k_cqY(const float* __restrict__ S2, const float* __restrict__ Ce,
                      float* __restrict__ Y) {
  int idx = blockIdx.x * 256 + threadIdx.x;
  if (idx >= B_ * 256 * LQ_) return;
  int q = idx & 63;
  int j = (idx >> 6) & 255;
  int b = idx >> 14;
  const float* s2 = S2 + (size_t)b * LC_ * LQ_ + q;
  const float* ce = Ce + ((size_t)b * 256 + j) * LC_;
  float acc = 0.f;
#pragma unroll 8
  for (int l = 0; l < LC_; l++) acc += s2[(size_t)l * LQ_] * ce[l];
  Y[idx] = acc;
}

__global__ __launch_bounds__(256) void k_cqAB(
    const float* __restrict__ S1, const float* __restrict__ Qe, const float* __restrict__ Y,
    float* __restrict__ A, float* __restrict__ Bt) {
  __shared__ float s1s[64][65];
  int l0 = blockIdx.x * 64;
  int b = blockIdx.z;
  int tid = threadIdx.x;
  for (int idx = tid; idx < 64 * 64; idx += 256) {
    int l = idx >> 6, q = idx & 63;
    s1s[l][q] = S1[((size_t)b * LC_ + l0 + l) * LQ_ + q];
  }
  __syncthreads();
  int ll = tid & 63, jj = tid >> 6;
  int j = blockIdx.y * 4 + jj;
  const float* qe = Qe + ((size_t)b * 256 + j) * LQ_;
  const float* yb = Y + ((size_t)b * 256 + j) * LQ_;
  float a = 0.f, bt = 0.f;
#pragma unroll 8
  for (int q = 0; q < 64; q++) {
    float sv = s1s[ll][q];
    a += sv * qe[q];
    bt += sv * yb[q];
  }
  A[((size_t)b * 256 + j) * LC_ + l0 + ll] = a;
  Bt[((size_t)b * 256 + j) * LC_ + l0 + ll] = bt;
}

// M0 = resizer_w [128,1280] @ X, X rows: [Ce; A; Ce*A; Ce*Bt; Ce]. MFMA.
__global__ __launch_bounds__(256) void k_resizer_mfma(
    const float* __restrict__ Ce, const float* __restrict__ A,
    const float* __restrict__ Bt, const ushortT* __restrict__ wbf,
    float* __restrict__ y) {
  __shared__ __align__(16) ushortT xbf[16 * 16 * 4];
  int l0 = blockIdx.x * 16;
  int o0 = blockIdx.y * 64;
  int b = blockIdx.z;
  int tid = threadIdx.x;
  int w = tid >> 6, lane = tid & 63, g2 = lane >> 4, r = lane & 15;
  const ushortT* arow = wbf + (size_t)(o0 + 16 * w + r) * 1280;
  f32x4 acc0 = {0.f, 0.f, 0.f, 0.f};
  for (int kt = 0; kt < 1280; kt += 64) {
    __syncthreads();
    for (int idx = tid; idx < 1024; idx += 256) {
      int kloc = idx >> 4, cc = idx & 15;
      int ch = kt + kloc;
      int seg = ch >> 8;
      int j = ch & 255;
      size_t p = ((size_t)b * 256 + j) * LC_ + l0 + cc;
      float v;
      if (seg == 0 || seg == 4) v = Ce[p];
      else if (seg == 1) v = A[p];
      else if (seg == 2) v = Ce[p] * A[p];
      else v = Ce[p] * Bt[p];
      xbf[(((kloc >> 2) * 16) + cc) * 4 + (kloc & 3)] = (ushortT)bfr(v);
    }
    __syncthreads();
#pragma unroll
    for (int kk2 = 0; kk2 < 2; kk2++) {
      bf16x8 a = ldA(arow, kt + kk2 * 32 + g2 * 4);
      bf16x8 b0 = ldB2(&xbf[(((kk2 * 8 + g2) * 16) + r) * 4],
                       &xbf[(((kk2 * 8 + 4 + g2) * 16) + r) * 4]);
      acc0 = __builtin_amdgcn_mfma_f32_16x16x32_bf16(a, b0, acc0, 0, 0, 0);
    }
  }
#pragma unroll
  for (int p = 0; p < 4; p++) {
    int o = o0 + 16 * w + g2 * 4 + p;
    y[((size_t)b * D_ + o) * LC_ + l0 + r] = acc0[p];
  }
}

// ---------------------------------------------------------------- host side

struct BlkP {
  int n_conv, k;
  const float* lnc_g[4]; const float* lnc_b[4];
  const float* dw[4]; const ushortT* pw[4]; const float* pw_b[4];
  const ushortT* mem_w; const ushortT* q_w;
  const float* ln1_g; const float* ln1_b;
  const ushortT* ffn1_w; const float* ffn1_b;
  const ushortT* ffn2_w; const float* ffn2_b;
  const float* ln2_g; const float* ln2_b;
};

static void fused_conv_pair(hipStream_t st, const float* in, float* out, int L,
                            const BlkP& P, int i0, bool addpos) {
  dim3 gc(L / 16, 2, B_);
  if (P.k == 7) {
    if (addpos)
      k_fusedconv<7, 1><<<gc, 256, 0, st>>>(in, out,
          P.dw[i0], P.pw[i0], P.pw_b[i0], P.lnc_g[i0], P.lnc_b[i0],
          P.dw[i0+1], P.pw[i0+1], P.pw_b[i0+1], P.lnc_g[i0+1], P.lnc_b[i0+1], L);
    else
      k_fusedconv<7, 0><<<gc, 256, 0, st>>>(in, out,
          P.dw[i0], P.pw[i0], P.pw_b[i0], P.lnc_g[i0], P.lnc_b[i0],
          P.dw[i0+1], P.pw[i0+1], P.pw_b[i0+1], P.lnc_g[i0+1], P.lnc_b[i0+1], L);
  } else {
    if (addpos)
      k_fusedconv<5, 1><<<gc, 256, 0, st>>>(in, out,
          P.dw[i0], P.pw[i0], P.pw_b[i0], P.lnc_g[i0], P.lnc_b[i0],
          P.dw[i0+1], P.pw[i0+1], P.pw_b[i0+1], P.lnc_g[i0+1], P.lnc_b[i0+1], L);
    else
      k_fusedconv<5, 0><<<gc, 256, 0, st>>>(in, out,
          P.dw[i0], P.pw[i0], P.pw_b[i0], P.lnc_g[i0], P.lnc_b[i0],
          P.dw[i0+1], P.pw[i0+1], P.pw_b[i0+1], P.lnc_g[i0+1], P.lnc_b[i0+1], L);
  }
}

static void encoder_tail(hipStream_t st, float* out, float* mkv, float* qpb,
                         const float* mask, int L, const BlkP& P) {
  k_lnproj_mfma<<<dim3(L / 32, 6, B_), 256, 0, st>>>(out, P.mem_w, P.q_w, mkv, qpb, P.ln1_g, P.ln1_b, L);
  if (L == LC_)
    k_attn_mfma<8><<<dim3(L / 32, H_, B_), 256, 0, st>>>(mkv, qpb, mask, out, L);
  else
    k_attn_mfma<2><<<dim3(L / 32, H_, B_), 256, 0, st>>>(mkv, qpb, mask, out, L);
  k_ffn_mfma<<<dim3(L / 16, 1, B_), 512, 0, st>>>(out, P.ffn1_w, P.ffn1_b, P.ffn2_w, P.ffn2_b, P.ln2_g, P.ln2_b, L);
}

extern "C" void kernel_launch(void* const* d_in, const int* in_sizes, int n_in,
                              void* d_out, int out_size, void* d_ws, size_t ws_size,
                              hipStream_t stream) {
  (void)in_sizes; (void)n_in; (void)out_size; (void)ws_size;
  const float* C        = (const float*)d_in[0];
  const float* Q        = (const float*)d_in[1];
  const float* maskC    = (const float*)d_in[2];
  const float* maskQ    = (const float*)d_in[3];
  const float* e_dw     = (const float*)d_in[4];
  const float* e_pw     = (const float*)d_in[5];
  const float* e_pw_b   = (const float*)d_in[6];
  const float* e_lnc_g  = (const float*)d_in[7];
  const float* e_lnc_b  = (const float*)d_in[8];
  const float* e_mem_w  = (const float*)d_in[9];
  const float* e_q_w    = (const float*)d_in[10];
  const float* e_ffn1_w = (const float*)d_in[11];
  const float* e_ffn1_b = (const float*)d_in[12];
  const float* e_ffn2_w = (const float*)d_in[13];
  const float* e_ffn2_b = (const float*)d_in[14];
  const float* e_ln1_g  = (const float*)d_in[15];
  const float* e_ln1_b  = (const float*)d_in[16];
  const float* e_ln2_g  = (const float*)d_in[17];
  const float* e_ln2_b  = (const float*)d_in[18];
  const float* w4C      = (const float*)d_in[19];
  const float* w4Q      = (const float*)d_in[20];
  const float* w4mlu    = (const float*)d_in[21];
  const float* cq_b     = (const float*)d_in[22];
  const float* resizer_w= (const float*)d_in[23];
  const float* m_dw     = (const float*)d_in[24];
  const float* m_pw     = (const float*)d_in[25];
  const float* m_pw_b   = (const float*)d_in[26];
  const float* m_lnc_g  = (const float*)d_in[27];
  const float* m_lnc_b  = (const float*)d_in[28];
  const float* m_mem_w  = (const float*)d_in[29];
  const float* m_q_w    = (const float*)d_in[30];
  const float* m_ffn1_w = (const float*)d_in[31];
  const float* m_ffn1_b = (const float*)d_in[32];
  const float* m_ffn2_w = (const float*)d_in[33];
  const float* m_ffn2_b = (const float*)d_in[34];
  const float* m_ln1_g  = (const float*)d_in[35];
  const float* m_ln1_b  = (const float*)d_in[36];
  const float* m_ln2_g  = (const float*)d_in[37];
  const float* m_ln2_b  = (const float*)d_in[38];

  float* ws = (float*)d_ws;
  const size_t SB = (size_t)B_ * D_ * LC_;  // 524288
  float* cur  = ws;
  float* aux  = cur + SB;
  float* mkv  = aux + SB;
  float* qpb  = mkv + 2 * SB;
  float* Ce   = qpb + SB;
  float* Qe   = Ce + 2 * SB;
  float* Sbuf = Qe + (size_t)B_ * 256 * LQ_;
  float* S1   = Sbuf + (size_t)B_ * LC_ * LQ_;
  float* S2   = S1 + (size_t)B_ * LC_ * LQ_;
  float* Yb   = S2 + (size_t)B_ * LC_ * LQ_;
  float* Mb   = Yb + (size_t)B_ * 256 * LQ_;
  float* Ab   = mkv;   // alias: free during CQ section
  float* Bb   = cur;   // alias: cur+aux contiguous 2SB
  ushortT* wb = (ushortT*)(Mb + SB);
  ushortT* w_epw  = wb;
  ushortT* w_emem = wb + 65536;
  ushortT* w_eq   = wb + 98304;
  ushortT* w_ef1  = wb + 114688;
  ushortT* w_ef2  = wb + 131072;
  ushortT* w_rsz  = wb + 147456;
  ushortT* w_mpw  = wb + 311296;
  ushortT* w_mmem = wb + 540672;
  ushortT* w_mq   = wb + 770048;
  ushortT* w_mf1  = wb + 884736;
  ushortT* w_mf2  = wb + 999424;

  k_prep<<<(1114112 + 255) / 256, 256, 0, stream>>>(
      e_pw, e_mem_w, e_q_w, e_ffn1_w, e_ffn2_w, resizer_w,
      m_pw, m_mem_w, m_q_w, m_ffn1_w, m_ffn2_w, wb);

  BlkP ep{};
  ep.n_conv = 4; ep.k = 7;
  for (int i = 0; i < 4; i++) {
    ep.lnc_g[i] = e_lnc_g + i * 128;
    ep.lnc_b[i] = e_lnc_b + i * 128;
    ep.dw[i]    = e_dw + i * 128 * 7;
    ep.pw[i]    = w_epw + (size_t)i * 128 * 128;
    ep.pw_b[i]  = e_pw_b + i * 128;
  }
  ep.mem_w = w_emem; ep.q_w = w_eq;
  ep.ln1_g = e_ln1_g; ep.ln1_b = e_ln1_b;
  ep.ffn1_w = w_ef1; ep.ffn1_b = e_ffn1_b;
  ep.ffn2_w = w_ef2; ep.ffn2_b = e_ffn2_b;
  ep.ln2_g = e_ln2_g; ep.ln2_b = e_ln2_b;

  // ---- C encoder: convs 0-1 (pos) -> cur, convs 2-3 -> aux, tail on aux ----
  fused_conv_pair(stream, C, cur, LC_, ep, 0, true);
  fused_conv_pair(stream, cur, aux, LC_, ep, 2, false);
  encoder_tail(stream, aux, mkv, qpb, maskC, LC_, ep);
  {
    int tot = B_ * 256 * LC_;
    k_concat2<<<(tot + 255) / 256, 256, 0, stream>>>(aux, C, Ce, LC_, tot);
  }
  // ---- Q encoder ----
  fused_conv_pair(stream, Q, cur, LQ_, ep, 0, true);
  fused_conv_pair(stream, cur, aux, LQ_, ep, 2, false);
  encoder_tail(stream, aux, mkv, qpb, maskQ, LQ_, ep);
  {
    int tot = B_ * 256 * LQ_;
    k_concat2<<<(tot + 255) / 256, 256, 0, stream>>>(aux, Q, Qe, LQ_, tot);
  }

  // ---- CQ attention + resizer -> Mb ----
  k_cqSrow<<<(B_ * LC_ * LQ_) / 256, 256, 0, stream>>>(Ce, Qe, w4C, w4Q, w4mlu, cq_b, maskQ, Sbuf, S1);
  k_softmax_col<<<B_ * LQ_, 256, 0, stream>>>(Sbuf, maskC, S2);
  k_cqY<<<(B_ * 256 * LQ_) / 256, 256, 0, stream>>>(S2, Ce, Yb);
  k_cqAB<<<dim3(LC_ / 64, 64, B_), 256, 0, stream>>>(S1, Qe, Yb, Ab, Bb);
  k_resizer_mfma<<<dim3(LC_ / 16, 2, B_), 256, 0, stream>>>(Ce, Ab, Bb, w_rsz, Mb);

  // ---- model encoder: 3 runs of 7 blocks, ping-pong cur/aux ----
  float* out = (float*)d_out;
  float* bufs[2] = {cur, aux};
  int cb = 0;
  const float* src = Mb;
  for (int r = 0; r < 3; r++) {
    for (int bi = 0; bi < 7; bi++) {
      BlkP mp{};
      mp.n_conv = 2; mp.k = 5;
      for (int ci = 0; ci < 2; ci++) {
        int pc = bi * 2 + ci;
        mp.lnc_g[ci] = m_lnc_g + pc * 128;
        mp.lnc_b[ci] = m_lnc_b + pc * 128;
        mp.dw[ci]    = m_dw + pc * 128 * 5;
        mp.pw[ci]    = w_mpw + (size_t)pc * 128 * 128;
        mp.pw_b[ci]  = m_pw_b + pc * 128;
      }
      mp.mem_w  = w_mmem + (size_t)bi * 256 * 128;
      mp.q_w    = w_mq + (size_t)bi * 128 * 128;
      mp.ffn1_w = w_mf1 + (size_t)bi * 128 * 128;
      mp.ffn1_b = m_ffn1_b + bi * 128;
      mp.ffn2_w = w_mf2 + (size_t)bi * 128 * 128;
      mp.ffn2_b = m_ffn2_b + bi * 128;
      mp.ln1_g = m_ln1_g + bi * 128; mp.ln1_b = m_ln1_b + bi * 128;
      mp.ln2_g = m_ln2_g + bi * 128; mp.ln2_b = m_ln2_b + bi * 128;
      float* ob = bufs[cb];
      fused_conv_pair(stream, src, ob, LC_, mp, 0, true);
      encoder_tail(stream, ob, mkv, qpb, maskC, LC_, mp);
      src = ob;
      cb ^= 1;
    }
    hipMemcpyAsync(out + (size_t)r * SB, src, SB * sizeof(float),
                   hipMemcpyDeviceToDevice, stream);
  }
}